// Round 3
// baseline (658.881 us; speedup 1.0000x reference)
//
#include <hip/hip_runtime.h>
#include <hip/hip_bf16.h>
#include <math.h>

static constexpr float SCALE = 0.03125f; // 1/sqrt(1024)

typedef __attribute__((ext_vector_type(4))) float f32x4;
typedef __attribute__((ext_vector_type(8))) __bf16 bf16x8;
typedef __attribute__((ext_vector_type(4))) __bf16 bf16x4;

__device__ __forceinline__ void g2l16(const void* g, void* l) {
  __builtin_amdgcn_global_load_lds(
      (const __attribute__((address_space(1))) unsigned int*)g,
      (__attribute__((address_space(3))) unsigned int*)l,
      16, 0, 0);
}

// ---------------- fused weight prep: 7 transposes + 4 casts + ln_sa in one launch --------
// tile ranges (64x64 wtrans tiles): qkv 0-767 | kT 768-1023 | vT 1024-1279 |
// saoT 1280-1535 | caoT 1536-1791 | lin1T 1792-2303 | lin2T 2304-2815
// casts (2048 elems/block): ihB 2816-4351 | hhB 4352-5887 | qhid 5888-7935 | ctx 7936-9983
// ln_sa rows: 9984-14079 (independent of everything else in this launch)
__global__ __launch_bounds__(256) void prep_all(
    const float* __restrict__ sa_qkv_w, const float* __restrict__ ca_k_w,
    const float* __restrict__ ca_v_w, const float* __restrict__ sa_out_w,
    const float* __restrict__ ca_out_w, const float* __restrict__ lin1_w,
    const float* __restrict__ lin2_w, const float* __restrict__ gru_w_ih,
    const float* __restrict__ gru_w_hh, const float* __restrict__ qhid,
    const float* __restrict__ contexts,
    const float* __restrict__ queries, const float* __restrict__ sa_norm_w,
    const float* __restrict__ sa_norm_b,
    __bf16* __restrict__ qkvT, __bf16* __restrict__ kT, __bf16* __restrict__ vT,
    __bf16* __restrict__ saoT, __bf16* __restrict__ caoT, __bf16* __restrict__ lin1T,
    __bf16* __restrict__ lin2T, __bf16* __restrict__ ihB, __bf16* __restrict__ hhB,
    __bf16* __restrict__ qhB, __bf16* __restrict__ ctxB, __bf16* __restrict__ xnB) {
  int bid = blockIdx.x;
  int t = threadIdx.x;
  if (bid >= 9984) {  // ---- LayerNorm(queries) -> xnB, D=1024 ----
    int row = bid - 9984;
    int c = t * 4;
    float4 v = *(const float4*)(queries + (size_t)row * 1024 + c);
    float s = v.x + v.y + v.z + v.w;
    float s2 = v.x*v.x + v.y*v.y + v.z*v.z + v.w*v.w;
    #pragma unroll
    for (int off = 32; off > 0; off >>= 1) {
      s += __shfl_xor(s, off);
      s2 += __shfl_xor(s2, off);
    }
    __shared__ float red[4], red2[4];
    int wv = t >> 6;
    if ((t & 63) == 0) { red[wv] = s; red2[wv] = s2; }
    __syncthreads();
    float S  = red[0] + red[1] + red[2] + red[3];
    float S2 = red2[0] + red2[1] + red2[2] + red2[3];
    float mean = S / 1024.f;
    float var = S2 / 1024.f - mean * mean;
    float rs = rsqrtf(var + 1e-5f);
    float vv[4] = {v.x, v.y, v.z, v.w};
    bf16x4 o;
    #pragma unroll
    for (int j = 0; j < 4; ++j)
      o[j] = (__bf16)((vv[j] - mean) * rs * sa_norm_w[c+j] + sa_norm_b[c+j]);
    *(bf16x4*)(xnB + (size_t)row * 1024 + c) = o;
    return;
  }
  if (bid >= 2816) {  // casts, 8 elems/thread
    const float* csrc; __bf16* cdst; int cbase;
    if (bid < 4352)      { csrc = gru_w_ih; cdst = ihB;  cbase = 2816; }
    else if (bid < 5888) { csrc = gru_w_hh; cdst = hhB;  cbase = 4352; }
    else if (bid < 7936) { csrc = qhid;     cdst = qhB;  cbase = 5888; }
    else                 { csrc = contexts; cdst = ctxB; cbase = 7936; }
    size_t idx = ((size_t)(bid - cbase) * 256 + t) * 8;
    float4 a = *(const float4*)(csrc + idx);
    float4 b = *(const float4*)(csrc + idx + 4);
    bf16x8 o = {(__bf16)a.x,(__bf16)a.y,(__bf16)a.z,(__bf16)a.w,
                (__bf16)b.x,(__bf16)b.y,(__bf16)b.z,(__bf16)b.w};
    *(bf16x8*)(cdst + idx) = o;
    return;
  }
  const float* src; __bf16* dst; int Kd, N, base;
  if (bid < 768)       { src = sa_qkv_w; dst = qkvT;  Kd = 1024; N = 3072; base = 0; }
  else if (bid < 1024) { src = ca_k_w;   dst = kT;    Kd = 1024; N = 1024; base = 768; }
  else if (bid < 1280) { src = ca_v_w;   dst = vT;    Kd = 1024; N = 1024; base = 1024; }
  else if (bid < 1536) { src = sa_out_w; dst = saoT;  Kd = 1024; N = 1024; base = 1280; }
  else if (bid < 1792) { src = ca_out_w; dst = caoT;  Kd = 1024; N = 1024; base = 1536; }
  else if (bid < 2304) { src = lin1_w;   dst = lin1T; Kd = 1024; N = 2048; base = 1792; }
  else                 { src = lin2_w;   dst = lin2T; Kd = 2048; N = 1024; base = 2304; }
  int tid = bid - base;
  int ntx = N >> 6;
  int n0 = (tid % ntx) * 64, k0 = (tid / ntx) * 64;
  __shared__ float tile[64][65];
  #pragma unroll
  for (int i = 0; i < 16; ++i) {
    int idx = i * 256 + t; int r = idx >> 6, c = idx & 63;
    tile[r][c] = src[(size_t)(k0 + r) * N + n0 + c];
  }
  __syncthreads();
  #pragma unroll
  for (int i = 0; i < 16; ++i) {
    int idx = i * 256 + t; int r = idx >> 6, c = idx & 63;
    dst[(size_t)(n0 + r) * Kd + k0 + c] = (__bf16)tile[c][r];
  }
}

// ---------------- LayerNorm (+ optional SiLU) -> bf16, fp32 or bf16 input ----------------
template <int NV>  // NV = D/1024 (4*NV elems/thread)
__global__ __launch_bounds__(256) void ln_bf16(
    const float* __restrict__ xf, const __bf16* __restrict__ xb,
    const float* __restrict__ w, const float* __restrict__ b,
    __bf16* __restrict__ out, int silu) {
  const int D = NV * 1024;
  int row = blockIdx.x, t = threadIdx.x;
  float vals[NV * 4];
  float s = 0.f, s2 = 0.f;
  #pragma unroll
  for (int i = 0; i < NV; ++i) {
    int c = (i * 256 + t) * 4;
    float4 v;
    if (xf) {
      v = *(const float4*)(xf + (size_t)row * D + c);
    } else {
      bf16x4 vb = *(const bf16x4*)(xb + (size_t)row * D + c);
      v = make_float4((float)vb[0], (float)vb[1], (float)vb[2], (float)vb[3]);
    }
    vals[i*4+0] = v.x; vals[i*4+1] = v.y; vals[i*4+2] = v.z; vals[i*4+3] = v.w;
    s += v.x + v.y + v.z + v.w;
    s2 += v.x*v.x + v.y*v.y + v.z*v.z + v.w*v.w;
  }
  #pragma unroll
  for (int off = 32; off > 0; off >>= 1) {
    s += __shfl_xor(s, off);
    s2 += __shfl_xor(s2, off);
  }
  __shared__ float red[4], red2[4];
  int wv = t >> 6;
  if ((t & 63) == 0) { red[wv] = s; red2[wv] = s2; }
  __syncthreads();
  float S  = red[0] + red[1] + red[2] + red[3];
  float S2 = red2[0] + red2[1] + red2[2] + red2[3];
  float mean = S / D;
  float var = S2 / D - mean * mean;
  float rs = rsqrtf(var + 1e-5f);
  #pragma unroll
  for (int i = 0; i < NV; ++i) {
    int c = (i * 256 + t) * 4;
    bf16x4 o;
    #pragma unroll
    for (int j = 0; j < 4; ++j) {
      float v = (vals[i*4+j] - mean) * rs * w[c+j] + b[c+j];
      if (silu) v = v / (1.f + __expf(-v));
      o[j] = (__bf16)v;
    }
    *(bf16x4*)(out + (size_t)row * D + c) = o;
  }
}

// ---------------- bf16 MFMA GEMM core, 2-buffer stage-early/drain-late pipeline ----------
// C[M,N] = A[M,K] @ B^T; B stored [N][K]. Tile 128x128, BK=64, 4 waves.
// vmode: 0 = plain epilogue; 1 = qkv layout (cols c: c%192>=128 are V, h=c/192,
// d=c%192-128); 2 = kv layout (c>=1024 are V, h=(c-1024)/64, d=c&63). V elements
// are written TRANSPOSED into VTout[(b*16+h)*64+d][k=row%1024] (bf16x4 packed store)
// and skipped in outB. Requires K % 128 == 0 (all call sites).
__device__ __forceinline__ void gemm_body(
    const __bf16* __restrict__ A, long long lda,
    const __bf16* __restrict__ B, long long ldb,
    float* __restrict__ outF, __bf16* __restrict__ outB, long long ldc,
    const float* __restrict__ bias, const float* __restrict__ res,
    int K, int bm, int bn, __bf16* __restrict__ VTout, int vmode) {
  __shared__ __bf16 Asm0[8192];
  __shared__ __bf16 Bsm0[8192];
  __shared__ __bf16 Asm1[8192];
  __shared__ __bf16 Bsm1[8192];
  int t = threadIdx.x;
  int lane = t & 63, w = t >> 6;
  int l15 = lane & 15, kg = lane >> 4;
  int wm = (w >> 1) * 64, wn = (w & 1) * 64;

  f32x4 acc[4][4];
  #pragma unroll
  for (int i = 0; i < 4; ++i)
    #pragma unroll
    for (int j = 0; j < 4; ++j) acc[i][j] = (f32x4)(0.0f);

  const __bf16* ga[4]; const __bf16* gb[4];
  int lo[4];
  #pragma unroll
  for (int i = 0; i < 4; ++i) {
    int slot = i * 256 + t;
    int row = slot >> 3, s = slot & 7;
    int sx = s ^ (row & 7);
    ga[i] = A + (size_t)(bm + row) * lda + (sx << 3);
    gb[i] = B + (size_t)(bn + row) * ldb + (sx << 3);
    lo[i] = (i * 256 + w * 64) << 3;
  }

  auto STAGE = [&](__bf16* As, __bf16* Bs, int k0) {
    #pragma unroll
    for (int i = 0; i < 4; ++i) g2l16(ga[i] + k0, As + lo[i]);
    #pragma unroll
    for (int i = 0; i < 4; ++i) g2l16(gb[i] + k0, Bs + lo[i]);
  };
  auto COMPUTE = [&](const __bf16* As, const __bf16* Bs) {
    #pragma unroll
    for (int kk = 0; kk < 2; ++kk) {
      bf16x8 af[4], bfr[4];
      #pragma unroll
      for (int mi = 0; mi < 4; ++mi) {
        int row = wm + mi * 16 + l15;
        int ks = kk * 4 + kg;
        af[mi] = *(const bf16x8*)(As + row * 64 + ((ks ^ (row & 7)) << 3));
      }
      #pragma unroll
      for (int ni = 0; ni < 4; ++ni) {
        int row = wn + ni * 16 + l15;
        int ks = kk * 4 + kg;
        bfr[ni] = *(const bf16x8*)(Bs + row * 64 + ((ks ^ (row & 7)) << 3));
      }
      #pragma unroll
      for (int mi = 0; mi < 4; ++mi)
        #pragma unroll
        for (int ni = 0; ni < 4; ++ni)
          acc[mi][ni] = __builtin_amdgcn_mfma_f32_16x16x32_bf16(
              af[mi], bfr[ni], acc[mi][ni], 0, 0, 0);
    }
  };
  #define GEMM_SYNC() do { \
    asm volatile("s_waitcnt vmcnt(0)" ::: "memory"); \
    __builtin_amdgcn_s_barrier(); \
    __builtin_amdgcn_sched_barrier(0); \
  } while (0)

  STAGE(Asm0, Bsm0, 0);
  GEMM_SYNC();
  int nk = K >> 6;  // even
  for (int kt = 0; kt + 2 < nk; kt += 2) {
    STAGE(Asm1, Bsm1, (kt + 1) << 6);
    COMPUTE(Asm0, Bsm0);
    GEMM_SYNC();
    STAGE(Asm0, Bsm0, (kt + 2) << 6);
    COMPUTE(Asm1, Bsm1);
    GEMM_SYNC();
  }
  // tail: tiles nk-2 (in buf0), nk-1
  STAGE(Asm1, Bsm1, (nk - 1) << 6);
  COMPUTE(Asm0, Bsm0);
  GEMM_SYNC();
  COMPUTE(Asm1, Bsm1);
  #undef GEMM_SYNC

  #pragma unroll
  for (int mi = 0; mi < 4; ++mi) {
    #pragma unroll
    for (int ni = 0; ni < 4; ++ni) {
      int rbase = bm + wm + mi * 16 + kg * 4;
      int c = bn + wn + ni * 16 + l15;
      if (vmode == 0) {
        #pragma unroll
        for (int r = 0; r < 4; ++r) {
          float val = acc[mi][ni][r];
          if (bias) val += bias[c];
          size_t off = (size_t)(rbase + r) * ldc + c;
          if (res) val += res[off];
          if (outF) outF[off] = val;
          if (outB) outB[off] = (__bf16)val;
        }
      } else {
        // bias/res/outF are null on vmode call sites
        int isV, h, d;
        if (vmode == 1) { int seg = c % 192; isV = seg >= 128; h = c / 192; d = seg - 128; }
        else            { isV = c >= 1024;  h = (c - 1024) >> 6; d = c & 63; }
        if (isV) {
          int b = rbase >> 10, k = rbase & 1023;  // 4 consecutive rows, same batch
          bf16x4 v4;
          #pragma unroll
          for (int r = 0; r < 4; ++r) v4[r] = (__bf16)acc[mi][ni][r];
          *(bf16x4*)(VTout + (((size_t)((b * 16 + h) * 64 + d)) << 10) + k) = v4;
        } else {
          #pragma unroll
          for (int r = 0; r < 4; ++r)
            outB[(size_t)(rbase + r) * ldc + c] = (__bf16)acc[mi][ni][r];
        }
      }
    }
  }
}

// Single-GEMM kernel (2D grid, XCD-aware swizzle; nwg divisible by 8 at all call sites).
__global__ __launch_bounds__(256) void gemm_bf16(
    const __bf16* __restrict__ A, long long lda,
    const __bf16* __restrict__ B, long long ldb,
    float* __restrict__ outF, __bf16* __restrict__ outB, long long ldc,
    const float* __restrict__ bias, const float* __restrict__ res, int K,
    __bf16* __restrict__ VTout, int vmode) {
  int nwg = gridDim.x * gridDim.y;
  int orig = blockIdx.y * gridDim.x + blockIdx.x;
  int swz = (orig & 7) * (nwg >> 3) + (orig >> 3);
  gemm_body(A, lda, B, ldb, outF, outB, ldc, bias, res, K,
            (swz / gridDim.x) * 128, (swz % gridDim.x) * 128, VTout, vmode);
}

// Dual-GEMM kernel: two independent GEMMs in one launch (1D grid, blocks < nb0 -> p0).
// Fills the machine when one GEMM alone has <2 blocks/CU. nb0 and nb1 divisible by 8.
__global__ __launch_bounds__(256) void gemm_dual(
    const __bf16* __restrict__ A0, long long lda0, const __bf16* __restrict__ B0, long long ldb0,
    float* __restrict__ oF0, __bf16* __restrict__ oB0, long long ldc0,
    const float* __restrict__ bias0, const float* __restrict__ res0, int K0, int gx0, int nb0,
    __bf16* __restrict__ VT0, int vm0,
    const __bf16* __restrict__ A1, long long lda1, const __bf16* __restrict__ B1, long long ldb1,
    float* __restrict__ oF1, __bf16* __restrict__ oB1, long long ldc1,
    const float* __restrict__ bias1, const float* __restrict__ res1, int K1, int gx1,
    __bf16* __restrict__ VT1, int vm1) {
  int bid = blockIdx.x;
  if (bid < nb0) {
    int swz = (bid & 7) * (nb0 >> 3) + (bid >> 3);
    gemm_body(A0, lda0, B0, ldb0, oF0, oB0, ldc0, bias0, res0, K0,
              (swz / gx0) * 128, (swz % gx0) * 128, VT0, vm0);
  } else {
    int b = bid - nb0;
    int nb1 = gridDim.x - nb0;
    int swz = (b & 7) * (nb1 >> 3) + (b >> 3);
    gemm_body(A1, lda1, B1, ldb1, oF1, oB1, ldc1, bias1, res1, K1,
              (swz / gx1) * 128, (swz % gx1) * 128, VT1, vm1);
  }
}

// ---------------- Fused flash attention, 3-deep pipelined K/V staging ----------------
// Per g=(b,h): O[q][d] = softmax_kv(S*scale) @ V, S = Q @ K^T (head dim 64).
// Swapped QK^T -> S^T acc (col=q=l15). P -> LDS packed bf16x4, XOR-swizzled.
// Psm/corr_l/l_l are wave-private rows => ONE raw s_barrier per tile suffices;
// staging for tile t+2 issued after the barrier (3 LDS buffers), waited with
// counted vmcnt (never 0 mid-loop). E: raw S stored nontemporally (268 MB stream).
template <int E>
__global__ __launch_bounds__(256) void flash_attn(
    const __bf16* __restrict__ Qb, long long q_sb, long long q_sh, int q_sm,
    const __bf16* __restrict__ Kb, long long k_sb, long long k_sh, int k_sm,
    const __bf16* __restrict__ VT, __bf16* __restrict__ Ob,
    float* __restrict__ energyOut, float scale) {
  __shared__ __bf16 Ksm[3][4096];
  __shared__ __bf16 Vsm[3][4096];
  __shared__ __bf16 Psm[128 * 64];
  __shared__ float corr_l[128];
  __shared__ float l_l[128];
  int g = blockIdx.y, b = g >> 4, h = g & 15;
  int qt = blockIdx.x * 128;
  const __bf16* Qg = Qb + (size_t)b * q_sb + (size_t)h * q_sh;
  const __bf16* Kg = Kb + (size_t)b * k_sb + (size_t)h * k_sh;
  const __bf16* Vg = VT + (size_t)g * 65536;
  int t = threadIdx.x, lane = t & 63, w = t >> 6;
  int l15 = lane & 15, kg = lane >> 4;
  int wq = w * 32;

  bf16x8 qf[2][2];
  #pragma unroll
  for (int nq = 0; nq < 2; ++nq)
    #pragma unroll
    for (int kk = 0; kk < 2; ++kk)
      qf[nq][kk] = *(const bf16x8*)(
          Qg + (size_t)(qt + wq + nq * 16 + l15) * q_sm + kk * 32 + kg * 8);

  f32x4 acc_o[2][4];
  #pragma unroll
  for (int i = 0; i < 2; ++i)
    #pragma unroll
    for (int j = 0; j < 4; ++j) acc_o[i][j] = (f32x4)(0.0f);
  float m_run[2] = {-1e30f, -1e30f};
  float l_run[2] = {0.f, 0.f};

  const __bf16* gK[2]; const __bf16* gV[2];
  int lo[2];
  #pragma unroll
  for (int i = 0; i < 2; ++i) {
    int slot = i * 256 + t;
    int row = slot >> 3, s = slot & 7, sx = s ^ (row & 7);
    gK[i] = Kg + (size_t)row * k_sm + (sx << 3);
    gV[i] = Vg + (size_t)row * 1024 + (sx << 3);
    lo[i] = (i * 256 + w * 64) << 3;
  }

  // prologue: stage tile 0 (4 oldest vmem ops) then tile 1
  #pragma unroll
  for (int i = 0; i < 2; ++i) g2l16(gK[i], &Ksm[0][lo[i]]);
  #pragma unroll
  for (int i = 0; i < 2; ++i) g2l16(gV[i], &Vsm[0][lo[i]]);
  #pragma unroll
  for (int i = 0; i < 2; ++i) g2l16(gK[i] + (size_t)64 * k_sm, &Ksm[1][lo[i]]);
  #pragma unroll
  for (int i = 0; i < 2; ++i) g2l16(gV[i] + 64, &Vsm[1][lo[i]]);

  int rb = 0;  // read buffer = kvt % 3
  for (int kvt = 0; kvt < 16; ++kvt) {
    // counted wait: exactly the newer-than-stage-kvt op count (4 loads/tile, 8 stores/tile if E)
    if (E) {
      if (kvt == 0)       asm volatile("s_waitcnt vmcnt(4)" ::: "memory");
      else if (kvt == 1)  asm volatile("s_waitcnt vmcnt(12)" ::: "memory");
      else if (kvt == 15) asm volatile("s_waitcnt vmcnt(16)" ::: "memory");
      else                asm volatile("s_waitcnt vmcnt(20)" ::: "memory");
    } else {
      if (kvt == 15)      asm volatile("s_waitcnt vmcnt(0)" ::: "memory");
      else                asm volatile("s_waitcnt vmcnt(4)" ::: "memory");
    }
    __builtin_amdgcn_s_barrier();
    __builtin_amdgcn_sched_barrier(0);  // pin: no memory op crosses the barrier

    if (kvt < 14) {  // stage tile kvt+2 (after barrier: all waves done reading that buffer)
      int sbuf = rb >= 1 ? rb - 1 : rb + 2;  // (kvt+2)%3
      size_t ko = (size_t)(kvt + 2) << 6;
      #pragma unroll
      for (int i = 0; i < 2; ++i) g2l16(gK[i] + ko * k_sm, &Ksm[sbuf][lo[i]]);
      #pragma unroll
      for (int i = 0; i < 2; ++i) g2l16(gV[i] + ko, &Vsm[sbuf][lo[i]]);
    }
    const __bf16* Ks = Ksm[rb];
    const __bf16* Vs = Vsm[rb];

    f32x4 accs[4][2];
    #pragma unroll
    for (int i = 0; i < 4; ++i)
      #pragma unroll
      for (int j = 0; j < 2; ++j) accs[i][j] = (f32x4)(0.0f);
    __builtin_amdgcn_s_setprio(1);
    #pragma unroll
    for (int tt = 0; tt < 4; ++tt) {
      bf16x8 kf[2];
      #pragma unroll
      for (int kk = 0; kk < 2; ++kk) {
        int row = tt * 16 + l15;
        int ks = kk * 4 + kg;
        kf[kk] = *(const bf16x8*)(Ks + row * 64 + ((ks ^ (row & 7)) << 3));
      }
      #pragma unroll
      for (int nq = 0; nq < 2; ++nq)
        #pragma unroll
        for (int kk = 0; kk < 2; ++kk)
          accs[tt][nq] = __builtin_amdgcn_mfma_f32_16x16x32_bf16(
              kf[kk], qf[nq][kk], accs[tt][nq], 0, 0, 0);
    }
    __builtin_amdgcn_s_setprio(0);

    if (E) {
      int kv0 = kvt << 6;
      float* eg = energyOut + ((size_t)g << 20);
      #pragma unroll
      for (int nq = 0; nq < 2; ++nq) {
        int q = qt + wq + nq * 16 + l15;
        #pragma unroll
        for (int tt = 0; tt < 4; ++tt)
          __builtin_nontemporal_store(
              accs[tt][nq], (f32x4*)(eg + (size_t)q * 1024 + kv0 + tt * 16 + kg * 4));
      }
    }

    #pragma unroll
    for (int nq = 0; nq < 2; ++nq) {
      float tmax = -1e30f;
      #pragma unroll
      for (int tt = 0; tt < 4; ++tt)
        #pragma unroll
        for (int r = 0; r < 4; ++r) tmax = fmaxf(tmax, accs[tt][nq][r]);
      tmax *= scale;
      tmax = fmaxf(tmax, __shfl_xor(tmax, 16));
      tmax = fmaxf(tmax, __shfl_xor(tmax, 32));
      float m_new = fmaxf(m_run[nq], tmax);
      float corr = __expf(m_run[nq] - m_new);
      m_run[nq] = m_new;
      int q = wq + nq * 16 + l15;
      float psum = 0.f;
      #pragma unroll
      for (int tt = 0; tt < 4; ++tt) {
        bf16x4 p4;
        #pragma unroll
        for (int r = 0; r < 4; ++r) {
          float p = __expf(accs[tt][nq][r] * scale - m_new);
          psum += p;
          p4[r] = (__bf16)p;
        }
        int kvs = (tt * 16 + kg * 4) ^ ((q & 7) << 3);
        *(bf16x4*)(Psm + q * 64 + kvs) = p4;
      }
      psum += __shfl_xor(psum, 16);
      psum += __shfl_xor(psum, 32);
      l_run[nq] = l_run[nq] * corr + psum;
      if (kg == 0) corr_l[q] = corr;
    }
    // no barrier: Psm / corr_l rows are wave-private

    #pragma unroll
    for (int mq = 0; mq < 2; ++mq) {
      f32x4 c4 = *(const f32x4*)&corr_l[wq + mq * 16 + kg * 4];
      #pragma unroll
      for (int nd = 0; nd < 4; ++nd)
        #pragma unroll
        for (int r = 0; r < 4; ++r) acc_o[mq][nd][r] *= c4[r];
    }
    __builtin_amdgcn_s_setprio(1);
    #pragma unroll
    for (int kk = 0; kk < 2; ++kk) {
      bf16x8 pf[2], vf[4];
      #pragma unroll
      for (int mq = 0; mq < 2; ++mq) {
        int row = wq + mq * 16 + l15;
        int kvs = (kk * 32 + kg * 8) ^ ((row & 7) << 3);
        pf[mq] = *(const bf16x8*)(Psm + row * 64 + kvs);
      }
      #pragma unroll
      for (int nd = 0; nd < 4; ++nd) {
        int vrow = nd * 16 + l15;
        vf[nd] = *(const bf16x8*)(Vs + vrow * 64 + (((kk * 4 + kg) ^ (vrow & 7)) << 3));
      }
      #pragma unroll
      for (int mq = 0; mq < 2; ++mq)
        #pragma unroll
        for (int nd = 0; nd < 4; ++nd)
          acc_o[mq][nd] = __builtin_amdgcn_mfma_f32_16x16x32_bf16(
              pf[mq], vf[nd], acc_o[mq][nd], 0, 0, 0);
    }
    __builtin_amdgcn_s_setprio(0);
    rb = rb == 2 ? 0 : rb + 1;
  }

  #pragma unroll
  for (int nq = 0; nq < 2; ++nq)
    if (kg == 0) l_l[wq + nq * 16 + l15] = l_run[nq];
  __syncthreads();

  #pragma unroll
  for (int mq = 0; mq < 2; ++mq) {
    f32x4 lv = *(const f32x4*)&l_l[wq + mq * 16 + kg * 4];
    #pragma unroll
    for (int nd = 0; nd < 4; ++nd) {
      int col = h * 64 + nd * 16 + l15;
      #pragma unroll
      for (int r = 0; r < 4; ++r) {
        int qrow = qt + wq + mq * 16 + kg * 4 + r;
        Ob[(size_t)(b * 1024 + qrow) * 1024 + col] = (__bf16)(acc_o[mq][nd][r] / lv[r]);
      }
    }
  }
}

// ---------------- GRU cell elementwise, bf16 inputs, 8 elems/thread ----------------
__global__ __launch_bounds__(256) void gru_kernel(
    const __bf16* __restrict__ gi, const __bf16* __restrict__ gh,
    const float* __restrict__ hf, float* __restrict__ qh, __bf16* __restrict__ qhb) {
  size_t e0 = ((size_t)blockIdx.x * 256 + threadIdx.x) * 8;  // over 4M elems
  int row = (int)(e0 >> 10), col = (int)(e0 & 1023);
  size_t base = (size_t)row * 3072 + col;
  bf16x8 vir = *(const bf16x8*)(gi + base);
  bf16x8 viz = *(const bf16x8*)(gi + base + 1024);
  bf16x8 vin = *(const bf16x8*)(gi + base + 2048);
  bf16x8 vhr = *(const bf16x8*)(gh + base);
  bf16x8 vhz = *(const bf16x8*)(gh + base + 1024);
  bf16x8 vhn = *(const bf16x8*)(gh + base + 2048);
  float4 h0 = *(const float4*)(hf + e0);
  float4 h1 = *(const float4*)(hf + e0 + 4);
  float hv[8] = {h0.x, h0.y, h0.z, h0.w, h1.x, h1.y, h1.z, h1.w};
  float q[8];
  #pragma unroll
  for (int j = 0; j < 8; ++j) {
    float r = 1.f / (1.f + __expf(-((float)vir[j] + (float)vhr[j])));
    float z = 1.f / (1.f + __expf(-((float)viz[j] + (float)vhz[j])));
    float n = tanhf((float)vin[j] + r * (float)vhn[j]);
    q[j] = (1.f - z) * n + z * hv[j];
  }
  *(float4*)(qh + e0)     = make_float4(q[0], q[1], q[2], q[3]);
  *(float4*)(qh + e0 + 4) = make_float4(q[4], q[5], q[6], q[7]);
  bf16x8 qb;
  #pragma unroll
  for (int j = 0; j < 8; ++j) qb[j] = (__bf16)q[j];
  *(bf16x8*)(qhb + e0) = qb;
}

extern "C" void kernel_launch(void* const* d_in, const int* in_sizes, int n_in,
                              void* d_out, int out_size, void* d_ws, size_t ws_size,
                              hipStream_t stream) {
  (void)in_sizes; (void)n_in; (void)out_size; (void)ws_size;
  const float* queries   = (const float*)d_in[0];
  const float* contexts  = (const float*)d_in[1];
  const float* qhid      = (const float*)d_in[2];
  const float* sa_norm_w = (const float*)d_in[3];
  const float* sa_norm_b = (const float*)d_in[4];
  const float* sa_qkv_w  = (const float*)d_in[5];
  const float* sa_out_w  = (const float*)d_in[6];
  const float* sa_out_b  = (const float*)d_in[7];
  const float* ca_norm_w = (const float*)d_in[8];
  const float* ca_norm_b = (const float*)d_in[9];
  const float* gru_w_ih  = (const float*)d_in[10];
  const float* gru_w_hh  = (const float*)d_in[11];
  const float* gru_b_ih  = (const float*)d_in[12];
  const float* gru_b_hh  = (const float*)d_in[13];
  const float* ca_k_w    = (const float*)d_in[14];
  const float* ca_v_w    = (const float*)d_in[15];
  const float* ca_out_w  = (const float*)d_in[16];
  const float* ca_out_b  = (const float*)d_in[17];
  const float* ln1_w     = (const float*)d_in[18];
  const float* ln1_b     = (const float*)d_in[19];
  const float* lin1_w    = (const float*)d_in[20];
  const float* ln2_w     = (const float*)d_in[21];
  const float* ln2_b     = (const float*)d_in[22];
  const float* lin2_w    = (const float*)d_in[23];

  float* out0   = (float*)d_out;               // [4096,1024]
  float* energy = out0 + (size_t)4194304;      // [64,1024,1024]
  float* qh_out = out0 + (size_t)71303168;     // [4096,1024]

  // ---- workspace map (units: MM = 1M floats = 4 MiB) ----
  const size_t MM = 1u << 20;
  float* ws = (float*)d_ws;
  float*  X     = ws;
  float*  X2    = ws + 4 * MM;
  __bf16* M1B    = (__bf16*)(ws + 9 * MM);
  __bf16* XN_b   = (__bf16*)(ws + 17 * MM);
  __bf16* QHID_b = (__bf16*)(ws + 19 * MM);
  __bf16* CTX_b  = (__bf16*)(ws + 21 * MM);
  __bf16* O_b    = (__bf16*)(ws + 23 * MM);
  __bf16* VT_b   = (__bf16*)(ws + 25 * MM);
  __bf16* QKV_b  = (__bf16*)(ws + 27 * MM);
  __bf16* KV_b   = (__bf16*)(ws + 27 * MM);  // [4096][2048] bf16, reuses QKV after SA
  __bf16* LN2_b  = (__bf16*)(ws);            // reuses dead X
  __bf16* qkvT   = (__bf16*)(ws + 33 * MM);
  __bf16* ihB    = (__bf16*)(ws + 34 * MM + MM / 2);
  __bf16* hhB    = (__bf16*)(ws + 36 * MM);
  __bf16* kT     = (__bf16*)(ws + 37 * MM + MM / 2);  // kT,vT contiguous => merged B [2048][1024]
  __bf16* vT     = (__bf16*)(ws + 38 * MM);
  __bf16* saoT   = (__bf16*)(ws + 38 * MM + MM / 2);
  __bf16* caoT   = (__bf16*)(ws + 39 * MM);
  __bf16* lin1T  = (__bf16*)(ws + 39 * MM + MM / 2);
  __bf16* lin2T  = (__bf16*)(ws + 40 * MM + MM / 2);
  __bf16* GI_b = (__bf16*)energy;            // [4096][3072] bf16 = 24 MB
  __bf16* GH_b = (__bf16*)(energy + 6 * MM); // next 24 MB

  const long long QKV_SB = 1024LL * 3072;
  const long long KV_SB  = 1024LL * 2048;

  // ---- fused prep: all weight transposes + casts + ln_sa ----
  prep_all<<<14080, 256, 0, stream>>>(
      sa_qkv_w, ca_k_w, ca_v_w, sa_out_w, ca_out_w, lin1_w, lin2_w,
      gru_w_ih, gru_w_hh, qhid, contexts, queries, sa_norm_w, sa_norm_b,
      qkvT, kT, vT, saoT, caoT, lin1T, lin2T, ihB, hhB, QHID_b, CTX_b, XN_b);

  // ---- SelfAttention ----
  // qkv GEMM writes Q,K to QKV_b and V directly transposed into VT_b (vmode=1)
  gemm_bf16<<<dim3(24, 32), 256, 0, stream>>>(
      XN_b, 1024, qkvT, 1024, nullptr, QKV_b, 3072, nullptr, nullptr, 1024, VT_b, 1);
  flash_attn<0><<<dim3(8, 64), 256, 0, stream>>>(
      QKV_b, QKV_SB, 192, 3072, QKV_b + 64, QKV_SB, 192, 3072,
      VT_b, O_b, nullptr, SCALE);
  // sa_out (256 blocks, chain) merged with gh (768 blocks, independent after prep)
  gemm_dual<<<1024, 256, 0, stream>>>(
      O_b, 1024, saoT, 1024, X, nullptr, 1024, sa_out_b, queries, 1024, 8, 256, nullptr, 0,
      QHID_b, 1024, hhB, 1024, nullptr, GH_b, 3072, gru_b_hh, nullptr, 1024, 24, nullptr, 0);

  // ---- GRU dynamic query ----
  ln_bf16<1><<<4096, 256, 0, stream>>>(X, nullptr, ca_norm_w, ca_norm_b, XN_b, 0);
  // gi (768 blocks, chain) merged with CA kv projection (512 blocks, independent);
  // kv writes K to KV_b and V directly transposed into VT_b (vmode=2)
  gemm_dual<<<1280, 256, 0, stream>>>(
      XN_b, 1024, ihB, 1024, nullptr, GI_b, 3072, gru_b_ih, nullptr, 1024, 24, 768, nullptr, 0,
      CTX_b, 1024, kT, 1024, nullptr, KV_b, 2048, nullptr, nullptr, 1024, 16, VT_b, 2);
  gru_kernel<<<2048, 256, 0, stream>>>(GI_b, GH_b, qhid, qh_out, QHID_b /*now QHB*/);

  // ---- Cross attention ----
  flash_attn<1><<<dim3(8, 64), 256, 0, stream>>>(
      QHID_b, 1024LL * 1024, 64, 1024, KV_b, KV_SB, 64, 2048,
      VT_b, O_b, energy, SCALE);
  gemm_bf16<<<dim3(8, 32), 256, 0, stream>>>(
      O_b, 1024, caoT, 1024, X2, nullptr, 1024, ca_out_b, X, 1024, nullptr, 0);

  // ---- MLP ----
  ln_bf16<1><<<4096, 256, 0, stream>>>(X2, nullptr, ln1_w, ln1_b, XN_b, 1);
  gemm_bf16<<<dim3(16, 32), 256, 0, stream>>>(
      XN_b, 1024, lin1T, 1024, nullptr, M1B, 2048, nullptr, nullptr, 1024, nullptr, 0);
  ln_bf16<2><<<4096, 256, 0, stream>>>(nullptr, M1B, ln2_w, ln2_b, LN2_b, 1);
  gemm_bf16<<<dim3(8, 32), 256, 0, stream>>>(
      LN2_b, 2048, lin2T, 2048, out0, nullptr, 1024, nullptr, X2, 2048, nullptr, 0);
}

// Round 4
// 640.679 us; speedup vs baseline: 1.0284x; 1.0284x over previous
//
#include <hip/hip_runtime.h>
#include <hip/hip_bf16.h>
#include <math.h>

static constexpr float SCALE = 0.03125f; // 1/sqrt(1024)

typedef __attribute__((ext_vector_type(4))) float f32x4;
typedef __attribute__((ext_vector_type(8))) __bf16 bf16x8;
typedef __attribute__((ext_vector_type(4))) __bf16 bf16x4;

__device__ __forceinline__ void g2l16(const void* g, void* l) {
  __builtin_amdgcn_global_load_lds(
      (const __attribute__((address_space(1))) unsigned int*)g,
      (__attribute__((address_space(3))) unsigned int*)l,
      16, 0, 0);
}

// ---------------- fused weight prep: 7 transposes + 4 casts + ln_sa in one launch --------
// tile ranges (64x64 wtrans tiles): qkv 0-767 | kT 768-1023 | vT 1024-1279 |
// saoT 1280-1535 | caoT 1536-1791 | lin1T 1792-2303 | lin2T 2304-2815
// casts (2048 elems/block): ihB 2816-4351 | hhB 4352-5887 | qhid 5888-7935 | ctx 7936-9983
// ln_sa rows: 9984-14079 (independent of everything else in this launch)
__global__ __launch_bounds__(256) void prep_all(
    const float* __restrict__ sa_qkv_w, const float* __restrict__ ca_k_w,
    const float* __restrict__ ca_v_w, const float* __restrict__ sa_out_w,
    const float* __restrict__ ca_out_w, const float* __restrict__ lin1_w,
    const float* __restrict__ lin2_w, const float* __restrict__ gru_w_ih,
    const float* __restrict__ gru_w_hh, const float* __restrict__ qhid,
    const float* __restrict__ contexts,
    const float* __restrict__ queries, const float* __restrict__ sa_norm_w,
    const float* __restrict__ sa_norm_b,
    __bf16* __restrict__ qkvT, __bf16* __restrict__ kT, __bf16* __restrict__ vT,
    __bf16* __restrict__ saoT, __bf16* __restrict__ caoT, __bf16* __restrict__ lin1T,
    __bf16* __restrict__ lin2T, __bf16* __restrict__ ihB, __bf16* __restrict__ hhB,
    __bf16* __restrict__ qhB, __bf16* __restrict__ ctxB, __bf16* __restrict__ xnB) {
  int bid = blockIdx.x;
  int t = threadIdx.x;
  if (bid >= 9984) {  // ---- LayerNorm(queries) -> xnB, D=1024 ----
    int row = bid - 9984;
    int c = t * 4;
    float4 v = *(const float4*)(queries + (size_t)row * 1024 + c);
    float s = v.x + v.y + v.z + v.w;
    float s2 = v.x*v.x + v.y*v.y + v.z*v.z + v.w*v.w;
    #pragma unroll
    for (int off = 32; off > 0; off >>= 1) {
      s += __shfl_xor(s, off);
      s2 += __shfl_xor(s2, off);
    }
    __shared__ float red[4], red2[4];
    int wv = t >> 6;
    if ((t & 63) == 0) { red[wv] = s; red2[wv] = s2; }
    __syncthreads();
    float S  = red[0] + red[1] + red[2] + red[3];
    float S2 = red2[0] + red2[1] + red2[2] + red2[3];
    float mean = S / 1024.f;
    float var = S2 / 1024.f - mean * mean;
    float rs = rsqrtf(var + 1e-5f);
    float vv[4] = {v.x, v.y, v.z, v.w};
    bf16x4 o;
    #pragma unroll
    for (int j = 0; j < 4; ++j)
      o[j] = (__bf16)((vv[j] - mean) * rs * sa_norm_w[c+j] + sa_norm_b[c+j]);
    *(bf16x4*)(xnB + (size_t)row * 1024 + c) = o;
    return;
  }
  if (bid >= 2816) {  // casts, 8 elems/thread
    const float* csrc; __bf16* cdst; int cbase;
    if (bid < 4352)      { csrc = gru_w_ih; cdst = ihB;  cbase = 2816; }
    else if (bid < 5888) { csrc = gru_w_hh; cdst = hhB;  cbase = 4352; }
    else if (bid < 7936) { csrc = qhid;     cdst = qhB;  cbase = 5888; }
    else                 { csrc = contexts; cdst = ctxB; cbase = 7936; }
    size_t idx = ((size_t)(bid - cbase) * 256 + t) * 8;
    float4 a = *(const float4*)(csrc + idx);
    float4 b = *(const float4*)(csrc + idx + 4);
    bf16x8 o = {(__bf16)a.x,(__bf16)a.y,(__bf16)a.z,(__bf16)a.w,
                (__bf16)b.x,(__bf16)b.y,(__bf16)b.z,(__bf16)b.w};
    *(bf16x8*)(cdst + idx) = o;
    return;
  }
  const float* src; __bf16* dst; int Kd, N, base;
  if (bid < 768)       { src = sa_qkv_w; dst = qkvT;  Kd = 1024; N = 3072; base = 0; }
  else if (bid < 1024) { src = ca_k_w;   dst = kT;    Kd = 1024; N = 1024; base = 768; }
  else if (bid < 1280) { src = ca_v_w;   dst = vT;    Kd = 1024; N = 1024; base = 1024; }
  else if (bid < 1536) { src = sa_out_w; dst = saoT;  Kd = 1024; N = 1024; base = 1280; }
  else if (bid < 1792) { src = ca_out_w; dst = caoT;  Kd = 1024; N = 1024; base = 1536; }
  else if (bid < 2304) { src = lin1_w;   dst = lin1T; Kd = 1024; N = 2048; base = 1792; }
  else                 { src = lin2_w;   dst = lin2T; Kd = 2048; N = 1024; base = 2304; }
  int tid = bid - base;
  int ntx = N >> 6;
  int n0 = (tid % ntx) * 64, k0 = (tid / ntx) * 64;
  __shared__ float tile[64][65];
  #pragma unroll
  for (int i = 0; i < 16; ++i) {
    int idx = i * 256 + t; int r = idx >> 6, c = idx & 63;
    tile[r][c] = src[(size_t)(k0 + r) * N + n0 + c];
  }
  __syncthreads();
  #pragma unroll
  for (int i = 0; i < 16; ++i) {
    int idx = i * 256 + t; int r = idx >> 6, c = idx & 63;
    dst[(size_t)(n0 + r) * Kd + k0 + c] = (__bf16)tile[c][r];
  }
}

// ---------------- LayerNorm (+ optional SiLU) -> bf16, fp32 or bf16 input ----------------
template <int NV>  // NV = D/1024 (4*NV elems/thread)
__global__ __launch_bounds__(256) void ln_bf16(
    const float* __restrict__ xf, const __bf16* __restrict__ xb,
    const float* __restrict__ w, const float* __restrict__ b,
    __bf16* __restrict__ out, int silu) {
  const int D = NV * 1024;
  int row = blockIdx.x, t = threadIdx.x;
  float vals[NV * 4];
  float s = 0.f, s2 = 0.f;
  #pragma unroll
  for (int i = 0; i < NV; ++i) {
    int c = (i * 256 + t) * 4;
    float4 v;
    if (xf) {
      v = *(const float4*)(xf + (size_t)row * D + c);
    } else {
      bf16x4 vb = *(const bf16x4*)(xb + (size_t)row * D + c);
      v = make_float4((float)vb[0], (float)vb[1], (float)vb[2], (float)vb[3]);
    }
    vals[i*4+0] = v.x; vals[i*4+1] = v.y; vals[i*4+2] = v.z; vals[i*4+3] = v.w;
    s += v.x + v.y + v.z + v.w;
    s2 += v.x*v.x + v.y*v.y + v.z*v.z + v.w*v.w;
  }
  #pragma unroll
  for (int off = 32; off > 0; off >>= 1) {
    s += __shfl_xor(s, off);
    s2 += __shfl_xor(s2, off);
  }
  __shared__ float red[4], red2[4];
  int wv = t >> 6;
  if ((t & 63) == 0) { red[wv] = s; red2[wv] = s2; }
  __syncthreads();
  float S  = red[0] + red[1] + red[2] + red[3];
  float S2 = red2[0] + red2[1] + red2[2] + red2[3];
  float mean = S / D;
  float var = S2 / D - mean * mean;
  float rs = rsqrtf(var + 1e-5f);
  #pragma unroll
  for (int i = 0; i < NV; ++i) {
    int c = (i * 256 + t) * 4;
    bf16x4 o;
    #pragma unroll
    for (int j = 0; j < 4; ++j) {
      float v = (vals[i*4+j] - mean) * rs * w[c+j] + b[c+j];
      if (silu) v = v / (1.f + __expf(-v));
      o[j] = (__bf16)v;
    }
    *(bf16x4*)(out + (size_t)row * D + c) = o;
  }
}

// ---------------- bf16 MFMA GEMM core, 2-buffer stage-early/drain-late pipeline ----------
// C[M,N] = A[M,K] @ B^T; B stored [N][K]. Tile 128x128, BK=64, 4 waves.
// Per K-step: STAGE(next buf) -> COMPUTE(cur buf) -> vmcnt(0) -> s_barrier.
// Requires K % 128 == 0 (all call sites). Plain coalesced epilogue only.
__device__ __forceinline__ void gemm_body(
    const __bf16* __restrict__ A, long long lda,
    const __bf16* __restrict__ B, long long ldb,
    float* __restrict__ outF, __bf16* __restrict__ outB, long long ldc,
    const float* __restrict__ bias, const float* __restrict__ res,
    int K, int bm, int bn) {
  __shared__ __bf16 Asm0[8192];
  __shared__ __bf16 Bsm0[8192];
  __shared__ __bf16 Asm1[8192];
  __shared__ __bf16 Bsm1[8192];
  int t = threadIdx.x;
  int lane = t & 63, w = t >> 6;
  int l15 = lane & 15, kg = lane >> 4;
  int wm = (w >> 1) * 64, wn = (w & 1) * 64;

  f32x4 acc[4][4];
  #pragma unroll
  for (int i = 0; i < 4; ++i)
    #pragma unroll
    for (int j = 0; j < 4; ++j) acc[i][j] = (f32x4)(0.0f);

  const __bf16* ga[4]; const __bf16* gb[4];
  int lo[4];
  #pragma unroll
  for (int i = 0; i < 4; ++i) {
    int slot = i * 256 + t;
    int row = slot >> 3, s = slot & 7;
    int sx = s ^ (row & 7);
    ga[i] = A + (size_t)(bm + row) * lda + (sx << 3);
    gb[i] = B + (size_t)(bn + row) * ldb + (sx << 3);
    lo[i] = (i * 256 + w * 64) << 3;
  }

  auto STAGE = [&](__bf16* As, __bf16* Bs, int k0) {
    #pragma unroll
    for (int i = 0; i < 4; ++i) g2l16(ga[i] + k0, As + lo[i]);
    #pragma unroll
    for (int i = 0; i < 4; ++i) g2l16(gb[i] + k0, Bs + lo[i]);
  };
  auto COMPUTE = [&](const __bf16* As, const __bf16* Bs) {
    #pragma unroll
    for (int kk = 0; kk < 2; ++kk) {
      bf16x8 af[4], bfr[4];
      #pragma unroll
      for (int mi = 0; mi < 4; ++mi) {
        int row = wm + mi * 16 + l15;
        int ks = kk * 4 + kg;
        af[mi] = *(const bf16x8*)(As + row * 64 + ((ks ^ (row & 7)) << 3));
      }
      #pragma unroll
      for (int ni = 0; ni < 4; ++ni) {
        int row = wn + ni * 16 + l15;
        int ks = kk * 4 + kg;
        bfr[ni] = *(const bf16x8*)(Bs + row * 64 + ((ks ^ (row & 7)) << 3));
      }
      #pragma unroll
      for (int mi = 0; mi < 4; ++mi)
        #pragma unroll
        for (int ni = 0; ni < 4; ++ni)
          acc[mi][ni] = __builtin_amdgcn_mfma_f32_16x16x32_bf16(
              af[mi], bfr[ni], acc[mi][ni], 0, 0, 0);
    }
  };
  #define GEMM_SYNC() do { \
    asm volatile("s_waitcnt vmcnt(0)" ::: "memory"); \
    __builtin_amdgcn_s_barrier(); \
    __builtin_amdgcn_sched_barrier(0); \
  } while (0)

  STAGE(Asm0, Bsm0, 0);
  GEMM_SYNC();
  int nk = K >> 6;  // even
  for (int kt = 0; kt + 2 < nk; kt += 2) {
    STAGE(Asm1, Bsm1, (kt + 1) << 6);
    COMPUTE(Asm0, Bsm0);
    GEMM_SYNC();
    STAGE(Asm0, Bsm0, (kt + 2) << 6);
    COMPUTE(Asm1, Bsm1);
    GEMM_SYNC();
  }
  // tail: tiles nk-2 (in buf0), nk-1
  STAGE(Asm1, Bsm1, (nk - 1) << 6);
  COMPUTE(Asm0, Bsm0);
  GEMM_SYNC();
  COMPUTE(Asm1, Bsm1);
  #undef GEMM_SYNC

  #pragma unroll
  for (int mi = 0; mi < 4; ++mi) {
    #pragma unroll
    for (int ni = 0; ni < 4; ++ni) {
      int rbase = bm + wm + mi * 16 + kg * 4;
      int c = bn + wn + ni * 16 + l15;
      #pragma unroll
      for (int r = 0; r < 4; ++r) {
        float val = acc[mi][ni][r];
        if (bias) val += bias[c];
        size_t off = (size_t)(rbase + r) * ldc + c;
        if (res) val += res[off];
        if (outF) outF[off] = val;
        if (outB) outB[off] = (__bf16)val;
      }
    }
  }
}

// Single-GEMM kernel (2D grid, XCD-aware swizzle; nwg divisible by 8 at all call sites).
__global__ __launch_bounds__(256) void gemm_bf16(
    const __bf16* __restrict__ A, long long lda,
    const __bf16* __restrict__ B, long long ldb,
    float* __restrict__ outF, __bf16* __restrict__ outB, long long ldc,
    const float* __restrict__ bias, const float* __restrict__ res, int K) {
  int nwg = gridDim.x * gridDim.y;
  int orig = blockIdx.y * gridDim.x + blockIdx.x;
  int swz = (orig & 7) * (nwg >> 3) + (orig >> 3);
  gemm_body(A, lda, B, ldb, outF, outB, ldc, bias, res, K,
            (swz / gridDim.x) * 128, (swz % gridDim.x) * 128);
}

// Dual-GEMM kernel: two independent GEMMs in one launch (1D grid, blocks < nb0 -> p0).
// nb0/nb1 divisible by 8. If batchB1 != 0, the second GEMM is batched over 4
// batches of 1024 rows: C_b = A1 @ (B1 + b<<20)^T written to oB1 + b<<20
// (used for VT_ca = vT @ ctx_b^T, writing V-transpose row-coalesced).
__global__ __launch_bounds__(256) void gemm_dual(
    const __bf16* __restrict__ A0, long long lda0, const __bf16* __restrict__ B0, long long ldb0,
    float* __restrict__ oF0, __bf16* __restrict__ oB0, long long ldc0,
    const float* __restrict__ bias0, const float* __restrict__ res0, int K0, int gx0, int nb0,
    const __bf16* __restrict__ A1, long long lda1, const __bf16* __restrict__ B1, long long ldb1,
    float* __restrict__ oF1, __bf16* __restrict__ oB1, long long ldc1,
    const float* __restrict__ bias1, const float* __restrict__ res1, int K1, int gx1,
    int batchB1) {
  int bid = blockIdx.x;
  if (bid < nb0) {
    int swz = (bid & 7) * (nb0 >> 3) + (bid >> 3);
    gemm_body(A0, lda0, B0, ldb0, oF0, oB0, ldc0, bias0, res0, K0,
              (swz / gx0) * 128, (swz % gx0) * 128);
  } else {
    int b = bid - nb0;
    int nb1 = gridDim.x - nb0;
    int swz = (b & 7) * (nb1 >> 3) + (b >> 3);
    int tm = swz / gx1, bn = (swz % gx1) * 128;
    if (batchB1) {
      int batch = tm >> 3;
      gemm_body(A1, lda1, B1 + ((size_t)batch << 20), ldb1, nullptr,
                oB1 + ((size_t)batch << 20), ldc1, bias1, res1, K1,
                (tm & 7) * 128, bn);
    } else {
      gemm_body(A1, lda1, B1, ldb1, oF1, oB1, ldc1, bias1, res1, K1,
                tm * 128, bn);
    }
  }
}

// ---------------- V transpose: V[b,k,h,d](bf16) -> VT[g][d][1024 k] ----------------
__global__ __launch_bounds__(256) void vtrans(
    const __bf16* __restrict__ V, long long v_sb, long long v_sh, int v_sm,
    __bf16* __restrict__ VT) {
  __shared__ __bf16 tile[64][72];
  int g = blockIdx.y, b = g >> 4, h = g & 15;
  int k0 = blockIdx.x * 64;
  const __bf16* Vb = V + (size_t)b * v_sb + (size_t)h * v_sh;
  int t = threadIdx.x;
  #pragma unroll
  for (int i = 0; i < 2; ++i) {
    int idx = i * 256 + t;
    int k = idx >> 3, dc = (idx & 7) * 8;
    bf16x8 v = *(const bf16x8*)(Vb + (size_t)(k0 + k) * v_sm + dc);
    #pragma unroll
    for (int j = 0; j < 8; ++j) tile[dc + j][k] = v[j];
  }
  __syncthreads();
  #pragma unroll
  for (int i = 0; i < 2; ++i) {
    int idx = i * 256 + t;
    int d = idx >> 3, kc = (idx & 7) * 8;
    bf16x8 v;
    #pragma unroll
    for (int j = 0; j < 8; ++j) v[j] = tile[d][kc + j];
    *(bf16x8*)(VT + ((size_t)g * 64 + d) * 1024 + k0 + kc) = v;
  }
}

// ---------------- Fused flash attention, 3-deep pipelined K/V staging ----------------
// Per g=(b,h): O[q][d] = softmax_kv(S*scale) @ V, S = Q @ K^T (head dim 64).
// Swapped QK^T -> S^T acc (col=q=l15). P -> LDS packed bf16x4, XOR-swizzled.
// Psm/corr_l/l_l are wave-private rows => ONE raw s_barrier per tile suffices;
// staging for tile t+2 issued after the barrier (3 LDS buffers), waited with
// counted vmcnt (never 0 mid-loop). E: raw S stored nontemporally (268 MB stream).
template <int E>
__global__ __launch_bounds__(256) void flash_attn(
    const __bf16* __restrict__ Qb, long long q_sb, long long q_sh, int q_sm,
    const __bf16* __restrict__ Kb, long long k_sb, long long k_sh, int k_sm,
    const __bf16* __restrict__ VT, __bf16* __restrict__ Ob,
    float* __restrict__ energyOut, float scale) {
  __shared__ __bf16 Ksm[3][4096];
  __shared__ __bf16 Vsm[3][4096];
  __shared__ __bf16 Psm[128 * 64];
  __shared__ float corr_l[128];
  __shared__ float l_l[128];
  int g = blockIdx.y, b = g >> 4, h = g & 15;
  int qt = blockIdx.x * 128;
  const __bf16* Qg = Qb + (size_t)b * q_sb + (size_t)h * q_sh;
  const __bf16* Kg = Kb + (size_t)b * k_sb + (size_t)h * k_sh;
  const __bf16* Vg = VT + (size_t)g * 65536;
  int t = threadIdx.x, lane = t & 63, w = t >> 6;
  int l15 = lane & 15, kg = lane >> 4;
  int wq = w * 32;

  bf16x8 qf[2][2];
  #pragma unroll
  for (int nq = 0; nq < 2; ++nq)
    #pragma unroll
    for (int kk = 0; kk < 2; ++kk)
      qf[nq][kk] = *(const bf16x8*)(
          Qg + (size_t)(qt + wq + nq * 16 + l15) * q_sm + kk * 32 + kg * 8);

  f32x4 acc_o[2][4];
  #pragma unroll
  for (int i = 0; i < 2; ++i)
    #pragma unroll
    for (int j = 0; j < 4; ++j) acc_o[i][j] = (f32x4)(0.0f);
  float m_run[2] = {-1e30f, -1e30f};
  float l_run[2] = {0.f, 0.f};

  const __bf16* gK[2]; const __bf16* gV[2];
  int lo[2];
  #pragma unroll
  for (int i = 0; i < 2; ++i) {
    int slot = i * 256 + t;
    int row = slot >> 3, s = slot & 7, sx = s ^ (row & 7);
    gK[i] = Kg + (size_t)row * k_sm + (sx << 3);
    gV[i] = Vg + (size_t)row * 1024 + (sx << 3);
    lo[i] = (i * 256 + w * 64) << 3;
  }

  // prologue: stage tile 0 (4 oldest vmem ops) then tile 1
  #pragma unroll
  for (int i = 0; i < 2; ++i) g2l16(gK[i], &Ksm[0][lo[i]]);
  #pragma unroll
  for (int i = 0; i < 2; ++i) g2l16(gV[i], &Vsm[0][lo[i]]);
  #pragma unroll
  for (int i = 0; i < 2; ++i) g2l16(gK[i] + (size_t)64 * k_sm, &Ksm[1][lo[i]]);
  #pragma unroll
  for (int i = 0; i < 2; ++i) g2l16(gV[i] + 64, &Vsm[1][lo[i]]);

  int rb = 0;  // read buffer = kvt % 3
  for (int kvt = 0; kvt < 16; ++kvt) {
    // counted wait: exactly the newer-than-stage-kvt op count (4 loads/tile, 8 stores/tile if E)
    if (E) {
      if (kvt == 0)       asm volatile("s_waitcnt vmcnt(4)" ::: "memory");
      else if (kvt == 1)  asm volatile("s_waitcnt vmcnt(12)" ::: "memory");
      else if (kvt == 15) asm volatile("s_waitcnt vmcnt(16)" ::: "memory");
      else                asm volatile("s_waitcnt vmcnt(20)" ::: "memory");
    } else {
      if (kvt == 15)      asm volatile("s_waitcnt vmcnt(0)" ::: "memory");
      else                asm volatile("s_waitcnt vmcnt(4)" ::: "memory");
    }
    __builtin_amdgcn_s_barrier();
    __builtin_amdgcn_sched_barrier(0);  // pin: no memory op crosses the barrier

    if (kvt < 14) {  // stage tile kvt+2 (after barrier: all waves done reading that buffer)
      int sbuf = rb >= 1 ? rb - 1 : rb + 2;  // (kvt+2)%3
      size_t ko = (size_t)(kvt + 2) << 6;
      #pragma unroll
      for (int i = 0; i < 2; ++i) g2l16(gK[i] + ko * k_sm, &Ksm[sbuf][lo[i]]);
      #pragma unroll
      for (int i = 0; i < 2; ++i) g2l16(gV[i] + ko, &Vsm[sbuf][lo[i]]);
    }
    const __bf16* Ks = Ksm[rb];
    const __bf16* Vs = Vsm[rb];

    f32x4 accs[4][2];
    #pragma unroll
    for (int i = 0; i < 4; ++i)
      #pragma unroll
      for (int j = 0; j < 2; ++j) accs[i][j] = (f32x4)(0.0f);
    __builtin_amdgcn_s_setprio(1);
    #pragma unroll
    for (int tt = 0; tt < 4; ++tt) {
      bf16x8 kf[2];
      #pragma unroll
      for (int kk = 0; kk < 2; ++kk) {
        int row = tt * 16 + l15;
        int ks = kk * 4 + kg;
        kf[kk] = *(const bf16x8*)(Ks + row * 64 + ((ks ^ (row & 7)) << 3));
      }
      #pragma unroll
      for (int nq = 0; nq < 2; ++nq)
        #pragma unroll
        for (int kk = 0; kk < 2; ++kk)
          accs[tt][nq] = __builtin_amdgcn_mfma_f32_16x16x32_bf16(
              kf[kk], qf[nq][kk], accs[tt][nq], 0, 0, 0);
    }
    __builtin_amdgcn_s_setprio(0);

    if (E) {
      int kv0 = kvt << 6;
      float* eg = energyOut + ((size_t)g << 20);
      #pragma unroll
      for (int nq = 0; nq < 2; ++nq) {
        int q = qt + wq + nq * 16 + l15;
        #pragma unroll
        for (int tt = 0; tt < 4; ++tt)
          __builtin_nontemporal_store(
              accs[tt][nq], (f32x4*)(eg + (size_t)q * 1024 + kv0 + tt * 16 + kg * 4));
      }
    }

    #pragma unroll
    for (int nq = 0; nq < 2; ++nq) {
      float tmax = -1e30f;
      #pragma unroll
      for (int tt = 0; tt < 4; ++tt)
        #pragma unroll
        for (int r = 0; r < 4; ++r) tmax = fmaxf(tmax, accs[tt][nq][r]);
      tmax *= scale;
      tmax = fmaxf(tmax, __shfl_xor(tmax, 16));
      tmax = fmaxf(tmax, __shfl_xor(tmax, 32));
      float m_new = fmaxf(m_run[nq], tmax);
      float corr = __expf(m_run[nq] - m_new);
      m_run[nq] = m_new;
      int q = wq + nq * 16 + l15;
      float psum = 0.f;
      #pragma unroll
      for (int tt = 0; tt < 4; ++tt) {
        bf16x4 p4;
        #pragma unroll
        for (int r = 0; r < 4; ++r) {
          float p = __expf(accs[tt][nq][r] * scale - m_new);
          psum += p;
          p4[r] = (__bf16)p;
        }
        int kvs = (tt * 16 + kg * 4) ^ ((q & 7) << 3);
        *(bf16x4*)(Psm + q * 64 + kvs) = p4;
      }
      psum += __shfl_xor(psum, 16);
      psum += __shfl_xor(psum, 32);
      l_run[nq] = l_run[nq] * corr + psum;
      if (kg == 0) corr_l[q] = corr;
    }
    // no barrier: Psm / corr_l rows are wave-private

    #pragma unroll
    for (int mq = 0; mq < 2; ++mq) {
      f32x4 c4 = *(const f32x4*)&corr_l[wq + mq * 16 + kg * 4];
      #pragma unroll
      for (int nd = 0; nd < 4; ++nd)
        #pragma unroll
        for (int r = 0; r < 4; ++r) acc_o[mq][nd][r] *= c4[r];
    }
    __builtin_amdgcn_s_setprio(1);
    #pragma unroll
    for (int kk = 0; kk < 2; ++kk) {
      bf16x8 pf[2], vf[4];
      #pragma unroll
      for (int mq = 0; mq < 2; ++mq) {
        int row = wq + mq * 16 + l15;
        int kvs = (kk * 32 + kg * 8) ^ ((row & 7) << 3);
        pf[mq] = *(const bf16x8*)(Psm + row * 64 + kvs);
      }
      #pragma unroll
      for (int nd = 0; nd < 4; ++nd) {
        int vrow = nd * 16 + l15;
        vf[nd] = *(const bf16x8*)(Vs + vrow * 64 + (((kk * 4 + kg) ^ (vrow & 7)) << 3));
      }
      #pragma unroll
      for (int mq = 0; mq < 2; ++mq)
        #pragma unroll
        for (int nd = 0; nd < 4; ++nd)
          acc_o[mq][nd] = __builtin_amdgcn_mfma_f32_16x16x32_bf16(
              pf[mq], vf[nd], acc_o[mq][nd], 0, 0, 0);
    }
    __builtin_amdgcn_s_setprio(0);
    rb = rb == 2 ? 0 : rb + 1;
  }

  #pragma unroll
  for (int nq = 0; nq < 2; ++nq)
    if (kg == 0) l_l[wq + nq * 16 + l15] = l_run[nq];
  __syncthreads();

  #pragma unroll
  for (int mq = 0; mq < 2; ++mq) {
    f32x4 lv = *(const f32x4*)&l_l[wq + mq * 16 + kg * 4];
    #pragma unroll
    for (int nd = 0; nd < 4; ++nd) {
      int col = h * 64 + nd * 16 + l15;
      #pragma unroll
      for (int r = 0; r < 4; ++r) {
        int qrow = qt + wq + mq * 16 + kg * 4 + r;
        Ob[(size_t)(b * 1024 + qrow) * 1024 + col] = (__bf16)(acc_o[mq][nd][r] / lv[r]);
      }
    }
  }
}

// ---------------- GRU cell elementwise, bf16 inputs, 8 elems/thread ----------------
__global__ __launch_bounds__(256) void gru_kernel(
    const __bf16* __restrict__ gi, const __bf16* __restrict__ gh,
    const float* __restrict__ hf, float* __restrict__ qh, __bf16* __restrict__ qhb) {
  size_t e0 = ((size_t)blockIdx.x * 256 + threadIdx.x) * 8;  // over 4M elems
  int row = (int)(e0 >> 10), col = (int)(e0 & 1023);
  size_t base = (size_t)row * 3072 + col;
  bf16x8 vir = *(const bf16x8*)(gi + base);
  bf16x8 viz = *(const bf16x8*)(gi + base + 1024);
  bf16x8 vin = *(const bf16x8*)(gi + base + 2048);
  bf16x8 vhr = *(const bf16x8*)(gh + base);
  bf16x8 vhz = *(const bf16x8*)(gh + base + 1024);
  bf16x8 vhn = *(const bf16x8*)(gh + base + 2048);
  float4 h0 = *(const float4*)(hf + e0);
  float4 h1 = *(const float4*)(hf + e0 + 4);
  float hv[8] = {h0.x, h0.y, h0.z, h0.w, h1.x, h1.y, h1.z, h1.w};
  float q[8];
  #pragma unroll
  for (int j = 0; j < 8; ++j) {
    float r = 1.f / (1.f + __expf(-((float)vir[j] + (float)vhr[j])));
    float z = 1.f / (1.f + __expf(-((float)viz[j] + (float)vhz[j])));
    float n = tanhf((float)vin[j] + r * (float)vhn[j]);
    q[j] = (1.f - z) * n + z * hv[j];
  }
  *(float4*)(qh + e0)     = make_float4(q[0], q[1], q[2], q[3]);
  *(float4*)(qh + e0 + 4) = make_float4(q[4], q[5], q[6], q[7]);
  bf16x8 qb;
  #pragma unroll
  for (int j = 0; j < 8; ++j) qb[j] = (__bf16)q[j];
  *(bf16x8*)(qhb + e0) = qb;
}

extern "C" void kernel_launch(void* const* d_in, const int* in_sizes, int n_in,
                              void* d_out, int out_size, void* d_ws, size_t ws_size,
                              hipStream_t stream) {
  (void)in_sizes; (void)n_in; (void)out_size; (void)ws_size;
  const float* queries   = (const float*)d_in[0];
  const float* contexts  = (const float*)d_in[1];
  const float* qhid      = (const float*)d_in[2];
  const float* sa_norm_w = (const float*)d_in[3];
  const float* sa_norm_b = (const float*)d_in[4];
  const float* sa_qkv_w  = (const float*)d_in[5];
  const float* sa_out_w  = (const float*)d_in[6];
  const float* sa_out_b  = (const float*)d_in[7];
  const float* ca_norm_w = (const float*)d_in[8];
  const float* ca_norm_b = (const float*)d_in[9];
  const float* gru_w_ih  = (const float*)d_in[10];
  const float* gru_w_hh  = (const float*)d_in[11];
  const float* gru_b_ih  = (const float*)d_in[12];
  const float* gru_b_hh  = (const float*)d_in[13];
  const float* ca_k_w    = (const float*)d_in[14];
  const float* ca_v_w    = (const float*)d_in[15];
  const float* ca_out_w  = (const float*)d_in[16];
  const float* ca_out_b  = (const float*)d_in[17];
  const float* ln1_w     = (const float*)d_in[18];
  const float* ln1_b     = (const float*)d_in[19];
  const float* lin1_w    = (const float*)d_in[20];
  const float* ln2_w     = (const float*)d_in[21];
  const float* ln2_b     = (const float*)d_in[22];
  const float* lin2_w    = (const float*)d_in[23];

  float* out0   = (float*)d_out;               // [4096,1024]
  float* energy = out0 + (size_t)4194304;      // [64,1024,1024]
  float* qh_out = out0 + (size_t)71303168;     // [4096,1024]

  // ---- workspace map (units: MM = 1M floats = 4 MiB) ----
  const size_t MM = 1u << 20;
  float* ws = (float*)d_ws;
  float*  X     = ws;
  float*  X2    = ws + 4 * MM;
  __bf16* M1B    = (__bf16*)(ws + 9 * MM);
  __bf16* VT_CA  = (__bf16*)(ws + 13 * MM);  // [4096][1024] bf16 (g-major V^T for CA)
  __bf16* XN_b   = (__bf16*)(ws + 17 * MM);
  __bf16* QHID_b = (__bf16*)(ws + 19 * MM);
  __bf16* CTX_b  = (__bf16*)(ws + 21 * MM);
  __bf16* O_b    = (__bf16*)(ws + 23 * MM);
  __bf16* VT_SA  = (__bf16*)(ws + 25 * MM);  // [4096][1024] bf16 (SA V^T via vtrans)
  __bf16* QKV_b  = (__bf16*)(ws + 27 * MM);
  __bf16* K_b    = (__bf16*)(ws + 27 * MM);  // [4096][1024] bf16, reuses QKV after SA
  __bf16* LN2_b  = (__bf16*)(ws);            // reuses dead X
  __bf16* qkvT   = (__bf16*)(ws + 33 * MM);
  __bf16* ihB    = (__bf16*)(ws + 34 * MM + MM / 2);
  __bf16* hhB    = (__bf16*)(ws + 36 * MM);
  __bf16* kT     = (__bf16*)(ws + 37 * MM + MM / 2);
  __bf16* vT     = (__bf16*)(ws + 38 * MM);
  __bf16* saoT   = (__bf16*)(ws + 38 * MM + MM / 2);
  __bf16* caoT   = (__bf16*)(ws + 39 * MM);
  __bf16* lin1T  = (__bf16*)(ws + 39 * MM + MM / 2);
  __bf16* lin2T  = (__bf16*)(ws + 40 * MM + MM / 2);
  __bf16* GI_b = (__bf16*)energy;            // [4096][3072] bf16 = 24 MB
  __bf16* GH_b = (__bf16*)(energy + 6 * MM); // next 24 MB

  const long long QKV_SB = 1024LL * 3072;

  // ---- fused prep: all weight transposes + casts + ln_sa ----
  prep_all<<<14080, 256, 0, stream>>>(
      sa_qkv_w, ca_k_w, ca_v_w, sa_out_w, ca_out_w, lin1_w, lin2_w,
      gru_w_ih, gru_w_hh, qhid, contexts, queries, sa_norm_w, sa_norm_b,
      qkvT, kT, vT, saoT, caoT, lin1T, lin2T, ihB, hhB, QHID_b, CTX_b, XN_b);

  // ---- SelfAttention (+ CA V^T projection, prep-only dependency) ----
  // qkv: [4096,1024]@qkvT^T -> QKV_b [4096][3072]
  // VTca: per batch b, vT @ CTX_b^T -> VT_CA (row-coalesced V-transpose, no vtrans)
  gemm_dual<<<1024, 256, 0, stream>>>(
      XN_b, 1024, qkvT, 1024, nullptr, QKV_b, 3072, nullptr, nullptr, 1024, 24, 768,
      vT, 1024, CTX_b, 1024, nullptr, VT_CA, 1024, nullptr, nullptr, 1024, 8, 1);
  vtrans<<<dim3(16, 64), 256, 0, stream>>>(QKV_b + 128, QKV_SB, 192, 3072, VT_SA);
  flash_attn<0><<<dim3(8, 64), 256, 0, stream>>>(
      QKV_b, QKV_SB, 192, 3072, QKV_b + 64, QKV_SB, 192, 3072,
      VT_SA, O_b, nullptr, SCALE);
  // sa_out (256 blocks, chain) merged with gh (768 blocks, independent after prep)
  gemm_dual<<<1024, 256, 0, stream>>>(
      O_b, 1024, saoT, 1024, X, nullptr, 1024, sa_out_b, queries, 1024, 8, 256,
      QHID_b, 1024, hhB, 1024, nullptr, GH_b, 3072, gru_b_hh, nullptr, 1024, 24, 0);

  // ---- GRU dynamic query ----
  ln_bf16<1><<<4096, 256, 0, stream>>>(X, nullptr, ca_norm_w, ca_norm_b, XN_b, 0);
  // gi (768 blocks, chain) merged with CA K projection (256 blocks, independent)
  gemm_dual<<<1024, 256, 0, stream>>>(
      XN_b, 1024, ihB, 1024, nullptr, GI_b, 3072, gru_b_ih, nullptr, 1024, 24, 768,
      CTX_b, 1024, kT, 1024, nullptr, K_b, 1024, nullptr, nullptr, 1024, 8, 0);
  gru_kernel<<<2048, 256, 0, stream>>>(GI_b, GH_b, qhid, qh_out, QHID_b /*now QHB*/);

  // ---- Cross attention ----
  flash_attn<1><<<dim3(8, 64), 256, 0, stream>>>(
      QHID_b, 1024LL * 1024, 64, 1024, K_b, 1024LL * 1024, 64, 1024,
      VT_CA, O_b, energy, SCALE);
  gemm_bf16<<<dim3(8, 32), 256, 0, stream>>>(
      O_b, 1024, caoT, 1024, X2, nullptr, 1024, ca_out_b, X, 1024);

  // ---- MLP ----
  ln_bf16<1><<<4096, 256, 0, stream>>>(X2, nullptr, ln1_w, ln1_b, XN_b, 1);
  gemm_bf16<<<dim3(16, 32), 256, 0, stream>>>(
      XN_b, 1024, lin1T, 1024, nullptr, M1B, 2048, nullptr, nullptr, 1024);
  ln_bf16<2><<<4096, 256, 0, stream>>>(nullptr, M1B, ln2_w, ln2_b, LN2_b, 1);
  gemm_bf16<<<dim3(8, 32), 256, 0, stream>>>(
      LN2_b, 2048, lin2T, 2048, out0, nullptr, 1024, nullptr, X2, 2048);
}

// Round 5
// 636.487 us; speedup vs baseline: 1.0352x; 1.0066x over previous
//
#include <hip/hip_runtime.h>
#include <hip/hip_bf16.h>
#include <math.h>

static constexpr float SCALE = 0.03125f; // 1/sqrt(1024)

typedef __attribute__((ext_vector_type(4))) float f32x4;
typedef __attribute__((ext_vector_type(8))) __bf16 bf16x8;
typedef __attribute__((ext_vector_type(4))) __bf16 bf16x4;

__device__ __forceinline__ void g2l16(const void* g, void* l) {
  __builtin_amdgcn_global_load_lds(
      (const __attribute__((address_space(1))) unsigned int*)g,
      (__attribute__((address_space(3))) unsigned int*)l,
      16, 0, 0);
}

// ---------------- fused weight prep: 7 transposes + 4 casts in one launch ----------------
// tile ranges (64x64 wtrans tiles): qkv 0-767 | kT 768-1023 | vT 1024-1279 |
// saoT 1280-1535 | caoT 1536-1791 | lin1T 1792-2303 | lin2T 2304-2815
// casts (2048 elems/block): ihB 2816-4351 | hhB 4352-5887 | qhid 5888-7935 | ctx 7936-9983
__global__ __launch_bounds__(256) void prep_all(
    const float* __restrict__ sa_qkv_w, const float* __restrict__ ca_k_w,
    const float* __restrict__ ca_v_w, const float* __restrict__ sa_out_w,
    const float* __restrict__ ca_out_w, const float* __restrict__ lin1_w,
    const float* __restrict__ lin2_w, const float* __restrict__ gru_w_ih,
    const float* __restrict__ gru_w_hh, const float* __restrict__ qhid,
    const float* __restrict__ contexts,
    __bf16* __restrict__ qkvT, __bf16* __restrict__ kT, __bf16* __restrict__ vT,
    __bf16* __restrict__ saoT, __bf16* __restrict__ caoT, __bf16* __restrict__ lin1T,
    __bf16* __restrict__ lin2T, __bf16* __restrict__ ihB, __bf16* __restrict__ hhB,
    __bf16* __restrict__ qhB, __bf16* __restrict__ ctxB) {
  int bid = blockIdx.x;
  int t = threadIdx.x;
  if (bid >= 2816) {  // casts, 8 elems/thread
    const float* csrc; __bf16* cdst; int cbase;
    if (bid < 4352)      { csrc = gru_w_ih; cdst = ihB;  cbase = 2816; }
    else if (bid < 5888) { csrc = gru_w_hh; cdst = hhB;  cbase = 4352; }
    else if (bid < 7936) { csrc = qhid;     cdst = qhB;  cbase = 5888; }
    else                 { csrc = contexts; cdst = ctxB; cbase = 7936; }
    size_t idx = ((size_t)(bid - cbase) * 256 + t) * 8;
    float4 a = *(const float4*)(csrc + idx);
    float4 b = *(const float4*)(csrc + idx + 4);
    bf16x8 o = {(__bf16)a.x,(__bf16)a.y,(__bf16)a.z,(__bf16)a.w,
                (__bf16)b.x,(__bf16)b.y,(__bf16)b.z,(__bf16)b.w};
    *(bf16x8*)(cdst + idx) = o;
    return;
  }
  const float* src; __bf16* dst; int Kd, N, base;
  if (bid < 768)       { src = sa_qkv_w; dst = qkvT;  Kd = 1024; N = 3072; base = 0; }
  else if (bid < 1024) { src = ca_k_w;   dst = kT;    Kd = 1024; N = 1024; base = 768; }
  else if (bid < 1280) { src = ca_v_w;   dst = vT;    Kd = 1024; N = 1024; base = 1024; }
  else if (bid < 1536) { src = sa_out_w; dst = saoT;  Kd = 1024; N = 1024; base = 1280; }
  else if (bid < 1792) { src = ca_out_w; dst = caoT;  Kd = 1024; N = 1024; base = 1536; }
  else if (bid < 2304) { src = lin1_w;   dst = lin1T; Kd = 1024; N = 2048; base = 1792; }
  else                 { src = lin2_w;   dst = lin2T; Kd = 2048; N = 1024; base = 2304; }
  int tid = bid - base;
  int ntx = N >> 6;
  int n0 = (tid % ntx) * 64, k0 = (tid / ntx) * 64;
  __shared__ float tile[64][65];
  #pragma unroll
  for (int i = 0; i < 16; ++i) {
    int idx = i * 256 + t; int r = idx >> 6, c = idx & 63;
    tile[r][c] = src[(size_t)(k0 + r) * N + n0 + c];
  }
  __syncthreads();
  #pragma unroll
  for (int i = 0; i < 16; ++i) {
    int idx = i * 256 + t; int r = idx >> 6, c = idx & 63;
    dst[(size_t)(n0 + r) * Kd + k0 + c] = (__bf16)tile[c][r];
  }
}

// ---------------- LayerNorm (+ optional SiLU) -> bf16, fp32 or bf16 input ----------------
template <int NV>  // NV = D/1024 (4*NV elems/thread)
__global__ __launch_bounds__(256) void ln_bf16(
    const float* __restrict__ xf, const __bf16* __restrict__ xb,
    const float* __restrict__ w, const float* __restrict__ b,
    __bf16* __restrict__ out, int silu) {
  const int D = NV * 1024;
  int row = blockIdx.x, t = threadIdx.x;
  float vals[NV * 4];
  float s = 0.f, s2 = 0.f;
  #pragma unroll
  for (int i = 0; i < NV; ++i) {
    int c = (i * 256 + t) * 4;
    float4 v;
    if (xf) {
      v = *(const float4*)(xf + (size_t)row * D + c);
    } else {
      bf16x4 vb = *(const bf16x4*)(xb + (size_t)row * D + c);
      v = make_float4((float)vb[0], (float)vb[1], (float)vb[2], (float)vb[3]);
    }
    vals[i*4+0] = v.x; vals[i*4+1] = v.y; vals[i*4+2] = v.z; vals[i*4+3] = v.w;
    s += v.x + v.y + v.z + v.w;
    s2 += v.x*v.x + v.y*v.y + v.z*v.z + v.w*v.w;
  }
  #pragma unroll
  for (int off = 32; off > 0; off >>= 1) {
    s += __shfl_xor(s, off);
    s2 += __shfl_xor(s2, off);
  }
  __shared__ float red[4], red2[4];
  int wv = t >> 6;
  if ((t & 63) == 0) { red[wv] = s; red2[wv] = s2; }
  __syncthreads();
  float S  = red[0] + red[1] + red[2] + red[3];
  float S2 = red2[0] + red2[1] + red2[2] + red2[3];
  float mean = S / D;
  float var = S2 / D - mean * mean;
  float rs = rsqrtf(var + 1e-5f);
  #pragma unroll
  for (int i = 0; i < NV; ++i) {
    int c = (i * 256 + t) * 4;
    bf16x4 o;
    #pragma unroll
    for (int j = 0; j < 4; ++j) {
      float v = (vals[i*4+j] - mean) * rs * w[c+j] + b[c+j];
      if (silu) v = v / (1.f + __expf(-v));
      o[j] = (__bf16)v;
    }
    *(bf16x4*)(out + (size_t)row * D + c) = o;
  }
}

// ---------------- bf16 MFMA GEMM core, 2-buffer stage-early/drain-late pipeline ----------
// C[M,N] = A[M,K] @ B^T; B stored [N][K]. Tile 128x128, BK=64, 4 waves.
// Per K-step: STAGE(next buf) -> COMPUTE(cur buf) -> vmcnt(0) -> s_barrier.
// Requires K % 128 == 0 (all call sites).
__device__ __forceinline__ void gemm_body(
    const __bf16* __restrict__ A, long long lda,
    const __bf16* __restrict__ B, long long ldb,
    float* __restrict__ outF, __bf16* __restrict__ outB, long long ldc,
    const float* __restrict__ bias, const float* __restrict__ res,
    int K, int bm, int bn) {
  __shared__ __bf16 Asm0[8192];
  __shared__ __bf16 Bsm0[8192];
  __shared__ __bf16 Asm1[8192];
  __shared__ __bf16 Bsm1[8192];
  int t = threadIdx.x;
  int lane = t & 63, w = t >> 6;
  int l15 = lane & 15, kg = lane >> 4;
  int wm = (w >> 1) * 64, wn = (w & 1) * 64;

  f32x4 acc[4][4];
  #pragma unroll
  for (int i = 0; i < 4; ++i)
    #pragma unroll
    for (int j = 0; j < 4; ++j) acc[i][j] = (f32x4)(0.0f);

  const __bf16* ga[4]; const __bf16* gb[4];
  int lo[4];
  #pragma unroll
  for (int i = 0; i < 4; ++i) {
    int slot = i * 256 + t;
    int row = slot >> 3, s = slot & 7;
    int sx = s ^ (row & 7);
    ga[i] = A + (size_t)(bm + row) * lda + (sx << 3);
    gb[i] = B + (size_t)(bn + row) * ldb + (sx << 3);
    lo[i] = (i * 256 + w * 64) << 3;
  }

  auto STAGE = [&](__bf16* As, __bf16* Bs, int k0) {
    #pragma unroll
    for (int i = 0; i < 4; ++i) g2l16(ga[i] + k0, As + lo[i]);
    #pragma unroll
    for (int i = 0; i < 4; ++i) g2l16(gb[i] + k0, Bs + lo[i]);
  };
  auto COMPUTE = [&](const __bf16* As, const __bf16* Bs) {
    #pragma unroll
    for (int kk = 0; kk < 2; ++kk) {
      bf16x8 af[4], bfr[4];
      #pragma unroll
      for (int mi = 0; mi < 4; ++mi) {
        int row = wm + mi * 16 + l15;
        int ks = kk * 4 + kg;
        af[mi] = *(const bf16x8*)(As + row * 64 + ((ks ^ (row & 7)) << 3));
      }
      #pragma unroll
      for (int ni = 0; ni < 4; ++ni) {
        int row = wn + ni * 16 + l15;
        int ks = kk * 4 + kg;
        bfr[ni] = *(const bf16x8*)(Bs + row * 64 + ((ks ^ (row & 7)) << 3));
      }
      #pragma unroll
      for (int mi = 0; mi < 4; ++mi)
        #pragma unroll
        for (int ni = 0; ni < 4; ++ni)
          acc[mi][ni] = __builtin_amdgcn_mfma_f32_16x16x32_bf16(
              af[mi], bfr[ni], acc[mi][ni], 0, 0, 0);
    }
  };
  #define GEMM_SYNC() do { \
    asm volatile("s_waitcnt vmcnt(0)" ::: "memory"); \
    __builtin_amdgcn_s_barrier(); \
    __builtin_amdgcn_sched_barrier(0); \
  } while (0)

  STAGE(Asm0, Bsm0, 0);
  GEMM_SYNC();
  int nk = K >> 6;  // even
  for (int kt = 0; kt + 2 < nk; kt += 2) {
    STAGE(Asm1, Bsm1, (kt + 1) << 6);
    COMPUTE(Asm0, Bsm0);
    GEMM_SYNC();
    STAGE(Asm0, Bsm0, (kt + 2) << 6);
    COMPUTE(Asm1, Bsm1);
    GEMM_SYNC();
  }
  // tail: tiles nk-2 (in buf0), nk-1
  STAGE(Asm1, Bsm1, (nk - 1) << 6);
  COMPUTE(Asm0, Bsm0);
  GEMM_SYNC();
  COMPUTE(Asm1, Bsm1);
  #undef GEMM_SYNC

  #pragma unroll
  for (int mi = 0; mi < 4; ++mi) {
    #pragma unroll
    for (int ni = 0; ni < 4; ++ni) {
      int rbase = bm + wm + mi * 16 + kg * 4;
      int c = bn + wn + ni * 16 + l15;
      #pragma unroll
      for (int r = 0; r < 4; ++r) {
        float val = acc[mi][ni][r];
        if (bias) val += bias[c];
        size_t off = (size_t)(rbase + r) * ldc + c;
        if (res) val += res[off];
        if (outF) outF[off] = val;
        if (outB) outB[off] = (__bf16)val;
      }
    }
  }
}

// Single-GEMM kernel (2D grid, XCD-aware swizzle; nwg divisible by 8 at all call sites).
__global__ __launch_bounds__(256) void gemm_bf16(
    const __bf16* __restrict__ A, long long lda,
    const __bf16* __restrict__ B, long long ldb,
    float* __restrict__ outF, __bf16* __restrict__ outB, long long ldc,
    const float* __restrict__ bias, const float* __restrict__ res, int K) {
  int nwg = gridDim.x * gridDim.y;
  int orig = blockIdx.y * gridDim.x + blockIdx.x;
  int swz = (orig & 7) * (nwg >> 3) + (orig >> 3);
  gemm_body(A, lda, B, ldb, outF, outB, ldc, bias, res, K,
            (swz / gridDim.x) * 128, (swz % gridDim.x) * 128);
}

// Dual-GEMM kernel: two independent GEMMs in one launch (1D grid, blocks < nb0 -> p0).
// Fills the machine when one GEMM alone has <2 blocks/CU. nb0 and nb1 divisible by 8.
__global__ __launch_bounds__(256) void gemm_dual(
    const __bf16* __restrict__ A0, long long lda0, const __bf16* __restrict__ B0, long long ldb0,
    float* __restrict__ oF0, __bf16* __restrict__ oB0, long long ldc0,
    const float* __restrict__ bias0, const float* __restrict__ res0, int K0, int gx0, int nb0,
    const __bf16* __restrict__ A1, long long lda1, const __bf16* __restrict__ B1, long long ldb1,
    float* __restrict__ oF1, __bf16* __restrict__ oB1, long long ldc1,
    const float* __restrict__ bias1, const float* __restrict__ res1, int K1, int gx1) {
  int bid = blockIdx.x;
  if (bid < nb0) {
    int swz = (bid & 7) * (nb0 >> 3) + (bid >> 3);
    gemm_body(A0, lda0, B0, ldb0, oF0, oB0, ldc0, bias0, res0, K0,
              (swz / gx0) * 128, (swz % gx0) * 128);
  } else {
    int b = bid - nb0;
    int nb1 = gridDim.x - nb0;
    int swz = (b & 7) * (nb1 >> 3) + (b >> 3);
    gemm_body(A1, lda1, B1, ldb1, oF1, oB1, ldc1, bias1, res1, K1,
              (swz / gx1) * 128, (swz % gx1) * 128);
  }
}

// ---------------- V transpose: V[b,k,h,d](bf16) -> VT[g][d][1024 k] ----------------
__global__ __launch_bounds__(256) void vtrans(
    const __bf16* __restrict__ V, long long v_sb, long long v_sh, int v_sm,
    __bf16* __restrict__ VT) {
  __shared__ __bf16 tile[64][72];
  int g = blockIdx.y, b = g >> 4, h = g & 15;
  int k0 = blockIdx.x * 64;
  const __bf16* Vb = V + (size_t)b * v_sb + (size_t)h * v_sh;
  int t = threadIdx.x;
  #pragma unroll
  for (int i = 0; i < 2; ++i) {
    int idx = i * 256 + t;
    int k = idx >> 3, dc = (idx & 7) * 8;
    bf16x8 v = *(const bf16x8*)(Vb + (size_t)(k0 + k) * v_sm + dc);
    #pragma unroll
    for (int j = 0; j < 8; ++j) tile[dc + j][k] = v[j];
  }
  __syncthreads();
  #pragma unroll
  for (int i = 0; i < 2; ++i) {
    int idx = i * 256 + t;
    int d = idx >> 3, kc = (idx & 7) * 8;
    bf16x8 v;
    #pragma unroll
    for (int j = 0; j < 8; ++j) v[j] = tile[d][kc + j];
    *(bf16x8*)(VT + ((size_t)g * 64 + d) * 1024 + k0 + kc) = v;
  }
}

// ---------------- Fused flash attention, 3-deep pipelined K/V staging ----------------
// Per g=(b,h): O[q][d] = softmax_kv(S*scale) @ V, S = Q @ K^T (head dim 64).
// Swapped QK^T -> S^T acc (col=q=l15). P -> LDS packed bf16x4, XOR-swizzled.
// Grid is dim3(64, 8): blockIdx.x = head g, blockIdx.y = q-tile. Linear block id
// = qt*64 + g, so XCD = g % 8 -> ALL q-tiles of a head share one XCD and its L2
// holds that head's K/V once (8 heads x 256 KB = 2 MB per L2). The previous
// (8,64) grid spread each head's q-tiles across all 8 XCDs (8x L2 fill traffic).
template <int E>
__global__ __launch_bounds__(256) void flash_attn(
    const __bf16* __restrict__ Qb, long long q_sb, long long q_sh, int q_sm,
    const __bf16* __restrict__ Kb, long long k_sb, long long k_sh, int k_sm,
    const __bf16* __restrict__ VT, __bf16* __restrict__ Ob,
    float* __restrict__ energyOut, float scale) {
  __shared__ __bf16 Ksm[3][4096];
  __shared__ __bf16 Vsm[3][4096];
  __shared__ __bf16 Psm[128 * 64];
  __shared__ float corr_l[128];
  __shared__ float l_l[128];
  int g = blockIdx.x, b = g >> 4, h = g & 15;
  int qt = blockIdx.y * 128;
  const __bf16* Qg = Qb + (size_t)b * q_sb + (size_t)h * q_sh;
  const __bf16* Kg = Kb + (size_t)b * k_sb + (size_t)h * k_sh;
  const __bf16* Vg = VT + (size_t)g * 65536;
  int t = threadIdx.x, lane = t & 63, w = t >> 6;
  int l15 = lane & 15, kg = lane >> 4;
  int wq = w * 32;

  bf16x8 qf[2][2];
  #pragma unroll
  for (int nq = 0; nq < 2; ++nq)
    #pragma unroll
    for (int kk = 0; kk < 2; ++kk)
      qf[nq][kk] = *(const bf16x8*)(
          Qg + (size_t)(qt + wq + nq * 16 + l15) * q_sm + kk * 32 + kg * 8);

  f32x4 acc_o[2][4];
  #pragma unroll
  for (int i = 0; i < 2; ++i)
    #pragma unroll
    for (int j = 0; j < 4; ++j) acc_o[i][j] = (f32x4)(0.0f);
  float m_run[2] = {-1e30f, -1e30f};
  float l_run[2] = {0.f, 0.f};

  const __bf16* gK[2]; const __bf16* gV[2];
  int lo[2];
  #pragma unroll
  for (int i = 0; i < 2; ++i) {
    int slot = i * 256 + t;
    int row = slot >> 3, s = slot & 7, sx = s ^ (row & 7);
    gK[i] = Kg + (size_t)row * k_sm + (sx << 3);
    gV[i] = Vg + (size_t)row * 1024 + (sx << 3);
    lo[i] = (i * 256 + w * 64) << 3;
  }

  // prologue: stage tile 0 (4 oldest vmem ops) then tile 1
  #pragma unroll
  for (int i = 0; i < 2; ++i) g2l16(gK[i], &Ksm[0][lo[i]]);
  #pragma unroll
  for (int i = 0; i < 2; ++i) g2l16(gV[i], &Vsm[0][lo[i]]);
  #pragma unroll
  for (int i = 0; i < 2; ++i) g2l16(gK[i] + (size_t)64 * k_sm, &Ksm[1][lo[i]]);
  #pragma unroll
  for (int i = 0; i < 2; ++i) g2l16(gV[i] + 64, &Vsm[1][lo[i]]);

  int rb = 0;  // read buffer = kvt % 3
  for (int kvt = 0; kvt < 16; ++kvt) {
    // counted wait: exactly the newer-than-stage-kvt op count (4 loads/tile, 8 stores/tile if E)
    if (E) {
      if (kvt == 0)       asm volatile("s_waitcnt vmcnt(4)" ::: "memory");
      else if (kvt == 1)  asm volatile("s_waitcnt vmcnt(12)" ::: "memory");
      else if (kvt == 15) asm volatile("s_waitcnt vmcnt(16)" ::: "memory");
      else                asm volatile("s_waitcnt vmcnt(20)" ::: "memory");
    } else {
      if (kvt == 15)      asm volatile("s_waitcnt vmcnt(0)" ::: "memory");
      else                asm volatile("s_waitcnt vmcnt(4)" ::: "memory");
    }
    __builtin_amdgcn_s_barrier();
    __builtin_amdgcn_sched_barrier(0);  // pin: no memory op crosses the barrier

    if (kvt < 14) {  // stage tile kvt+2 (after barrier: all waves done reading that buffer)
      int sbuf = rb >= 1 ? rb - 1 : rb + 2;  // (kvt+2)%3
      size_t ko = (size_t)(kvt + 2) << 6;
      #pragma unroll
      for (int i = 0; i < 2; ++i) g2l16(gK[i] + ko * k_sm, &Ksm[sbuf][lo[i]]);
      #pragma unroll
      for (int i = 0; i < 2; ++i) g2l16(gV[i] + ko, &Vsm[sbuf][lo[i]]);
    }
    const __bf16* Ks = Ksm[rb];
    const __bf16* Vs = Vsm[rb];

    f32x4 accs[4][2];
    #pragma unroll
    for (int i = 0; i < 4; ++i)
      #pragma unroll
      for (int j = 0; j < 2; ++j) accs[i][j] = (f32x4)(0.0f);
    __builtin_amdgcn_s_setprio(1);
    #pragma unroll
    for (int tt = 0; tt < 4; ++tt) {
      bf16x8 kf[2];
      #pragma unroll
      for (int kk = 0; kk < 2; ++kk) {
        int row = tt * 16 + l15;
        int ks = kk * 4 + kg;
        kf[kk] = *(const bf16x8*)(Ks + row * 64 + ((ks ^ (row & 7)) << 3));
      }
      #pragma unroll
      for (int nq = 0; nq < 2; ++nq)
        #pragma unroll
        for (int kk = 0; kk < 2; ++kk)
          accs[tt][nq] = __builtin_amdgcn_mfma_f32_16x16x32_bf16(
              kf[kk], qf[nq][kk], accs[tt][nq], 0, 0, 0);
    }
    __builtin_amdgcn_s_setprio(0);

    if (E) {
      int kv0 = kvt << 6;
      float* eg = energyOut + ((size_t)g << 20);
      #pragma unroll
      for (int nq = 0; nq < 2; ++nq) {
        int q = qt + wq + nq * 16 + l15;
        #pragma unroll
        for (int tt = 0; tt < 4; ++tt)
          __builtin_nontemporal_store(
              accs[tt][nq], (f32x4*)(eg + (size_t)q * 1024 + kv0 + tt * 16 + kg * 4));
      }
    }

    #pragma unroll
    for (int nq = 0; nq < 2; ++nq) {
      float tmax = -1e30f;
      #pragma unroll
      for (int tt = 0; tt < 4; ++tt)
        #pragma unroll
        for (int r = 0; r < 4; ++r) tmax = fmaxf(tmax, accs[tt][nq][r]);
      tmax *= scale;
      tmax = fmaxf(tmax, __shfl_xor(tmax, 16));
      tmax = fmaxf(tmax, __shfl_xor(tmax, 32));
      float m_new = fmaxf(m_run[nq], tmax);
      float corr = __expf(m_run[nq] - m_new);
      m_run[nq] = m_new;
      int q = wq + nq * 16 + l15;
      float psum = 0.f;
      #pragma unroll
      for (int tt = 0; tt < 4; ++tt) {
        bf16x4 p4;
        #pragma unroll
        for (int r = 0; r < 4; ++r) {
          float p = __expf(accs[tt][nq][r] * scale - m_new);
          psum += p;
          p4[r] = (__bf16)p;
        }
        int kvs = (tt * 16 + kg * 4) ^ ((q & 7) << 3);
        *(bf16x4*)(Psm + q * 64 + kvs) = p4;
      }
      psum += __shfl_xor(psum, 16);
      psum += __shfl_xor(psum, 32);
      l_run[nq] = l_run[nq] * corr + psum;
      if (kg == 0) corr_l[q] = corr;
    }
    // no barrier: Psm / corr_l rows are wave-private

    #pragma unroll
    for (int mq = 0; mq < 2; ++mq) {
      f32x4 c4 = *(const f32x4*)&corr_l[wq + mq * 16 + kg * 4];
      #pragma unroll
      for (int nd = 0; nd < 4; ++nd)
        #pragma unroll
        for (int r = 0; r < 4; ++r) acc_o[mq][nd][r] *= c4[r];
    }
    __builtin_amdgcn_s_setprio(1);
    #pragma unroll
    for (int kk = 0; kk < 2; ++kk) {
      bf16x8 pf[2], vf[4];
      #pragma unroll
      for (int mq = 0; mq < 2; ++mq) {
        int row = wq + mq * 16 + l15;
        int kvs = (kk * 32 + kg * 8) ^ ((row & 7) << 3);
        pf[mq] = *(const bf16x8*)(Psm + row * 64 + kvs);
      }
      #pragma unroll
      for (int nd = 0; nd < 4; ++nd) {
        int vrow = nd * 16 + l15;
        vf[nd] = *(const bf16x8*)(Vs + vrow * 64 + (((kk * 4 + kg) ^ (vrow & 7)) << 3));
      }
      #pragma unroll
      for (int mq = 0; mq < 2; ++mq)
        #pragma unroll
        for (int nd = 0; nd < 4; ++nd)
          acc_o[mq][nd] = __builtin_amdgcn_mfma_f32_16x16x32_bf16(
              pf[mq], vf[nd], acc_o[mq][nd], 0, 0, 0);
    }
    __builtin_amdgcn_s_setprio(0);
    rb = rb == 2 ? 0 : rb + 1;
  }

  #pragma unroll
  for (int nq = 0; nq < 2; ++nq)
    if (kg == 0) l_l[wq + nq * 16 + l15] = l_run[nq];
  __syncthreads();

  #pragma unroll
  for (int mq = 0; mq < 2; ++mq) {
    f32x4 lv = *(const f32x4*)&l_l[wq + mq * 16 + kg * 4];
    #pragma unroll
    for (int nd = 0; nd < 4; ++nd) {
      int col = h * 64 + nd * 16 + l15;
      #pragma unroll
      for (int r = 0; r < 4; ++r) {
        int qrow = qt + wq + mq * 16 + kg * 4 + r;
        Ob[(size_t)(b * 1024 + qrow) * 1024 + col] = (__bf16)(acc_o[mq][nd][r] / lv[r]);
      }
    }
  }
}

// ---------------- GRU cell elementwise, bf16 inputs, 8 elems/thread ----------------
__global__ __launch_bounds__(256) void gru_kernel(
    const __bf16* __restrict__ gi, const __bf16* __restrict__ gh,
    const float* __restrict__ hf, float* __restrict__ qh, __bf16* __restrict__ qhb) {
  size_t e0 = ((size_t)blockIdx.x * 256 + threadIdx.x) * 8;  // over 4M elems
  int row = (int)(e0 >> 10), col = (int)(e0 & 1023);
  size_t base = (size_t)row * 3072 + col;
  bf16x8 vir = *(const bf16x8*)(gi + base);
  bf16x8 viz = *(const bf16x8*)(gi + base + 1024);
  bf16x8 vin = *(const bf16x8*)(gi + base + 2048);
  bf16x8 vhr = *(const bf16x8*)(gh + base);
  bf16x8 vhz = *(const bf16x8*)(gh + base + 1024);
  bf16x8 vhn = *(const bf16x8*)(gh + base + 2048);
  float4 h0 = *(const float4*)(hf + e0);
  float4 h1 = *(const float4*)(hf + e0 + 4);
  float hv[8] = {h0.x, h0.y, h0.z, h0.w, h1.x, h1.y, h1.z, h1.w};
  float q[8];
  #pragma unroll
  for (int j = 0; j < 8; ++j) {
    float r = 1.f / (1.f + __expf(-((float)vir[j] + (float)vhr[j])));
    float z = 1.f / (1.f + __expf(-((float)viz[j] + (float)vhz[j])));
    float n = tanhf((float)vin[j] + r * (float)vhn[j]);
    q[j] = (1.f - z) * n + z * hv[j];
  }
  *(float4*)(qh + e0)     = make_float4(q[0], q[1], q[2], q[3]);
  *(float4*)(qh + e0 + 4) = make_float4(q[4], q[5], q[6], q[7]);
  bf16x8 qb;
  #pragma unroll
  for (int j = 0; j < 8; ++j) qb[j] = (__bf16)q[j];
  *(bf16x8*)(qhb + e0) = qb;
}

extern "C" void kernel_launch(void* const* d_in, const int* in_sizes, int n_in,
                              void* d_out, int out_size, void* d_ws, size_t ws_size,
                              hipStream_t stream) {
  (void)in_sizes; (void)n_in; (void)out_size; (void)ws_size;
  const float* queries   = (const float*)d_in[0];
  const float* contexts  = (const float*)d_in[1];
  const float* qhid      = (const float*)d_in[2];
  const float* sa_norm_w = (const float*)d_in[3];
  const float* sa_norm_b = (const float*)d_in[4];
  const float* sa_qkv_w  = (const float*)d_in[5];
  const float* sa_out_w  = (const float*)d_in[6];
  const float* sa_out_b  = (const float*)d_in[7];
  const float* ca_norm_w = (const float*)d_in[8];
  const float* ca_norm_b = (const float*)d_in[9];
  const float* gru_w_ih  = (const float*)d_in[10];
  const float* gru_w_hh  = (const float*)d_in[11];
  const float* gru_b_ih  = (const float*)d_in[12];
  const float* gru_b_hh  = (const float*)d_in[13];
  const float* ca_k_w    = (const float*)d_in[14];
  const float* ca_v_w    = (const float*)d_in[15];
  const float* ca_out_w  = (const float*)d_in[16];
  const float* ca_out_b  = (const float*)d_in[17];
  const float* ln1_w     = (const float*)d_in[18];
  const float* ln1_b     = (const float*)d_in[19];
  const float* lin1_w    = (const float*)d_in[20];
  const float* ln2_w     = (const float*)d_in[21];
  const float* ln2_b     = (const float*)d_in[22];
  const float* lin2_w    = (const float*)d_in[23];

  float* out0   = (float*)d_out;               // [4096,1024]
  float* energy = out0 + (size_t)4194304;      // [64,1024,1024]
  float* qh_out = out0 + (size_t)71303168;     // [4096,1024]

  // ---- workspace map (units: MM = 1M floats = 4 MiB) ----
  const size_t MM = 1u << 20;
  float* ws = (float*)d_ws;
  float*  X     = ws;
  float*  X2    = ws + 4 * MM;
  __bf16* M1B    = (__bf16*)(ws + 9 * MM);
  __bf16* XN_b   = (__bf16*)(ws + 17 * MM);
  __bf16* QHID_b = (__bf16*)(ws + 19 * MM);
  __bf16* CTX_b  = (__bf16*)(ws + 21 * MM);
  __bf16* O_b    = (__bf16*)(ws + 23 * MM);
  __bf16* VT_b   = (__bf16*)(ws + 25 * MM);
  __bf16* QKV_b  = (__bf16*)(ws + 27 * MM);
  __bf16* KV_b   = (__bf16*)(ws + 27 * MM);  // [4096][2048] bf16, reuses QKV after SA
  __bf16* LN2_b  = (__bf16*)(ws);            // reuses dead X
  __bf16* qkvT   = (__bf16*)(ws + 33 * MM);
  __bf16* ihB    = (__bf16*)(ws + 34 * MM + MM / 2);
  __bf16* hhB    = (__bf16*)(ws + 36 * MM);
  __bf16* kT     = (__bf16*)(ws + 37 * MM + MM / 2);  // kT,vT contiguous => merged B [2048][1024]
  __bf16* vT     = (__bf16*)(ws + 38 * MM);
  __bf16* saoT   = (__bf16*)(ws + 38 * MM + MM / 2);
  __bf16* caoT   = (__bf16*)(ws + 39 * MM);
  __bf16* lin1T  = (__bf16*)(ws + 39 * MM + MM / 2);
  __bf16* lin2T  = (__bf16*)(ws + 40 * MM + MM / 2);
  __bf16* GI_b = (__bf16*)energy;            // [4096][3072] bf16 = 24 MB
  __bf16* GH_b = (__bf16*)(energy + 6 * MM); // next 24 MB

  const long long QKV_SB = 1024LL * 3072;
  const long long KV_SB  = 1024LL * 2048;

  // ---- fused prep: all weight transposes + casts ----
  prep_all<<<9984, 256, 0, stream>>>(
      sa_qkv_w, ca_k_w, ca_v_w, sa_out_w, ca_out_w, lin1_w, lin2_w,
      gru_w_ih, gru_w_hh, qhid, contexts,
      qkvT, kT, vT, saoT, caoT, lin1T, lin2T, ihB, hhB, QHID_b, CTX_b);

  // ---- SelfAttention ----
  ln_bf16<1><<<4096, 256, 0, stream>>>(queries, nullptr, sa_norm_w, sa_norm_b, XN_b, 0);
  gemm_bf16<<<dim3(24, 32), 256, 0, stream>>>(
      XN_b, 1024, qkvT, 1024, nullptr, QKV_b, 3072, nullptr, nullptr, 1024);
  vtrans<<<dim3(16, 64), 256, 0, stream>>>(QKV_b + 128, QKV_SB, 192, 3072, VT_b);
  flash_attn<0><<<dim3(64, 8), 256, 0, stream>>>(
      QKV_b, QKV_SB, 192, 3072, QKV_b + 64, QKV_SB, 192, 3072,
      VT_b, O_b, nullptr, SCALE);
  // sa_out (256 blocks, chain) merged with gh (768 blocks, independent after prep)
  gemm_dual<<<1024, 256, 0, stream>>>(
      O_b, 1024, saoT, 1024, X, nullptr, 1024, sa_out_b, queries, 1024, 8, 256,
      QHID_b, 1024, hhB, 1024, nullptr, GH_b, 3072, gru_b_hh, nullptr, 1024, 24);

  // ---- GRU dynamic query ----
  ln_bf16<1><<<4096, 256, 0, stream>>>(X, nullptr, ca_norm_w, ca_norm_b, XN_b, 0);
  // gi (768 blocks, chain) merged with CA kv projection (512 blocks, independent)
  gemm_dual<<<1280, 256, 0, stream>>>(
      XN_b, 1024, ihB, 1024, nullptr, GI_b, 3072, gru_b_ih, nullptr, 1024, 24, 768,
      CTX_b, 1024, kT, 1024, nullptr, KV_b, 2048, nullptr, nullptr, 1024, 16);
  gru_kernel<<<2048, 256, 0, stream>>>(GI_b, GH_b, qhid, qh_out, QHID_b /*now QHB*/);

  // ---- Cross attention ----
  vtrans<<<dim3(16, 64), 256, 0, stream>>>(KV_b + 1024, KV_SB, 64, 2048, VT_b);
  flash_attn<1><<<dim3(64, 8), 256, 0, stream>>>(
      QHID_b, 1024LL * 1024, 64, 1024, KV_b, KV_SB, 64, 2048,
      VT_b, O_b, energy, SCALE);
  gemm_bf16<<<dim3(8, 32), 256, 0, stream>>>(
      O_b, 1024, caoT, 1024, X2, nullptr, 1024, ca_out_b, X, 1024);

  // ---- MLP ----
  ln_bf16<1><<<4096, 256, 0, stream>>>(X2, nullptr, ln1_w, ln1_b, XN_b, 1);
  gemm_bf16<<<dim3(16, 32), 256, 0, stream>>>(
      XN_b, 1024, lin1T, 1024, nullptr, M1B, 2048, nullptr, nullptr, 1024);
  ln_bf16<2><<<4096, 256, 0, stream>>>(nullptr, M1B, ln2_w, ln2_b, LN2_b, 1);
  gemm_bf16<<<dim3(8, 32), 256, 0, stream>>>(
      LN2_b, 2048, lin2T, 2048, out0, nullptr, 1024, nullptr, X2, 2048);
}

// Round 6
// 616.967 us; speedup vs baseline: 1.0679x; 1.0316x over previous
//
#include <hip/hip_runtime.h>
#include <hip/hip_bf16.h>
#include <math.h>

static constexpr float SCALE = 0.03125f; // 1/sqrt(1024)

typedef __attribute__((ext_vector_type(4))) float f32x4;
typedef __attribute__((ext_vector_type(8))) __bf16 bf16x8;
typedef __attribute__((ext_vector_type(4))) __bf16 bf16x4;

__device__ __forceinline__ void g2l16(const void* g, void* l) {
  __builtin_amdgcn_global_load_lds(
      (const __attribute__((address_space(1))) unsigned int*)g,
      (__attribute__((address_space(3))) unsigned int*)l,
      16, 0, 0);
}

// ---------------- fused weight prep: 7 transposes + 4 casts + ln_sa in one launch --------
// tile ranges (64x64 wtrans tiles): qkv 0-767 | kT 768-1023 | vT 1024-1279 |
// saoT 1280-1535 | caoT 1536-1791 | lin1T 1792-2303 | lin2T 2304-2815
// casts (2048 elems/block): ihB 2816-4351 | hhB 4352-5887 | qhid 5888-7935 | ctx 7936-9983
// ln_sa rows: 9984-14079 (reads only the `queries` input -> independent of the rest)
__global__ __launch_bounds__(256) void prep_all(
    const float* __restrict__ sa_qkv_w, const float* __restrict__ ca_k_w,
    const float* __restrict__ ca_v_w, const float* __restrict__ sa_out_w,
    const float* __restrict__ ca_out_w, const float* __restrict__ lin1_w,
    const float* __restrict__ lin2_w, const float* __restrict__ gru_w_ih,
    const float* __restrict__ gru_w_hh, const float* __restrict__ qhid,
    const float* __restrict__ contexts,
    const float* __restrict__ queries, const float* __restrict__ sa_norm_w,
    const float* __restrict__ sa_norm_b,
    __bf16* __restrict__ qkvT, __bf16* __restrict__ kT, __bf16* __restrict__ vT,
    __bf16* __restrict__ saoT, __bf16* __restrict__ caoT, __bf16* __restrict__ lin1T,
    __bf16* __restrict__ lin2T, __bf16* __restrict__ ihB, __bf16* __restrict__ hhB,
    __bf16* __restrict__ qhB, __bf16* __restrict__ ctxB, __bf16* __restrict__ xnB) {
  int bid = blockIdx.x;
  int t = threadIdx.x;
  if (bid >= 9984) {  // ---- LayerNorm(queries) -> xnB, D=1024 ----
    int row = bid - 9984;
    int c = t * 4;
    float4 v = *(const float4*)(queries + (size_t)row * 1024 + c);
    float s = v.x + v.y + v.z + v.w;
    float s2 = v.x*v.x + v.y*v.y + v.z*v.z + v.w*v.w;
    #pragma unroll
    for (int off = 32; off > 0; off >>= 1) {
      s += __shfl_xor(s, off);
      s2 += __shfl_xor(s2, off);
    }
    __shared__ float red[4], red2[4];
    int wv = t >> 6;
    if ((t & 63) == 0) { red[wv] = s; red2[wv] = s2; }
    __syncthreads();
    float S  = red[0] + red[1] + red[2] + red[3];
    float S2 = red2[0] + red2[1] + red2[2] + red2[3];
    float mean = S / 1024.f;
    float var = S2 / 1024.f - mean * mean;
    float rs = rsqrtf(var + 1e-5f);
    float vv[4] = {v.x, v.y, v.z, v.w};
    bf16x4 o;
    #pragma unroll
    for (int j = 0; j < 4; ++j)
      o[j] = (__bf16)((vv[j] - mean) * rs * sa_norm_w[c+j] + sa_norm_b[c+j]);
    *(bf16x4*)(xnB + (size_t)row * 1024 + c) = o;
    return;
  }
  if (bid >= 2816) {  // casts, 8 elems/thread
    const float* csrc; __bf16* cdst; int cbase;
    if (bid < 4352)      { csrc = gru_w_ih; cdst = ihB;  cbase = 2816; }
    else if (bid < 5888) { csrc = gru_w_hh; cdst = hhB;  cbase = 4352; }
    else if (bid < 7936) { csrc = qhid;     cdst = qhB;  cbase = 5888; }
    else                 { csrc = contexts; cdst = ctxB; cbase = 7936; }
    size_t idx = ((size_t)(bid - cbase) * 256 + t) * 8;
    float4 a = *(const float4*)(csrc + idx);
    float4 b = *(const float4*)(csrc + idx + 4);
    bf16x8 o = {(__bf16)a.x,(__bf16)a.y,(__bf16)a.z,(__bf16)a.w,
                (__bf16)b.x,(__bf16)b.y,(__bf16)b.z,(__bf16)b.w};
    *(bf16x8*)(cdst + idx) = o;
    return;
  }
  const float* src; __bf16* dst; int Kd, N, base;
  if (bid < 768)       { src = sa_qkv_w; dst = qkvT;  Kd = 1024; N = 3072; base = 0; }
  else if (bid < 1024) { src = ca_k_w;   dst = kT;    Kd = 1024; N = 1024; base = 768; }
  else if (bid < 1280) { src = ca_v_w;   dst = vT;    Kd = 1024; N = 1024; base = 1024; }
  else if (bid < 1536) { src = sa_out_w; dst = saoT;  Kd = 1024; N = 1024; base = 1280; }
  else if (bid < 1792) { src = ca_out_w; dst = caoT;  Kd = 1024; N = 1024; base = 1536; }
  else if (bid < 2304) { src = lin1_w;   dst = lin1T; Kd = 1024; N = 2048; base = 1792; }
  else                 { src = lin2_w;   dst = lin2T; Kd = 2048; N = 1024; base = 2304; }
  int tid = bid - base;
  int ntx = N >> 6;
  int n0 = (tid % ntx) * 64, k0 = (tid / ntx) * 64;
  __shared__ float tile[64][65];
  #pragma unroll
  for (int i = 0; i < 16; ++i) {
    int idx = i * 256 + t; int r = idx >> 6, c = idx & 63;
    tile[r][c] = src[(size_t)(k0 + r) * N + n0 + c];
  }
  __syncthreads();
  #pragma unroll
  for (int i = 0; i < 16; ++i) {
    int idx = i * 256 + t; int r = idx >> 6, c = idx & 63;
    dst[(size_t)(n0 + r) * Kd + k0 + c] = (__bf16)tile[c][r];
  }
}

// ---------------- LayerNorm (+ optional SiLU) -> bf16, fp32 or bf16 input ----------------
template <int NV>  // NV = D/1024 (4*NV elems/thread)
__global__ __launch_bounds__(256) void ln_bf16(
    const float* __restrict__ xf, const __bf16* __restrict__ xb,
    const float* __restrict__ w, const float* __restrict__ b,
    __bf16* __restrict__ out, int silu) {
  const int D = NV * 1024;
  int row = blockIdx.x, t = threadIdx.x;
  float vals[NV * 4];
  float s = 0.f, s2 = 0.f;
  #pragma unroll
  for (int i = 0; i < NV; ++i) {
    int c = (i * 256 + t) * 4;
    float4 v;
    if (xf) {
      v = *(const float4*)(xf + (size_t)row * D + c);
    } else {
      bf16x4 vb = *(const bf16x4*)(xb + (size_t)row * D + c);
      v = make_float4((float)vb[0], (float)vb[1], (float)vb[2], (float)vb[3]);
    }
    vals[i*4+0] = v.x; vals[i*4+1] = v.y; vals[i*4+2] = v.z; vals[i*4+3] = v.w;
    s += v.x + v.y + v.z + v.w;
    s2 += v.x*v.x + v.y*v.y + v.z*v.z + v.w*v.w;
  }
  #pragma unroll
  for (int off = 32; off > 0; off >>= 1) {
    s += __shfl_xor(s, off);
    s2 += __shfl_xor(s2, off);
  }
  __shared__ float red[4], red2[4];
  int wv = t >> 6;
  if ((t & 63) == 0) { red[wv] = s; red2[wv] = s2; }
  __syncthreads();
  float S  = red[0] + red[1] + red[2] + red[3];
  float S2 = red2[0] + red2[1] + red2[2] + red2[3];
  float mean = S / D;
  float var = S2 / D - mean * mean;
  float rs = rsqrtf(var + 1e-5f);
  #pragma unroll
  for (int i = 0; i < NV; ++i) {
    int c = (i * 256 + t) * 4;
    bf16x4 o;
    #pragma unroll
    for (int j = 0; j < 4; ++j) {
      float v = (vals[i*4+j] - mean) * rs * w[c+j] + b[c+j];
      if (silu) v = v / (1.f + __expf(-v));
      o[j] = (__bf16)v;
    }
    *(bf16x4*)(out + (size_t)row * D + c) = o;
  }
}

// ---------------- bf16 MFMA GEMM core, 2-buffer stage-early/drain-late pipeline ----------
// C[M,N] = A[M,K] @ B^T; B stored [N][K]. Tile 128x128, BK=64, 4 waves.
// Per K-step: STAGE(next buf) -> COMPUTE(cur buf) -> vmcnt(0) -> s_barrier.
// Requires K % 128 == 0 (all call sites).
__device__ __forceinline__ void gemm_body(
    const __bf16* __restrict__ A, long long lda,
    const __bf16* __restrict__ B, long long ldb,
    float* __restrict__ outF, __bf16* __restrict__ outB, long long ldc,
    const float* __restrict__ bias, const float* __restrict__ res,
    int K, int bm, int bn) {
  __shared__ __bf16 Asm0[8192];
  __shared__ __bf16 Bsm0[8192];
  __shared__ __bf16 Asm1[8192];
  __shared__ __bf16 Bsm1[8192];
  int t = threadIdx.x;
  int lane = t & 63, w = t >> 6;
  int l15 = lane & 15, kg = lane >> 4;
  int wm = (w >> 1) * 64, wn = (w & 1) * 64;

  f32x4 acc[4][4];
  #pragma unroll
  for (int i = 0; i < 4; ++i)
    #pragma unroll
    for (int j = 0; j < 4; ++j) acc[i][j] = (f32x4)(0.0f);

  const __bf16* ga[4]; const __bf16* gb[4];
  int lo[4];
  #pragma unroll
  for (int i = 0; i < 4; ++i) {
    int slot = i * 256 + t;
    int row = slot >> 3, s = slot & 7;
    int sx = s ^ (row & 7);
    ga[i] = A + (size_t)(bm + row) * lda + (sx << 3);
    gb[i] = B + (size_t)(bn + row) * ldb + (sx << 3);
    lo[i] = (i * 256 + w * 64) << 3;
  }

  auto STAGE = [&](__bf16* As, __bf16* Bs, int k0) {
    #pragma unroll
    for (int i = 0; i < 4; ++i) g2l16(ga[i] + k0, As + lo[i]);
    #pragma unroll
    for (int i = 0; i < 4; ++i) g2l16(gb[i] + k0, Bs + lo[i]);
  };
  auto COMPUTE = [&](const __bf16* As, const __bf16* Bs) {
    #pragma unroll
    for (int kk = 0; kk < 2; ++kk) {
      bf16x8 af[4], bfr[4];
      #pragma unroll
      for (int mi = 0; mi < 4; ++mi) {
        int row = wm + mi * 16 + l15;
        int ks = kk * 4 + kg;
        af[mi] = *(const bf16x8*)(As + row * 64 + ((ks ^ (row & 7)) << 3));
      }
      #pragma unroll
      for (int ni = 0; ni < 4; ++ni) {
        int row = wn + ni * 16 + l15;
        int ks = kk * 4 + kg;
        bfr[ni] = *(const bf16x8*)(Bs + row * 64 + ((ks ^ (row & 7)) << 3));
      }
      #pragma unroll
      for (int mi = 0; mi < 4; ++mi)
        #pragma unroll
        for (int ni = 0; ni < 4; ++ni)
          acc[mi][ni] = __builtin_amdgcn_mfma_f32_16x16x32_bf16(
              af[mi], bfr[ni], acc[mi][ni], 0, 0, 0);
    }
  };
  #define GEMM_SYNC() do { \
    asm volatile("s_waitcnt vmcnt(0)" ::: "memory"); \
    __builtin_amdgcn_s_barrier(); \
    __builtin_amdgcn_sched_barrier(0); \
  } while (0)

  STAGE(Asm0, Bsm0, 0);
  GEMM_SYNC();
  int nk = K >> 6;  // even
  for (int kt = 0; kt + 2 < nk; kt += 2) {
    STAGE(Asm1, Bsm1, (kt + 1) << 6);
    COMPUTE(Asm0, Bsm0);
    GEMM_SYNC();
    STAGE(Asm0, Bsm0, (kt + 2) << 6);
    COMPUTE(Asm1, Bsm1);
    GEMM_SYNC();
  }
  // tail: tiles nk-2 (in buf0), nk-1
  STAGE(Asm1, Bsm1, (nk - 1) << 6);
  COMPUTE(Asm0, Bsm0);
  GEMM_SYNC();
  COMPUTE(Asm1, Bsm1);
  #undef GEMM_SYNC

  #pragma unroll
  for (int mi = 0; mi < 4; ++mi) {
    #pragma unroll
    for (int ni = 0; ni < 4; ++ni) {
      int rbase = bm + wm + mi * 16 + kg * 4;
      int c = bn + wn + ni * 16 + l15;
      #pragma unroll
      for (int r = 0; r < 4; ++r) {
        float val = acc[mi][ni][r];
        if (bias) val += bias[c];
        size_t off = (size_t)(rbase + r) * ldc + c;
        if (res) val += res[off];
        if (outF) outF[off] = val;
        if (outB) outB[off] = (__bf16)val;
      }
    }
  }
}

// Single-GEMM kernel (2D grid, XCD-aware swizzle; nwg divisible by 8 at all call sites).
__global__ __launch_bounds__(256) void gemm_bf16(
    const __bf16* __restrict__ A, long long lda,
    const __bf16* __restrict__ B, long long ldb,
    float* __restrict__ outF, __bf16* __restrict__ outB, long long ldc,
    const float* __restrict__ bias, const float* __restrict__ res, int K) {
  int nwg = gridDim.x * gridDim.y;
  int orig = blockIdx.y * gridDim.x + blockIdx.x;
  int swz = (orig & 7) * (nwg >> 3) + (orig >> 3);
  gemm_body(A, lda, B, ldb, outF, outB, ldc, bias, res, K,
            (swz / gridDim.x) * 128, (swz % gridDim.x) * 128);
}

// Dual-GEMM kernel: two independent GEMMs in one launch (1D grid, blocks < nb0 -> p0).
// Fills the machine when one GEMM alone has <2 blocks/CU. nb0 and nb1 divisible by 8.
__global__ __launch_bounds__(256) void gemm_dual(
    const __bf16* __restrict__ A0, long long lda0, const __bf16* __restrict__ B0, long long ldb0,
    float* __restrict__ oF0, __bf16* __restrict__ oB0, long long ldc0,
    const float* __restrict__ bias0, const float* __restrict__ res0, int K0, int gx0, int nb0,
    const __bf16* __restrict__ A1, long long lda1, const __bf16* __restrict__ B1, long long ldb1,
    float* __restrict__ oF1, __bf16* __restrict__ oB1, long long ldc1,
    const float* __restrict__ bias1, const float* __restrict__ res1, int K1, int gx1) {
  int bid = blockIdx.x;
  if (bid < nb0) {
    int swz = (bid & 7) * (nb0 >> 3) + (bid >> 3);
    gemm_body(A0, lda0, B0, ldb0, oF0, oB0, ldc0, bias0, res0, K0,
              (swz / gx0) * 128, (swz % gx0) * 128);
  } else {
    int b = bid - nb0;
    int nb1 = gridDim.x - nb0;
    int swz = (b & 7) * (nb1 >> 3) + (b >> 3);
    gemm_body(A1, lda1, B1, ldb1, oF1, oB1, ldc1, bias1, res1, K1,
              (swz / gx1) * 128, (swz % gx1) * 128);
  }
}

// ---------------- V transpose: V[b,k,h,d](bf16) -> VT[g][d][1024 k] ----------------
__device__ __forceinline__ void vtrans_body(
    const __bf16* __restrict__ V, long long v_sb, long long v_sh, int v_sm,
    __bf16* __restrict__ VT, int g, int k0) {
  __shared__ __bf16 tile[64][72];
  int b = g >> 4, h = g & 15;
  const __bf16* Vb = V + (size_t)b * v_sb + (size_t)h * v_sh;
  int t = threadIdx.x;
  #pragma unroll
  for (int i = 0; i < 2; ++i) {
    int idx = i * 256 + t;
    int k = idx >> 3, dc = (idx & 7) * 8;
    bf16x8 v = *(const bf16x8*)(Vb + (size_t)(k0 + k) * v_sm + dc);
    #pragma unroll
    for (int j = 0; j < 8; ++j) tile[dc + j][k] = v[j];
  }
  __syncthreads();
  #pragma unroll
  for (int i = 0; i < 2; ++i) {
    int idx = i * 256 + t;
    int d = idx >> 3, kc = (idx & 7) * 8;
    bf16x8 v;
    #pragma unroll
    for (int j = 0; j < 8; ++j) v[j] = tile[d][kc + j];
    *(bf16x8*)(VT + ((size_t)g * 64 + d) * 1024 + k0 + kc) = v;
  }
}

__global__ __launch_bounds__(256) void vtrans(
    const __bf16* __restrict__ V, long long v_sb, long long v_sh, int v_sm,
    __bf16* __restrict__ VT) {
  vtrans_body(V, v_sb, v_sh, v_sm, VT, blockIdx.y, blockIdx.x * 64);
}

// ---------------- GRU elementwise (blocks 0-2047) + CA V-transpose (2048-3071) ----------
// The two are mutually independent (gru: GI/GH -> qh; vtrans: KV_b -> VT) and both
// sit between the gi+kv GEMM and flash1 -> one launch removes a serial gap.
__global__ __launch_bounds__(256) void gru_vtrans(
    const __bf16* __restrict__ gi, const __bf16* __restrict__ gh,
    const float* __restrict__ hf, float* __restrict__ qh, __bf16* __restrict__ qhb,
    const __bf16* __restrict__ V, long long v_sb, long long v_sh, int v_sm,
    __bf16* __restrict__ VT) {
  if (blockIdx.x >= 2048) {
    int vb = blockIdx.x - 2048;
    vtrans_body(V, v_sb, v_sh, v_sm, VT, vb >> 4, (vb & 15) * 64);
    return;
  }
  size_t e0 = ((size_t)blockIdx.x * 256 + threadIdx.x) * 8;  // over 4M elems
  int row = (int)(e0 >> 10), col = (int)(e0 & 1023);
  size_t base = (size_t)row * 3072 + col;
  bf16x8 vir = *(const bf16x8*)(gi + base);
  bf16x8 viz = *(const bf16x8*)(gi + base + 1024);
  bf16x8 vin = *(const bf16x8*)(gi + base + 2048);
  bf16x8 vhr = *(const bf16x8*)(gh + base);
  bf16x8 vhz = *(const bf16x8*)(gh + base + 1024);
  bf16x8 vhn = *(const bf16x8*)(gh + base + 2048);
  float4 h0 = *(const float4*)(hf + e0);
  float4 h1 = *(const float4*)(hf + e0 + 4);
  float hv[8] = {h0.x, h0.y, h0.z, h0.w, h1.x, h1.y, h1.z, h1.w};
  float q[8];
  #pragma unroll
  for (int j = 0; j < 8; ++j) {
    float r = 1.f / (1.f + __expf(-((float)vir[j] + (float)vhr[j])));
    float z = 1.f / (1.f + __expf(-((float)viz[j] + (float)vhz[j])));
    float n = tanhf((float)vin[j] + r * (float)vhn[j]);
    q[j] = (1.f - z) * n + z * hv[j];
  }
  *(float4*)(qh + e0)     = make_float4(q[0], q[1], q[2], q[3]);
  *(float4*)(qh + e0 + 4) = make_float4(q[4], q[5], q[6], q[7]);
  bf16x8 qb;
  #pragma unroll
  for (int j = 0; j < 8; ++j) qb[j] = (__bf16)q[j];
  *(bf16x8*)(qhb + e0) = qb;
}

// ---------------- Fused flash attention, 3-deep pipelined K/V staging ----------------
// Per g=(b,h): O[q][d] = softmax_kv(S*scale) @ V, S = Q @ K^T (head dim 64).
// Swapped QK^T -> S^T acc (col=q=l15). P -> LDS packed bf16x4, XOR-swizzled.
// Psm/corr_l/l_l are wave-private rows => ONE raw s_barrier per tile suffices;
// staging for tile t+2 issued after the barrier (3 LDS buffers), waited with
// counted vmcnt (never 0 mid-loop). E: raw S stored nontemporally (268 MB stream).
template <int E>
__global__ __launch_bounds__(256) void flash_attn(
    const __bf16* __restrict__ Qb, long long q_sb, long long q_sh, int q_sm,
    const __bf16* __restrict__ Kb, long long k_sb, long long k_sh, int k_sm,
    const __bf16* __restrict__ VT, __bf16* __restrict__ Ob,
    float* __restrict__ energyOut, float scale) {
  __shared__ __bf16 Ksm[3][4096];
  __shared__ __bf16 Vsm[3][4096];
  __shared__ __bf16 Psm[128 * 64];
  __shared__ float corr_l[128];
  __shared__ float l_l[128];
  int g = blockIdx.y, b = g >> 4, h = g & 15;
  int qt = blockIdx.x * 128;
  const __bf16* Qg = Qb + (size_t)b * q_sb + (size_t)h * q_sh;
  const __bf16* Kg = Kb + (size_t)b * k_sb + (size_t)h * k_sh;
  const __bf16* Vg = VT + (size_t)g * 65536;
  int t = threadIdx.x, lane = t & 63, w = t >> 6;
  int l15 = lane & 15, kg = lane >> 4;
  int wq = w * 32;

  bf16x8 qf[2][2];
  #pragma unroll
  for (int nq = 0; nq < 2; ++nq)
    #pragma unroll
    for (int kk = 0; kk < 2; ++kk)
      qf[nq][kk] = *(const bf16x8*)(
          Qg + (size_t)(qt + wq + nq * 16 + l15) * q_sm + kk * 32 + kg * 8);

  f32x4 acc_o[2][4];
  #pragma unroll
  for (int i = 0; i < 2; ++i)
    #pragma unroll
    for (int j = 0; j < 4; ++j) acc_o[i][j] = (f32x4)(0.0f);
  float m_run[2] = {-1e30f, -1e30f};
  float l_run[2] = {0.f, 0.f};

  const __bf16* gK[2]; const __bf16* gV[2];
  int lo[2];
  #pragma unroll
  for (int i = 0; i < 2; ++i) {
    int slot = i * 256 + t;
    int row = slot >> 3, s = slot & 7, sx = s ^ (row & 7);
    gK[i] = Kg + (size_t)row * k_sm + (sx << 3);
    gV[i] = Vg + (size_t)row * 1024 + (sx << 3);
    lo[i] = (i * 256 + w * 64) << 3;
  }

  // prologue: stage tile 0 (4 oldest vmem ops) then tile 1
  #pragma unroll
  for (int i = 0; i < 2; ++i) g2l16(gK[i], &Ksm[0][lo[i]]);
  #pragma unroll
  for (int i = 0; i < 2; ++i) g2l16(gV[i], &Vsm[0][lo[i]]);
  #pragma unroll
  for (int i = 0; i < 2; ++i) g2l16(gK[i] + (size_t)64 * k_sm, &Ksm[1][lo[i]]);
  #pragma unroll
  for (int i = 0; i < 2; ++i) g2l16(gV[i] + 64, &Vsm[1][lo[i]]);

  int rb = 0;  // read buffer = kvt % 3
  for (int kvt = 0; kvt < 16; ++kvt) {
    // counted wait: exactly the newer-than-stage-kvt op count (4 loads/tile, 8 stores/tile if E)
    if (E) {
      if (kvt == 0)       asm volatile("s_waitcnt vmcnt(4)" ::: "memory");
      else if (kvt == 1)  asm volatile("s_waitcnt vmcnt(12)" ::: "memory");
      else if (kvt == 15) asm volatile("s_waitcnt vmcnt(16)" ::: "memory");
      else                asm volatile("s_waitcnt vmcnt(20)" ::: "memory");
    } else {
      if (kvt == 15)      asm volatile("s_waitcnt vmcnt(0)" ::: "memory");
      else                asm volatile("s_waitcnt vmcnt(4)" ::: "memory");
    }
    __builtin_amdgcn_s_barrier();
    __builtin_amdgcn_sched_barrier(0);  // pin: no memory op crosses the barrier

    if (kvt < 14) {  // stage tile kvt+2 (after barrier: all waves done reading that buffer)
      int sbuf = rb >= 1 ? rb - 1 : rb + 2;  // (kvt+2)%3
      size_t ko = (size_t)(kvt + 2) << 6;
      #pragma unroll
      for (int i = 0; i < 2; ++i) g2l16(gK[i] + ko * k_sm, &Ksm[sbuf][lo[i]]);
      #pragma unroll
      for (int i = 0; i < 2; ++i) g2l16(gV[i] + ko, &Vsm[sbuf][lo[i]]);
    }
    const __bf16* Ks = Ksm[rb];
    const __bf16* Vs = Vsm[rb];

    f32x4 accs[4][2];
    #pragma unroll
    for (int i = 0; i < 4; ++i)
      #pragma unroll
      for (int j = 0; j < 2; ++j) accs[i][j] = (f32x4)(0.0f);
    __builtin_amdgcn_s_setprio(1);
    #pragma unroll
    for (int tt = 0; tt < 4; ++tt) {
      bf16x8 kf[2];
      #pragma unroll
      for (int kk = 0; kk < 2; ++kk) {
        int row = tt * 16 + l15;
        int ks = kk * 4 + kg;
        kf[kk] = *(const bf16x8*)(Ks + row * 64 + ((ks ^ (row & 7)) << 3));
      }
      #pragma unroll
      for (int nq = 0; nq < 2; ++nq)
        #pragma unroll
        for (int kk = 0; kk < 2; ++kk)
          accs[tt][nq] = __builtin_amdgcn_mfma_f32_16x16x32_bf16(
              kf[kk], qf[nq][kk], accs[tt][nq], 0, 0, 0);
    }
    __builtin_amdgcn_s_setprio(0);

    if (E) {
      int kv0 = kvt << 6;
      float* eg = energyOut + ((size_t)g << 20);
      #pragma unroll
      for (int nq = 0; nq < 2; ++nq) {
        int q = qt + wq + nq * 16 + l15;
        #pragma unroll
        for (int tt = 0; tt < 4; ++tt)
          __builtin_nontemporal_store(
              accs[tt][nq], (f32x4*)(eg + (size_t)q * 1024 + kv0 + tt * 16 + kg * 4));
      }
    }

    #pragma unroll
    for (int nq = 0; nq < 2; ++nq) {
      float tmax = -1e30f;
      #pragma unroll
      for (int tt = 0; tt < 4; ++tt)
        #pragma unroll
        for (int r = 0; r < 4; ++r) tmax = fmaxf(tmax, accs[tt][nq][r]);
      tmax *= scale;
      tmax = fmaxf(tmax, __shfl_xor(tmax, 16));
      tmax = fmaxf(tmax, __shfl_xor(tmax, 32));
      float m_new = fmaxf(m_run[nq], tmax);
      float corr = __expf(m_run[nq] - m_new);
      m_run[nq] = m_new;
      int q = wq + nq * 16 + l15;
      float psum = 0.f;
      #pragma unroll
      for (int tt = 0; tt < 4; ++tt) {
        bf16x4 p4;
        #pragma unroll
        for (int r = 0; r < 4; ++r) {
          float p = __expf(accs[tt][nq][r] * scale - m_new);
          psum += p;
          p4[r] = (__bf16)p;
        }
        int kvs = (tt * 16 + kg * 4) ^ ((q & 7) << 3);
        *(bf16x4*)(Psm + q * 64 + kvs) = p4;
      }
      psum += __shfl_xor(psum, 16);
      psum += __shfl_xor(psum, 32);
      l_run[nq] = l_run[nq] * corr + psum;
      if (kg == 0) corr_l[q] = corr;
    }
    // no barrier: Psm / corr_l rows are wave-private

    #pragma unroll
    for (int mq = 0; mq < 2; ++mq) {
      f32x4 c4 = *(const f32x4*)&corr_l[wq + mq * 16 + kg * 4];
      #pragma unroll
      for (int nd = 0; nd < 4; ++nd)
        #pragma unroll
        for (int r = 0; r < 4; ++r) acc_o[mq][nd][r] *= c4[r];
    }
    __builtin_amdgcn_s_setprio(1);
    #pragma unroll
    for (int kk = 0; kk < 2; ++kk) {
      bf16x8 pf[2], vf[4];
      #pragma unroll
      for (int mq = 0; mq < 2; ++mq) {
        int row = wq + mq * 16 + l15;
        int kvs = (kk * 32 + kg * 8) ^ ((row & 7) << 3);
        pf[mq] = *(const bf16x8*)(Psm + row * 64 + kvs);
      }
      #pragma unroll
      for (int nd = 0; nd < 4; ++nd) {
        int vrow = nd * 16 + l15;
        vf[nd] = *(const bf16x8*)(Vs + vrow * 64 + (((kk * 4 + kg) ^ (vrow & 7)) << 3));
      }
      #pragma unroll
      for (int mq = 0; mq < 2; ++mq)
        #pragma unroll
        for (int nd = 0; nd < 4; ++nd)
          acc_o[mq][nd] = __builtin_amdgcn_mfma_f32_16x16x32_bf16(
              pf[mq], vf[nd], acc_o[mq][nd], 0, 0, 0);
    }
    __builtin_amdgcn_s_setprio(0);
    rb = rb == 2 ? 0 : rb + 1;
  }

  #pragma unroll
  for (int nq = 0; nq < 2; ++nq)
    if (kg == 0) l_l[wq + nq * 16 + l15] = l_run[nq];
  __syncthreads();

  #pragma unroll
  for (int mq = 0; mq < 2; ++mq) {
    f32x4 lv = *(const f32x4*)&l_l[wq + mq * 16 + kg * 4];
    #pragma unroll
    for (int nd = 0; nd < 4; ++nd) {
      int col = h * 64 + nd * 16 + l15;
      #pragma unroll
      for (int r = 0; r < 4; ++r) {
        int qrow = qt + wq + mq * 16 + kg * 4 + r;
        Ob[(size_t)(b * 1024 + qrow) * 1024 + col] = (__bf16)(acc_o[mq][nd][r] / lv[r]);
      }
    }
  }
}

extern "C" void kernel_launch(void* const* d_in, const int* in_sizes, int n_in,
                              void* d_out, int out_size, void* d_ws, size_t ws_size,
                              hipStream_t stream) {
  (void)in_sizes; (void)n_in; (void)out_size; (void)ws_size;
  const float* queries   = (const float*)d_in[0];
  const float* contexts  = (const float*)d_in[1];
  const float* qhid      = (const float*)d_in[2];
  const float* sa_norm_w = (const float*)d_in[3];
  const float* sa_norm_b = (const float*)d_in[4];
  const float* sa_qkv_w  = (const float*)d_in[5];
  const float* sa_out_w  = (const float*)d_in[6];
  const float* sa_out_b  = (const float*)d_in[7];
  const float* ca_norm_w = (const float*)d_in[8];
  const float* ca_norm_b = (const float*)d_in[9];
  const float* gru_w_ih  = (const float*)d_in[10];
  const float* gru_w_hh  = (const float*)d_in[11];
  const float* gru_b_ih  = (const float*)d_in[12];
  const float* gru_b_hh  = (const float*)d_in[13];
  const float* ca_k_w    = (const float*)d_in[14];
  const float* ca_v_w    = (const float*)d_in[15];
  const float* ca_out_w  = (const float*)d_in[16];
  const float* ca_out_b  = (const float*)d_in[17];
  const float* ln1_w     = (const float*)d_in[18];
  const float* ln1_b     = (const float*)d_in[19];
  const float* lin1_w    = (const float*)d_in[20];
  const float* ln2_w     = (const float*)d_in[21];
  const float* ln2_b     = (const float*)d_in[22];
  const float* lin2_w    = (const float*)d_in[23];

  float* out0   = (float*)d_out;               // [4096,1024]
  float* energy = out0 + (size_t)4194304;      // [64,1024,1024]
  float* qh_out = out0 + (size_t)71303168;     // [4096,1024]

  // ---- workspace map (units: MM = 1M floats = 4 MiB) ----
  const size_t MM = 1u << 20;
  float* ws = (float*)d_ws;
  float*  X     = ws;
  float*  X2    = ws + 4 * MM;
  __bf16* M1B    = (__bf16*)(ws + 9 * MM);
  __bf16* XN_b   = (__bf16*)(ws + 17 * MM);
  __bf16* QHID_b = (__bf16*)(ws + 19 * MM);
  __bf16* CTX_b  = (__bf16*)(ws + 21 * MM);
  __bf16* O_b    = (__bf16*)(ws + 23 * MM);
  __bf16* VT_b   = (__bf16*)(ws + 25 * MM);
  __bf16* QKV_b  = (__bf16*)(ws + 27 * MM);
  __bf16* KV_b   = (__bf16*)(ws + 27 * MM);  // [4096][2048] bf16, reuses QKV after SA
  __bf16* LN2_b  = (__bf16*)(ws);            // reuses dead X
  __bf16* qkvT   = (__bf16*)(ws + 33 * MM);
  __bf16* ihB    = (__bf16*)(ws + 34 * MM + MM / 2);
  __bf16* hhB    = (__bf16*)(ws + 36 * MM);
  __bf16* kT     = (__bf16*)(ws + 37 * MM + MM / 2);  // kT,vT contiguous => merged B [2048][1024]
  __bf16* vT     = (__bf16*)(ws + 38 * MM);
  __bf16* saoT   = (__bf16*)(ws + 38 * MM + MM / 2);
  __bf16* caoT   = (__bf16*)(ws + 39 * MM);
  __bf16* lin1T  = (__bf16*)(ws + 39 * MM + MM / 2);
  __bf16* lin2T  = (__bf16*)(ws + 40 * MM + MM / 2);
  __bf16* GI_b = (__bf16*)energy;            // [4096][3072] bf16 = 24 MB
  __bf16* GH_b = (__bf16*)(energy + 6 * MM); // next 24 MB

  const long long QKV_SB = 1024LL * 3072;
  const long long KV_SB  = 1024LL * 2048;

  // ---- fused prep: all weight transposes + casts + ln_sa ----
  prep_all<<<14080, 256, 0, stream>>>(
      sa_qkv_w, ca_k_w, ca_v_w, sa_out_w, ca_out_w, lin1_w, lin2_w,
      gru_w_ih, gru_w_hh, qhid, contexts, queries, sa_norm_w, sa_norm_b,
      qkvT, kT, vT, saoT, caoT, lin1T, lin2T, ihB, hhB, QHID_b, CTX_b, XN_b);

  // ---- SelfAttention ----
  gemm_bf16<<<dim3(24, 32), 256, 0, stream>>>(
      XN_b, 1024, qkvT, 1024, nullptr, QKV_b, 3072, nullptr, nullptr, 1024);
  vtrans<<<dim3(16, 64), 256, 0, stream>>>(QKV_b + 128, QKV_SB, 192, 3072, VT_b);
  flash_attn<0><<<dim3(8, 64), 256, 0, stream>>>(
      QKV_b, QKV_SB, 192, 3072, QKV_b + 64, QKV_SB, 192, 3072,
      VT_b, O_b, nullptr, SCALE);
  // sa_out (256 blocks, chain) merged with gh (768 blocks, independent after prep)
  gemm_dual<<<1024, 256, 0, stream>>>(
      O_b, 1024, saoT, 1024, X, nullptr, 1024, sa_out_b, queries, 1024, 8, 256,
      QHID_b, 1024, hhB, 1024, nullptr, GH_b, 3072, gru_b_hh, nullptr, 1024, 24);

  // ---- GRU dynamic query ----
  ln_bf16<1><<<4096, 256, 0, stream>>>(X, nullptr, ca_norm_w, ca_norm_b, XN_b, 0);
  // gi (768 blocks, chain) merged with CA kv projection (512 blocks, independent)
  gemm_dual<<<1280, 256, 0, stream>>>(
      XN_b, 1024, ihB, 1024, nullptr, GI_b, 3072, gru_b_ih, nullptr, 1024, 24, 768,
      CTX_b, 1024, kT, 1024, nullptr, KV_b, 2048, nullptr, nullptr, 1024, 16);
  // gru elementwise (2048 blocks) + CA V-transpose (1024 blocks): independent, one launch
  gru_vtrans<<<3072, 256, 0, stream>>>(
      GI_b, GH_b, qhid, qh_out, QHID_b /*now QHB*/,
      KV_b + 1024, KV_SB, 64, 2048, VT_b);

  // ---- Cross attention ----
  flash_attn<1><<<dim3(8, 64), 256, 0, stream>>>(
      QHID_b, 1024LL * 1024, 64, 1024, KV_b, KV_SB, 64, 2048,
      VT_b, O_b, energy, SCALE);
  gemm_bf16<<<dim3(8, 32), 256, 0, stream>>>(
      O_b, 1024, caoT, 1024, X2, nullptr, 1024, ca_out_b, X, 1024);

  // ---- MLP ----
  ln_bf16<1><<<4096, 256, 0, stream>>>(X2, nullptr, ln1_w, ln1_b, XN_b, 1);
  gemm_bf16<<<dim3(16, 32), 256, 0, stream>>>(
      XN_b, 1024, lin1T, 1024, nullptr, M1B, 2048, nullptr, nullptr, 1024);
  ln_bf16<2><<<4096, 256, 0, stream>>>(nullptr, M1B, ln2_w, ln2_b, LN2_b, 1);
  gemm_bf16<<<dim3(8, 32), 256, 0, stream>>>(
      LN2_b, 2048, lin2T, 2048, out0, nullptr, 1024, nullptr, X2, 2048);
}

// Round 7
// 609.526 us; speedup vs baseline: 1.0810x; 1.0122x over previous
//
#include <hip/hip_runtime.h>
#include <hip/hip_bf16.h>
#include <math.h>

static constexpr float SCALE = 0.03125f; // 1/sqrt(1024)

typedef __attribute__((ext_vector_type(4))) float f32x4;
typedef __attribute__((ext_vector_type(8))) __bf16 bf16x8;
typedef __attribute__((ext_vector_type(4))) __bf16 bf16x4;

__device__ __forceinline__ void g2l16(const void* g, void* l) {
  __builtin_amdgcn_global_load_lds(
      (const __attribute__((address_space(1))) unsigned int*)g,
      (__attribute__((address_space(3))) unsigned int*)l,
      16, 0, 0);
}

// ---------------- fused weight prep: 7 transposes + 4 casts + ln_sa in one launch --------
// tile ranges (64x64 wtrans tiles): qkv 0-767 | kT 768-1023 | vT 1024-1279 |
// saoT 1280-1535 | caoT 1536-1791 | lin1T 1792-2303 | lin2T 2304-2815
// casts (2048 elems/block): ihB 2816-4351 | hhB 4352-5887 | qhid 5888-7935 | ctx 7936-9983
// ln_sa rows: 9984-14079 (reads only the `queries` input -> independent of the rest)
__global__ __launch_bounds__(256) void prep_all(
    const float* __restrict__ sa_qkv_w, const float* __restrict__ ca_k_w,
    const float* __restrict__ ca_v_w, const float* __restrict__ sa_out_w,
    const float* __restrict__ ca_out_w, const float* __restrict__ lin1_w,
    const float* __restrict__ lin2_w, const float* __restrict__ gru_w_ih,
    const float* __restrict__ gru_w_hh, const float* __restrict__ qhid,
    const float* __restrict__ contexts,
    const float* __restrict__ queries, const float* __restrict__ sa_norm_w,
    const float* __restrict__ sa_norm_b,
    __bf16* __restrict__ qkvT, __bf16* __restrict__ kT, __bf16* __restrict__ vT,
    __bf16* __restrict__ saoT, __bf16* __restrict__ caoT, __bf16* __restrict__ lin1T,
    __bf16* __restrict__ lin2T, __bf16* __restrict__ ihB, __bf16* __restrict__ hhB,
    __bf16* __restrict__ qhB, __bf16* __restrict__ ctxB, __bf16* __restrict__ xnB) {
  int bid = blockIdx.x;
  int t = threadIdx.x;
  if (bid >= 9984) {  // ---- LayerNorm(queries) -> xnB, D=1024 ----
    int row = bid - 9984;
    int c = t * 4;
    float4 v = *(const float4*)(queries + (size_t)row * 1024 + c);
    float s = v.x + v.y + v.z + v.w;
    float s2 = v.x*v.x + v.y*v.y + v.z*v.z + v.w*v.w;
    #pragma unroll
    for (int off = 32; off > 0; off >>= 1) {
      s += __shfl_xor(s, off);
      s2 += __shfl_xor(s2, off);
    }
    __shared__ float red[4], red2[4];
    int wv = t >> 6;
    if ((t & 63) == 0) { red[wv] = s; red2[wv] = s2; }
    __syncthreads();
    float S  = red[0] + red[1] + red[2] + red[3];
    float S2 = red2[0] + red2[1] + red2[2] + red2[3];
    float mean = S / 1024.f;
    float var = S2 / 1024.f - mean * mean;
    float rs = rsqrtf(var + 1e-5f);
    float vv[4] = {v.x, v.y, v.z, v.w};
    bf16x4 o;
    #pragma unroll
    for (int j = 0; j < 4; ++j)
      o[j] = (__bf16)((vv[j] - mean) * rs * sa_norm_w[c+j] + sa_norm_b[c+j]);
    *(bf16x4*)(xnB + (size_t)row * 1024 + c) = o;
    return;
  }
  if (bid >= 2816) {  // casts, 8 elems/thread
    const float* csrc; __bf16* cdst; int cbase;
    if (bid < 4352)      { csrc = gru_w_ih; cdst = ihB;  cbase = 2816; }
    else if (bid < 5888) { csrc = gru_w_hh; cdst = hhB;  cbase = 4352; }
    else if (bid < 7936) { csrc = qhid;     cdst = qhB;  cbase = 5888; }
    else                 { csrc = contexts; cdst = ctxB; cbase = 7936; }
    size_t idx = ((size_t)(bid - cbase) * 256 + t) * 8;
    float4 a = *(const float4*)(csrc + idx);
    float4 b = *(const float4*)(csrc + idx + 4);
    bf16x8 o = {(__bf16)a.x,(__bf16)a.y,(__bf16)a.z,(__bf16)a.w,
                (__bf16)b.x,(__bf16)b.y,(__bf16)b.z,(__bf16)b.w};
    *(bf16x8*)(cdst + idx) = o;
    return;
  }
  const float* src; __bf16* dst; int Kd, N, base;
  if (bid < 768)       { src = sa_qkv_w; dst = qkvT;  Kd = 1024; N = 3072; base = 0; }
  else if (bid < 1024) { src = ca_k_w;   dst = kT;    Kd = 1024; N = 1024; base = 768; }
  else if (bid < 1280) { src = ca_v_w;   dst = vT;    Kd = 1024; N = 1024; base = 1024; }
  else if (bid < 1536) { src = sa_out_w; dst = saoT;  Kd = 1024; N = 1024; base = 1280; }
  else if (bid < 1792) { src = ca_out_w; dst = caoT;  Kd = 1024; N = 1024; base = 1536; }
  else if (bid < 2304) { src = lin1_w;   dst = lin1T; Kd = 1024; N = 2048; base = 1792; }
  else                 { src = lin2_w;   dst = lin2T; Kd = 2048; N = 1024; base = 2304; }
  int tid = bid - base;
  int ntx = N >> 6;
  int n0 = (tid % ntx) * 64, k0 = (tid / ntx) * 64;
  __shared__ float tile[64][65];
  #pragma unroll
  for (int i = 0; i < 16; ++i) {
    int idx = i * 256 + t; int r = idx >> 6, c = idx & 63;
    tile[r][c] = src[(size_t)(k0 + r) * N + n0 + c];
  }
  __syncthreads();
  #pragma unroll
  for (int i = 0; i < 16; ++i) {
    int idx = i * 256 + t; int r = idx >> 6, c = idx & 63;
    dst[(size_t)(n0 + r) * Kd + k0 + c] = (__bf16)tile[c][r];
  }
}

// ---------------- LayerNorm (+ optional SiLU) -> bf16, fp32 or bf16 input ----------------
template <int NV>  // NV = D/1024 (4*NV elems/thread)
__global__ __launch_bounds__(256) void ln_bf16(
    const float* __restrict__ xf, const __bf16* __restrict__ xb,
    const float* __restrict__ w, const float* __restrict__ b,
    __bf16* __restrict__ out, int silu) {
  const int D = NV * 1024;
  int row = blockIdx.x, t = threadIdx.x;
  float vals[NV * 4];
  float s = 0.f, s2 = 0.f;
  #pragma unroll
  for (int i = 0; i < NV; ++i) {
    int c = (i * 256 + t) * 4;
    float4 v;
    if (xf) {
      v = *(const float4*)(xf + (size_t)row * D + c);
    } else {
      bf16x4 vb = *(const bf16x4*)(xb + (size_t)row * D + c);
      v = make_float4((float)vb[0], (float)vb[1], (float)vb[2], (float)vb[3]);
    }
    vals[i*4+0] = v.x; vals[i*4+1] = v.y; vals[i*4+2] = v.z; vals[i*4+3] = v.w;
    s += v.x + v.y + v.z + v.w;
    s2 += v.x*v.x + v.y*v.y + v.z*v.z + v.w*v.w;
  }
  #pragma unroll
  for (int off = 32; off > 0; off >>= 1) {
    s += __shfl_xor(s, off);
    s2 += __shfl_xor(s2, off);
  }
  __shared__ float red[4], red2[4];
  int wv = t >> 6;
  if ((t & 63) == 0) { red[wv] = s; red2[wv] = s2; }
  __syncthreads();
  float S  = red[0] + red[1] + red[2] + red[3];
  float S2 = red2[0] + red2[1] + red2[2] + red2[3];
  float mean = S / D;
  float var = S2 / D - mean * mean;
  float rs = rsqrtf(var + 1e-5f);
  #pragma unroll
  for (int i = 0; i < NV; ++i) {
    int c = (i * 256 + t) * 4;
    bf16x4 o;
    #pragma unroll
    for (int j = 0; j < 4; ++j) {
      float v = (vals[i*4+j] - mean) * rs * w[c+j] + b[c+j];
      if (silu) v = v / (1.f + __expf(-v));
      o[j] = (__bf16)v;
    }
    *(bf16x4*)(out + (size_t)row * D + c) = o;
  }
}

// ---------------- bf16 MFMA GEMM core, 2-buffer stage-early/drain-late pipeline ----------
// C[M,N] = A[M,K] @ B^T; B stored [N][K]. Tile 128x128, BK=64, 4 waves.
// Per K-step: STAGE(next buf) -> COMPUTE(cur buf) -> vmcnt(0) -> s_barrier.
// Requires K % 128 == 0 (all call sites).
// vmode: 0 = plain epilogue. 1/2 = V-transpose epilogue: wave col stripes that are
// V (qkv layout: (bn+wn)%192==128; kv layout: bn+wn>=1024) are written TRANSPOSED
// into VTout[(b*16+h)*64+d][k] via a wave-private LDS scratch (reuses Asm0/Bsm0,
// dead after the last barrier; tail compute reads only Asm1/Bsm1) with coalesced
// 16B stores. Values are the same (__bf16)acc bits the old vtrans kernel copied.
__device__ __forceinline__ void gemm_body(
    const __bf16* __restrict__ A, long long lda,
    const __bf16* __restrict__ B, long long ldb,
    float* __restrict__ outF, __bf16* __restrict__ outB, long long ldc,
    const float* __restrict__ bias, const float* __restrict__ res,
    int K, int bm, int bn, __bf16* __restrict__ VTout, int vmode) {
  __shared__ __bf16 Asm0[8192];
  __shared__ __bf16 Bsm0[8192];
  __shared__ __bf16 Asm1[8192];
  __shared__ __bf16 Bsm1[8192];
  int t = threadIdx.x;
  int lane = t & 63, w = t >> 6;
  int l15 = lane & 15, kg = lane >> 4;
  int wm = (w >> 1) * 64, wn = (w & 1) * 64;

  f32x4 acc[4][4];
  #pragma unroll
  for (int i = 0; i < 4; ++i)
    #pragma unroll
    for (int j = 0; j < 4; ++j) acc[i][j] = (f32x4)(0.0f);

  const __bf16* ga[4]; const __bf16* gb[4];
  int lo[4];
  #pragma unroll
  for (int i = 0; i < 4; ++i) {
    int slot = i * 256 + t;
    int row = slot >> 3, s = slot & 7;
    int sx = s ^ (row & 7);
    ga[i] = A + (size_t)(bm + row) * lda + (sx << 3);
    gb[i] = B + (size_t)(bn + row) * ldb + (sx << 3);
    lo[i] = (i * 256 + w * 64) << 3;
  }

  auto STAGE = [&](__bf16* As, __bf16* Bs, int k0) {
    #pragma unroll
    for (int i = 0; i < 4; ++i) g2l16(ga[i] + k0, As + lo[i]);
    #pragma unroll
    for (int i = 0; i < 4; ++i) g2l16(gb[i] + k0, Bs + lo[i]);
  };
  auto COMPUTE = [&](const __bf16* As, const __bf16* Bs) {
    #pragma unroll
    for (int kk = 0; kk < 2; ++kk) {
      bf16x8 af[4], bfr[4];
      #pragma unroll
      for (int mi = 0; mi < 4; ++mi) {
        int row = wm + mi * 16 + l15;
        int ks = kk * 4 + kg;
        af[mi] = *(const bf16x8*)(As + row * 64 + ((ks ^ (row & 7)) << 3));
      }
      #pragma unroll
      for (int ni = 0; ni < 4; ++ni) {
        int row = wn + ni * 16 + l15;
        int ks = kk * 4 + kg;
        bfr[ni] = *(const bf16x8*)(Bs + row * 64 + ((ks ^ (row & 7)) << 3));
      }
      #pragma unroll
      for (int mi = 0; mi < 4; ++mi)
        #pragma unroll
        for (int ni = 0; ni < 4; ++ni)
          acc[mi][ni] = __builtin_amdgcn_mfma_f32_16x16x32_bf16(
              af[mi], bfr[ni], acc[mi][ni], 0, 0, 0);
    }
  };
  #define GEMM_SYNC() do { \
    asm volatile("s_waitcnt vmcnt(0)" ::: "memory"); \
    __builtin_amdgcn_s_barrier(); \
    __builtin_amdgcn_sched_barrier(0); \
  } while (0)

  STAGE(Asm0, Bsm0, 0);
  GEMM_SYNC();
  int nk = K >> 6;  // even
  for (int kt = 0; kt + 2 < nk; kt += 2) {
    STAGE(Asm1, Bsm1, (kt + 1) << 6);
    COMPUTE(Asm0, Bsm0);
    GEMM_SYNC();
    STAGE(Asm0, Bsm0, (kt + 2) << 6);
    COMPUTE(Asm1, Bsm1);
    GEMM_SYNC();
  }
  // tail: tiles nk-2 (in buf0), nk-1
  STAGE(Asm1, Bsm1, (nk - 1) << 6);
  COMPUTE(Asm0, Bsm0);
  GEMM_SYNC();
  COMPUTE(Asm1, Bsm1);
  #undef GEMM_SYNC

  int cw = bn + wn;
  int isV = 0;
  if (vmode == 1)      isV = (cw % 192) == 128;
  else if (vmode == 2) isV = cw >= 1024;

  if (isV) {
    // ---- V-transpose epilogue (wave-private; Asm0/Bsm0 dead after last barrier) ----
    int h = (vmode == 1) ? (cw / 192) : ((cw - 1024) >> 6);
    int rowb = bm + wm;               // 64 rows, within one batch (64-aligned)
    int b = rowb >> 10, k0 = rowb & 1023;
    __bf16* scr = (w < 2 ? Asm0 : Bsm0) + (w & 1) * 4096;  // 64x64 bf16 = 4096 elems
    #pragma unroll
    for (int mi = 0; mi < 4; ++mi) {
      #pragma unroll
      for (int ni = 0; ni < 4; ++ni) {
        int d = ni * 16 + l15;
        int sw = (d & 7) << 3;
        #pragma unroll
        for (int r = 0; r < 4; ++r) {
          int kl = mi * 16 + kg * 4 + r;
          scr[d * 64 + (kl ^ sw)] = (__bf16)acc[mi][ni][r];
        }
      }
    }
    // read back transposed: 8 iters x 64 lanes cover 64 d x 8 chunks of 8 k
    #pragma unroll
    for (int i = 0; i < 8; ++i) {
      int idx = i * 64 + lane;
      int d = idx >> 3, kc = (idx & 7) * 8;
      bf16x8 v = *(const bf16x8*)&scr[d * 64 + (kc ^ ((d & 7) << 3))];
      *(bf16x8*)(VTout + ((size_t)((b * 16 + h) * 64 + d) << 10) + k0 + kc) = v;
    }
    return;
  }

  #pragma unroll
  for (int mi = 0; mi < 4; ++mi) {
    #pragma unroll
    for (int ni = 0; ni < 4; ++ni) {
      int rbase = bm + wm + mi * 16 + kg * 4;
      int c = bn + wn + ni * 16 + l15;
      #pragma unroll
      for (int r = 0; r < 4; ++r) {
        float val = acc[mi][ni][r];
        if (bias) val += bias[c];
        size_t off = (size_t)(rbase + r) * ldc + c;
        if (res) val += res[off];
        if (outF) outF[off] = val;
        if (outB) outB[off] = (__bf16)val;
      }
    }
  }
}

// Single-GEMM kernel (2D grid, XCD-aware swizzle; nwg divisible by 8 at all call sites).
__global__ __launch_bounds__(256) void gemm_bf16(
    const __bf16* __restrict__ A, long long lda,
    const __bf16* __restrict__ B, long long ldb,
    float* __restrict__ outF, __bf16* __restrict__ outB, long long ldc,
    const float* __restrict__ bias, const float* __restrict__ res, int K,
    __bf16* __restrict__ VTout, int vmode) {
  int nwg = gridDim.x * gridDim.y;
  int orig = blockIdx.y * gridDim.x + blockIdx.x;
  int swz = (orig & 7) * (nwg >> 3) + (orig >> 3);
  gemm_body(A, lda, B, ldb, outF, outB, ldc, bias, res, K,
            (swz / gridDim.x) * 128, (swz % gridDim.x) * 128, VTout, vmode);
}

// Dual-GEMM kernel: two independent GEMMs in one launch (1D grid, blocks < nb0 -> p0).
// Fills the machine when one GEMM alone has <2 blocks/CU. nb0 and nb1 divisible by 8.
__global__ __launch_bounds__(256) void gemm_dual(
    const __bf16* __restrict__ A0, long long lda0, const __bf16* __restrict__ B0, long long ldb0,
    float* __restrict__ oF0, __bf16* __restrict__ oB0, long long ldc0,
    const float* __restrict__ bias0, const float* __restrict__ res0, int K0, int gx0, int nb0,
    const __bf16* __restrict__ A1, long long lda1, const __bf16* __restrict__ B1, long long ldb1,
    float* __restrict__ oF1, __bf16* __restrict__ oB1, long long ldc1,
    const float* __restrict__ bias1, const float* __restrict__ res1, int K1, int gx1,
    __bf16* __restrict__ VT1, int vm1) {
  int bid = blockIdx.x;
  if (bid < nb0) {
    int swz = (bid & 7) * (nb0 >> 3) + (bid >> 3);
    gemm_body(A0, lda0, B0, ldb0, oF0, oB0, ldc0, bias0, res0, K0,
              (swz / gx0) * 128, (swz % gx0) * 128, nullptr, 0);
  } else {
    int b = bid - nb0;
    int nb1 = gridDim.x - nb0;
    int swz = (b & 7) * (nb1 >> 3) + (b >> 3);
    gemm_body(A1, lda1, B1, ldb1, oF1, oB1, ldc1, bias1, res1, K1,
              (swz / gx1) * 128, (swz % gx1) * 128, VT1, vm1);
  }
}

// ---------------- GRU cell elementwise, bf16 inputs, 8 elems/thread ----------------
__global__ __launch_bounds__(256) void gru_kernel(
    const __bf16* __restrict__ gi, const __bf16* __restrict__ gh,
    const float* __restrict__ hf, float* __restrict__ qh, __bf16* __restrict__ qhb) {
  size_t e0 = ((size_t)blockIdx.x * 256 + threadIdx.x) * 8;  // over 4M elems
  int row = (int)(e0 >> 10), col = (int)(e0 & 1023);
  size_t base = (size_t)row * 3072 + col;
  bf16x8 vir = *(const bf16x8*)(gi + base);
  bf16x8 viz = *(const bf16x8*)(gi + base + 1024);
  bf16x8 vin = *(const bf16x8*)(gi + base + 2048);
  bf16x8 vhr = *(const bf16x8*)(gh + base);
  bf16x8 vhz = *(const bf16x8*)(gh + base + 1024);
  bf16x8 vhn = *(const bf16x8*)(gh + base + 2048);
  float4 h0 = *(const float4*)(hf + e0);
  float4 h1 = *(const float4*)(hf + e0 + 4);
  float hv[8] = {h0.x, h0.y, h0.z, h0.w, h1.x, h1.y, h1.z, h1.w};
  float q[8];
  #pragma unroll
  for (int j = 0; j < 8; ++j) {
    float r = 1.f / (1.f + __expf(-((float)vir[j] + (float)vhr[j])));
    float z = 1.f / (1.f + __expf(-((float)viz[j] + (float)vhz[j])));
    float n = tanhf((float)vin[j] + r * (float)vhn[j]);
    q[j] = (1.f - z) * n + z * hv[j];
  }
  *(float4*)(qh + e0)     = make_float4(q[0], q[1], q[2], q[3]);
  *(float4*)(qh + e0 + 4) = make_float4(q[4], q[5], q[6], q[7]);
  bf16x8 qb;
  #pragma unroll
  for (int j = 0; j < 8; ++j) qb[j] = (__bf16)q[j];
  *(bf16x8*)(qhb + e0) = qb;
}

// ---------------- Fused flash attention, 3-deep pipelined K/V staging ----------------
// Per g=(b,h): O[q][d] = softmax_kv(S*scale) @ V, S = Q @ K^T (head dim 64).
// Swapped QK^T -> S^T acc (col=q=l15). P -> LDS packed bf16x4, XOR-swizzled.
// Psm/corr_l/l_l are wave-private rows => ONE raw s_barrier per tile suffices;
// staging for tile t+2 issued after the barrier (3 LDS buffers), waited with
// counted vmcnt (never 0 mid-loop). E: raw S stored nontemporally (268 MB stream).
template <int E>
__global__ __launch_bounds__(256) void flash_attn(
    const __bf16* __restrict__ Qb, long long q_sb, long long q_sh, int q_sm,
    const __bf16* __restrict__ Kb, long long k_sb, long long k_sh, int k_sm,
    const __bf16* __restrict__ VT, __bf16* __restrict__ Ob,
    float* __restrict__ energyOut, float scale) {
  __shared__ __bf16 Ksm[3][4096];
  __shared__ __bf16 Vsm[3][4096];
  __shared__ __bf16 Psm[128 * 64];
  __shared__ float corr_l[128];
  __shared__ float l_l[128];
  int g = blockIdx.y, b = g >> 4, h = g & 15;
  int qt = blockIdx.x * 128;
  const __bf16* Qg = Qb + (size_t)b * q_sb + (size_t)h * q_sh;
  const __bf16* Kg = Kb + (size_t)b * k_sb + (size_t)h * k_sh;
  const __bf16* Vg = VT + (size_t)g * 65536;
  int t = threadIdx.x, lane = t & 63, w = t >> 6;
  int l15 = lane & 15, kg = lane >> 4;
  int wq = w * 32;

  bf16x8 qf[2][2];
  #pragma unroll
  for (int nq = 0; nq < 2; ++nq)
    #pragma unroll
    for (int kk = 0; kk < 2; ++kk)
      qf[nq][kk] = *(const bf16x8*)(
          Qg + (size_t)(qt + wq + nq * 16 + l15) * q_sm + kk * 32 + kg * 8);

  f32x4 acc_o[2][4];
  #pragma unroll
  for (int i = 0; i < 2; ++i)
    #pragma unroll
    for (int j = 0; j < 4; ++j) acc_o[i][j] = (f32x4)(0.0f);
  float m_run[2] = {-1e30f, -1e30f};
  float l_run[2] = {0.f, 0.f};

  const __bf16* gK[2]; const __bf16* gV[2];
  int lo[2];
  #pragma unroll
  for (int i = 0; i < 2; ++i) {
    int slot = i * 256 + t;
    int row = slot >> 3, s = slot & 7, sx = s ^ (row & 7);
    gK[i] = Kg + (size_t)row * k_sm + (sx << 3);
    gV[i] = Vg + (size_t)row * 1024 + (sx << 3);
    lo[i] = (i * 256 + w * 64) << 3;
  }

  // prologue: stage tile 0 (4 oldest vmem ops) then tile 1
  #pragma unroll
  for (int i = 0; i < 2; ++i) g2l16(gK[i], &Ksm[0][lo[i]]);
  #pragma unroll
  for (int i = 0; i < 2; ++i) g2l16(gV[i], &Vsm[0][lo[i]]);
  #pragma unroll
  for (int i = 0; i < 2; ++i) g2l16(gK[i] + (size_t)64 * k_sm, &Ksm[1][lo[i]]);
  #pragma unroll
  for (int i = 0; i < 2; ++i) g2l16(gV[i] + 64, &Vsm[1][lo[i]]);

  int rb = 0;  // read buffer = kvt % 3
  for (int kvt = 0; kvt < 16; ++kvt) {
    // counted wait: exactly the newer-than-stage-kvt op count (4 loads/tile, 8 stores/tile if E)
    if (E) {
      if (kvt == 0)       asm volatile("s_waitcnt vmcnt(4)" ::: "memory");
      else if (kvt == 1)  asm volatile("s_waitcnt vmcnt(12)" ::: "memory");
      else if (kvt == 15) asm volatile("s_waitcnt vmcnt(16)" ::: "memory");
      else                asm volatile("s_waitcnt vmcnt(20)" ::: "memory");
    } else {
      if (kvt == 15)      asm volatile("s_waitcnt vmcnt(0)" ::: "memory");
      else                asm volatile("s_waitcnt vmcnt(4)" ::: "memory");
    }
    __builtin_amdgcn_s_barrier();
    __builtin_amdgcn_sched_barrier(0);  // pin: no memory op crosses the barrier

    if (kvt < 14) {  // stage tile kvt+2 (after barrier: all waves done reading that buffer)
      int sbuf = rb >= 1 ? rb - 1 : rb + 2;  // (kvt+2)%3
      size_t ko = (size_t)(kvt + 2) << 6;
      #pragma unroll
      for (int i = 0; i < 2; ++i) g2l16(gK[i] + ko * k_sm, &Ksm[sbuf][lo[i]]);
      #pragma unroll
      for (int i = 0; i < 2; ++i) g2l16(gV[i] + ko, &Vsm[sbuf][lo[i]]);
    }
    const __bf16* Ks = Ksm[rb];
    const __bf16* Vs = Vsm[rb];

    f32x4 accs[4][2];
    #pragma unroll
    for (int i = 0; i < 4; ++i)
      #pragma unroll
      for (int j = 0; j < 2; ++j) accs[i][j] = (f32x4)(0.0f);
    __builtin_amdgcn_s_setprio(1);
    #pragma unroll
    for (int tt = 0; tt < 4; ++tt) {
      bf16x8 kf[2];
      #pragma unroll
      for (int kk = 0; kk < 2; ++kk) {
        int row = tt * 16 + l15;
        int ks = kk * 4 + kg;
        kf[kk] = *(const bf16x8*)(Ks + row * 64 + ((ks ^ (row & 7)) << 3));
      }
      #pragma unroll
      for (int nq = 0; nq < 2; ++nq)
        #pragma unroll
        for (int kk = 0; kk < 2; ++kk)
          accs[tt][nq] = __builtin_amdgcn_mfma_f32_16x16x32_bf16(
              kf[kk], qf[nq][kk], accs[tt][nq], 0, 0, 0);
    }
    __builtin_amdgcn_s_setprio(0);

    if (E) {
      int kv0 = kvt << 6;
      float* eg = energyOut + ((size_t)g << 20);
      #pragma unroll
      for (int nq = 0; nq < 2; ++nq) {
        int q = qt + wq + nq * 16 + l15;
        #pragma unroll
        for (int tt = 0; tt < 4; ++tt)
          __builtin_nontemporal_store(
              accs[tt][nq], (f32x4*)(eg + (size_t)q * 1024 + kv0 + tt * 16 + kg * 4));
      }
    }

    #pragma unroll
    for (int nq = 0; nq < 2; ++nq) {
      float tmax = -1e30f;
      #pragma unroll
      for (int tt = 0; tt < 4; ++tt)
        #pragma unroll
        for (int r = 0; r < 4; ++r) tmax = fmaxf(tmax, accs[tt][nq][r]);
      tmax *= scale;
      tmax = fmaxf(tmax, __shfl_xor(tmax, 16));
      tmax = fmaxf(tmax, __shfl_xor(tmax, 32));
      float m_new = fmaxf(m_run[nq], tmax);
      float corr = __expf(m_run[nq] - m_new);
      m_run[nq] = m_new;
      int q = wq + nq * 16 + l15;
      float psum = 0.f;
      #pragma unroll
      for (int tt = 0; tt < 4; ++tt) {
        bf16x4 p4;
        #pragma unroll
        for (int r = 0; r < 4; ++r) {
          float p = __expf(accs[tt][nq][r] * scale - m_new);
          psum += p;
          p4[r] = (__bf16)p;
        }
        int kvs = (tt * 16 + kg * 4) ^ ((q & 7) << 3);
        *(bf16x4*)(Psm + q * 64 + kvs) = p4;
      }
      psum += __shfl_xor(psum, 16);
      psum += __shfl_xor(psum, 32);
      l_run[nq] = l_run[nq] * corr + psum;
      if (kg == 0) corr_l[q] = corr;
    }
    // no barrier: Psm / corr_l rows are wave-private

    #pragma unroll
    for (int mq = 0; mq < 2; ++mq) {
      f32x4 c4 = *(const f32x4*)&corr_l[wq + mq * 16 + kg * 4];
      #pragma unroll
      for (int nd = 0; nd < 4; ++nd)
        #pragma unroll
        for (int r = 0; r < 4; ++r) acc_o[mq][nd][r] *= c4[r];
    }
    __builtin_amdgcn_s_setprio(1);
    #pragma unroll
    for (int kk = 0; kk < 2; ++kk) {
      bf16x8 pf[2], vf[4];
      #pragma unroll
      for (int mq = 0; mq < 2; ++mq) {
        int row = wq + mq * 16 + l15;
        int kvs = (kk * 32 + kg * 8) ^ ((row & 7) << 3);
        pf[mq] = *(const bf16x8*)(Psm + row * 64 + kvs);
      }
      #pragma unroll
      for (int nd = 0; nd < 4; ++nd) {
        int vrow = nd * 16 + l15;
        vf[nd] = *(const bf16x8*)(Vs + vrow * 64 + (((kk * 4 + kg) ^ (vrow & 7)) << 3));
      }
      #pragma unroll
      for (int mq = 0; mq < 2; ++mq)
        #pragma unroll
        for (int nd = 0; nd < 4; ++nd)
          acc_o[mq][nd] = __builtin_amdgcn_mfma_f32_16x16x32_bf16(
              pf[mq], vf[nd], acc_o[mq][nd], 0, 0, 0);
    }
    __builtin_amdgcn_s_setprio(0);
    rb = rb == 2 ? 0 : rb + 1;
  }

  #pragma unroll
  for (int nq = 0; nq < 2; ++nq)
    if (kg == 0) l_l[wq + nq * 16 + l15] = l_run[nq];
  __syncthreads();

  #pragma unroll
  for (int mq = 0; mq < 2; ++mq) {
    f32x4 lv = *(const f32x4*)&l_l[wq + mq * 16 + kg * 4];
    #pragma unroll
    for (int nd = 0; nd < 4; ++nd) {
      int col = h * 64 + nd * 16 + l15;
      #pragma unroll
      for (int r = 0; r < 4; ++r) {
        int qrow = qt + wq + mq * 16 + kg * 4 + r;
        Ob[(size_t)(b * 1024 + qrow) * 1024 + col] = (__bf16)(acc_o[mq][nd][r] / lv[r]);
      }
    }
  }
}

extern "C" void kernel_launch(void* const* d_in, const int* in_sizes, int n_in,
                              void* d_out, int out_size, void* d_ws, size_t ws_size,
                              hipStream_t stream) {
  (void)in_sizes; (void)n_in; (void)out_size; (void)ws_size;
  const float* queries   = (const float*)d_in[0];
  const float* contexts  = (const float*)d_in[1];
  const float* qhid      = (const float*)d_in[2];
  const float* sa_norm_w = (const float*)d_in[3];
  const float* sa_norm_b = (const float*)d_in[4];
  const float* sa_qkv_w  = (const float*)d_in[5];
  const float* sa_out_w  = (const float*)d_in[6];
  const float* sa_out_b  = (const float*)d_in[7];
  const float* ca_norm_w = (const float*)d_in[8];
  const float* ca_norm_b = (const float*)d_in[9];
  const float* gru_w_ih  = (const float*)d_in[10];
  const float* gru_w_hh  = (const float*)d_in[11];
  const float* gru_b_ih  = (const float*)d_in[12];
  const float* gru_b_hh  = (const float*)d_in[13];
  const float* ca_k_w    = (const float*)d_in[14];
  const float* ca_v_w    = (const float*)d_in[15];
  const float* ca_out_w  = (const float*)d_in[16];
  const float* ca_out_b  = (const float*)d_in[17];
  const float* ln1_w     = (const float*)d_in[18];
  const float* ln1_b     = (const float*)d_in[19];
  const float* lin1_w    = (const float*)d_in[20];
  const float* ln2_w     = (const float*)d_in[21];
  const float* ln2_b     = (const float*)d_in[22];
  const float* lin2_w    = (const float*)d_in[23];

  float* out0   = (float*)d_out;               // [4096,1024]
  float* energy = out0 + (size_t)4194304;      // [64,1024,1024]
  float* qh_out = out0 + (size_t)71303168;     // [4096,1024]

  // ---- workspace map (units: MM = 1M floats = 4 MiB) ----
  const size_t MM = 1u << 20;
  float* ws = (float*)d_ws;
  float*  X     = ws;
  float*  X2    = ws + 4 * MM;
  __bf16* M1B    = (__bf16*)(ws + 9 * MM);
  __bf16* XN_b   = (__bf16*)(ws + 17 * MM);
  __bf16* QHID_b = (__bf16*)(ws + 19 * MM);
  __bf16* CTX_b  = (__bf16*)(ws + 21 * MM);
  __bf16* O_b    = (__bf16*)(ws + 23 * MM);
  __bf16* VT_b   = (__bf16*)(ws + 25 * MM);
  __bf16* QKV_b  = (__bf16*)(ws + 27 * MM);
  __bf16* KV_b   = (__bf16*)(ws + 27 * MM);  // [4096][2048] bf16, reuses QKV after SA
  __bf16* LN2_b  = (__bf16*)(ws);            // reuses dead X
  __bf16* qkvT   = (__bf16*)(ws + 33 * MM);
  __bf16* ihB    = (__bf16*)(ws + 34 * MM + MM / 2);
  __bf16* hhB    = (__bf16*)(ws + 36 * MM);
  __bf16* kT     = (__bf16*)(ws + 37 * MM + MM / 2);  // kT,vT contiguous => merged B [2048][1024]
  __bf16* vT     = (__bf16*)(ws + 38 * MM);
  __bf16* saoT   = (__bf16*)(ws + 38 * MM + MM / 2);
  __bf16* caoT   = (__bf16*)(ws + 39 * MM);
  __bf16* lin1T  = (__bf16*)(ws + 39 * MM + MM / 2);
  __bf16* lin2T  = (__bf16*)(ws + 40 * MM + MM / 2);
  __bf16* GI_b = (__bf16*)energy;            // [4096][3072] bf16 = 24 MB
  __bf16* GH_b = (__bf16*)(energy + 6 * MM); // next 24 MB

  const long long QKV_SB = 1024LL * 3072;
  const long long KV_SB  = 1024LL * 2048;

  // ---- fused prep: all weight transposes + casts + ln_sa ----
  prep_all<<<14080, 256, 0, stream>>>(
      sa_qkv_w, ca_k_w, ca_v_w, sa_out_w, ca_out_w, lin1_w, lin2_w,
      gru_w_ih, gru_w_hh, qhid, contexts, queries, sa_norm_w, sa_norm_b,
      qkvT, kT, vT, saoT, caoT, lin1T, lin2T, ihB, hhB, QHID_b, CTX_b, XN_b);

  // ---- SelfAttention ----
  // qkv GEMM writes Q,K rows to QKV_b and V stripes transposed into VT_b (vmode=1)
  gemm_bf16<<<dim3(24, 32), 256, 0, stream>>>(
      XN_b, 1024, qkvT, 1024, nullptr, QKV_b, 3072, nullptr, nullptr, 1024, VT_b, 1);
  flash_attn<0><<<dim3(8, 64), 256, 0, stream>>>(
      QKV_b, QKV_SB, 192, 3072, QKV_b + 64, QKV_SB, 192, 3072,
      VT_b, O_b, nullptr, SCALE);
  // sa_out (256 blocks, chain) merged with gh (768 blocks, independent after prep)
  gemm_dual<<<1024, 256, 0, stream>>>(
      O_b, 1024, saoT, 1024, X, nullptr, 1024, sa_out_b, queries, 1024, 8, 256,
      QHID_b, 1024, hhB, 1024, nullptr, GH_b, 3072, gru_b_hh, nullptr, 1024, 24,
      nullptr, 0);

  // ---- GRU dynamic query ----
  ln_bf16<1><<<4096, 256, 0, stream>>>(X, nullptr, ca_norm_w, ca_norm_b, XN_b, 0);
  // gi (768 blocks, chain) merged with CA kv projection (512 blocks, independent);
  // kv writes K rows to KV_b and V stripes transposed into VT_b (vmode=2)
  gemm_dual<<<1280, 256, 0, stream>>>(
      XN_b, 1024, ihB, 1024, nullptr, GI_b, 3072, gru_b_ih, nullptr, 1024, 24, 768,
      CTX_b, 1024, kT, 1024, nullptr, KV_b, 2048, nullptr, nullptr, 1024, 16,
      VT_b, 2);
  gru_kernel<<<2048, 256, 0, stream>>>(GI_b, GH_b, qhid, qh_out, QHID_b /*now QHB*/);

  // ---- Cross attention ----
  flash_attn<1><<<dim3(8, 64), 256, 0, stream>>>(
      QHID_b, 1024LL * 1024, 64, 1024, KV_b, KV_SB, 64, 2048,
      VT_b, O_b, energy, SCALE);
  gemm_bf16<<<dim3(8, 32), 256, 0, stream>>>(
      O_b, 1024, caoT, 1024, X2, nullptr, 1024, ca_out_b, X, 1024, nullptr, 0);

  // ---- MLP ----
  ln_bf16<1><<<4096, 256, 0, stream>>>(X2, nullptr, ln1_w, ln1_b, XN_b, 1);
  gemm_bf16<<<dim3(16, 32), 256, 0, stream>>>(
      XN_b, 1024, lin1T, 1024, nullptr, M1B, 2048, nullptr, nullptr, 1024, nullptr, 0);
  ln_bf16<2><<<4096, 256, 0, stream>>>(nullptr, M1B, ln2_w, ln2_b, LN2_b, 1);
  gemm_bf16<<<dim3(8, 32), 256, 0, stream>>>(
      LN2_b, 2048, lin2T, 2048, out0, nullptr, 1024, nullptr, X2, 2048, nullptr, 0);
}

// Round 8
// 590.964 us; speedup vs baseline: 1.1149x; 1.0314x over previous
//
#include <hip/hip_runtime.h>
#include <hip/hip_bf16.h>
#include <math.h>

static constexpr float SCALE = 0.03125f; // 1/sqrt(1024)

typedef __attribute__((ext_vector_type(4))) float f32x4;
typedef __attribute__((ext_vector_type(8))) __bf16 bf16x8;
typedef __attribute__((ext_vector_type(4))) __bf16 bf16x4;

__device__ __forceinline__ void g2l16(const void* g, void* l) {
  __builtin_amdgcn_global_load_lds(
      (const __attribute__((address_space(1))) unsigned int*)g,
      (__attribute__((address_space(3))) unsigned int*)l,
      16, 0, 0);
}

// ---------------- prep helpers (shared by prep_crit and the merged gemm_prep) ----------
// 64x64 fp32->bf16 transpose tile; tile buffer supplied by caller (16.6 KB as float[64][65]).
__device__ __forceinline__ void wtrans_tile(
    const float* __restrict__ src, __bf16* __restrict__ dst,
    int Kd, int N, int tid, float (*tile)[65]) {
  int t = threadIdx.x;
  int ntx = N >> 6;
  int n0 = (tid % ntx) * 64, k0 = (tid / ntx) * 64;
  #pragma unroll
  for (int i = 0; i < 16; ++i) {
    int idx = i * 256 + t; int r = idx >> 6, c = idx & 63;
    tile[r][c] = src[(size_t)(k0 + r) * N + n0 + c];
  }
  __syncthreads();
  #pragma unroll
  for (int i = 0; i < 16; ++i) {
    int idx = i * 256 + t; int r = idx >> 6, c = idx & 63;
    dst[(size_t)(n0 + r) * Kd + k0 + c] = (__bf16)tile[c][r];
  }
}

// ---------------- prep_crit: qkvT transpose (768 tiles) + ln_sa (4096 rows) -------------
// Only the pieces the qkv GEMM needs; everything else rides inside the qkv launch.
__global__ __launch_bounds__(256) void prep_crit(
    const float* __restrict__ sa_qkv_w,
    const float* __restrict__ queries, const float* __restrict__ sa_norm_w,
    const float* __restrict__ sa_norm_b,
    __bf16* __restrict__ qkvT, __bf16* __restrict__ xnB) {
  int bid = blockIdx.x;
  int t = threadIdx.x;
  if (bid < 768) {
    __shared__ float tile[64][65];
    wtrans_tile(sa_qkv_w, qkvT, 1024, 3072, bid, tile);
    return;
  }
  // ---- LayerNorm(queries) -> xnB, D=1024 ----
  int row = bid - 768;
  int c = t * 4;
  float4 v = *(const float4*)(queries + (size_t)row * 1024 + c);
  float s = v.x + v.y + v.z + v.w;
  float s2 = v.x*v.x + v.y*v.y + v.z*v.z + v.w*v.w;
  #pragma unroll
  for (int off = 32; off > 0; off >>= 1) {
    s += __shfl_xor(s, off);
    s2 += __shfl_xor(s2, off);
  }
  __shared__ float red[4], red2[4];
  int wv = t >> 6;
  if ((t & 63) == 0) { red[wv] = s; red2[wv] = s2; }
  __syncthreads();
  float S  = red[0] + red[1] + red[2] + red[3];
  float S2 = red2[0] + red2[1] + red2[2] + red2[3];
  float mean = S / 1024.f;
  float var = S2 / 1024.f - mean * mean;
  float rs = rsqrtf(var + 1e-5f);
  float vv[4] = {v.x, v.y, v.z, v.w};
  bf16x4 o;
  #pragma unroll
  for (int j = 0; j < 4; ++j)
    o[j] = (__bf16)((vv[j] - mean) * rs * sa_norm_w[c+j] + sa_norm_b[c+j]);
  *(bf16x4*)(xnB + (size_t)row * 1024 + c) = o;
}

// ---------------- LayerNorm (+ optional SiLU) -> bf16, fp32 or bf16 input ----------------
template <int NV>  // NV = D/1024 (4*NV elems/thread)
__global__ __launch_bounds__(256) void ln_bf16(
    const float* __restrict__ xf, const __bf16* __restrict__ xb,
    const float* __restrict__ w, const float* __restrict__ b,
    __bf16* __restrict__ out, int silu) {
  const int D = NV * 1024;
  int row = blockIdx.x, t = threadIdx.x;
  float vals[NV * 4];
  float s = 0.f, s2 = 0.f;
  #pragma unroll
  for (int i = 0; i < NV; ++i) {
    int c = (i * 256 + t) * 4;
    float4 v;
    if (xf) {
      v = *(const float4*)(xf + (size_t)row * D + c);
    } else {
      bf16x4 vb = *(const bf16x4*)(xb + (size_t)row * D + c);
      v = make_float4((float)vb[0], (float)vb[1], (float)vb[2], (float)vb[3]);
    }
    vals[i*4+0] = v.x; vals[i*4+1] = v.y; vals[i*4+2] = v.z; vals[i*4+3] = v.w;
    s += v.x + v.y + v.z + v.w;
    s2 += v.x*v.x + v.y*v.y + v.z*v.z + v.w*v.w;
  }
  #pragma unroll
  for (int off = 32; off > 0; off >>= 1) {
    s += __shfl_xor(s, off);
    s2 += __shfl_xor(s2, off);
  }
  __shared__ float red[4], red2[4];
  int wv = t >> 6;
  if ((t & 63) == 0) { red[wv] = s; red2[wv] = s2; }
  __syncthreads();
  float S  = red[0] + red[1] + red[2] + red[3];
  float S2 = red2[0] + red2[1] + red2[2] + red2[3];
  float mean = S / D;
  float var = S2 / D - mean * mean;
  float rs = rsqrtf(var + 1e-5f);
  #pragma unroll
  for (int i = 0; i < NV; ++i) {
    int c = (i * 256 + t) * 4;
    bf16x4 o;
    #pragma unroll
    for (int j = 0; j < 4; ++j) {
      float v = (vals[i*4+j] - mean) * rs * w[c+j] + b[c+j];
      if (silu) v = v / (1.f + __expf(-v));
      o[j] = (__bf16)v;
    }
    *(bf16x4*)(out + (size_t)row * D + c) = o;
  }
}

// ---------------- bf16 MFMA GEMM core, 2-buffer stage-early/drain-late pipeline ----------
// C[M,N] = A[M,K] @ B^T; B stored [N][K]. Tile 128x128, BK=64, 4 waves.
// LDS (64 KB) supplied by the caller: sm[0..8191]=Asm0, [8192..16383]=Bsm0,
// [16384..24575]=Asm1, [24576..32767]=Bsm1.
// vmode: 0 = plain epilogue. 1/2 = V-transpose epilogue (wave-private scratch in
// Asm0/Bsm0, dead after last barrier); values identical to the old vtrans copy.
__device__ __forceinline__ void gemm_body(
    __bf16* __restrict__ sm,
    const __bf16* __restrict__ A, long long lda,
    const __bf16* __restrict__ B, long long ldb,
    float* __restrict__ outF, __bf16* __restrict__ outB, long long ldc,
    const float* __restrict__ bias, const float* __restrict__ res,
    int K, int bm, int bn, __bf16* __restrict__ VTout, int vmode) {
  __bf16* Asm0 = sm;
  __bf16* Bsm0 = sm + 8192;
  __bf16* Asm1 = sm + 16384;
  __bf16* Bsm1 = sm + 24576;
  int t = threadIdx.x;
  int lane = t & 63, w = t >> 6;
  int l15 = lane & 15, kg = lane >> 4;
  int wm = (w >> 1) * 64, wn = (w & 1) * 64;

  f32x4 acc[4][4];
  #pragma unroll
  for (int i = 0; i < 4; ++i)
    #pragma unroll
    for (int j = 0; j < 4; ++j) acc[i][j] = (f32x4)(0.0f);

  const __bf16* ga[4]; const __bf16* gb[4];
  int lo[4];
  #pragma unroll
  for (int i = 0; i < 4; ++i) {
    int slot = i * 256 + t;
    int row = slot >> 3, s = slot & 7;
    int sx = s ^ (row & 7);
    ga[i] = A + (size_t)(bm + row) * lda + (sx << 3);
    gb[i] = B + (size_t)(bn + row) * ldb + (sx << 3);
    lo[i] = (i * 256 + w * 64) << 3;
  }

  auto STAGE = [&](__bf16* As, __bf16* Bs, int k0) {
    #pragma unroll
    for (int i = 0; i < 4; ++i) g2l16(ga[i] + k0, As + lo[i]);
    #pragma unroll
    for (int i = 0; i < 4; ++i) g2l16(gb[i] + k0, Bs + lo[i]);
  };
  auto COMPUTE = [&](const __bf16* As, const __bf16* Bs) {
    #pragma unroll
    for (int kk = 0; kk < 2; ++kk) {
      bf16x8 af[4], bfr[4];
      #pragma unroll
      for (int mi = 0; mi < 4; ++mi) {
        int row = wm + mi * 16 + l15;
        int ks = kk * 4 + kg;
        af[mi] = *(const bf16x8*)(As + row * 64 + ((ks ^ (row & 7)) << 3));
      }
      #pragma unroll
      for (int ni = 0; ni < 4; ++ni) {
        int row = wn + ni * 16 + l15;
        int ks = kk * 4 + kg;
        bfr[ni] = *(const bf16x8*)(Bs + row * 64 + ((ks ^ (row & 7)) << 3));
      }
      #pragma unroll
      for (int mi = 0; mi < 4; ++mi)
        #pragma unroll
        for (int ni = 0; ni < 4; ++ni)
          acc[mi][ni] = __builtin_amdgcn_mfma_f32_16x16x32_bf16(
              af[mi], bfr[ni], acc[mi][ni], 0, 0, 0);
    }
  };
  #define GEMM_SYNC() do { \
    asm volatile("s_waitcnt vmcnt(0)" ::: "memory"); \
    __builtin_amdgcn_s_barrier(); \
    __builtin_amdgcn_sched_barrier(0); \
  } while (0)

  STAGE(Asm0, Bsm0, 0);
  GEMM_SYNC();
  int nk = K >> 6;  // even
  for (int kt = 0; kt + 2 < nk; kt += 2) {
    STAGE(Asm1, Bsm1, (kt + 1) << 6);
    COMPUTE(Asm0, Bsm0);
    GEMM_SYNC();
    STAGE(Asm0, Bsm0, (kt + 2) << 6);
    COMPUTE(Asm1, Bsm1);
    GEMM_SYNC();
  }
  // tail: tiles nk-2 (in buf0), nk-1
  STAGE(Asm1, Bsm1, (nk - 1) << 6);
  COMPUTE(Asm0, Bsm0);
  GEMM_SYNC();
  COMPUTE(Asm1, Bsm1);
  #undef GEMM_SYNC

  int cw = bn + wn;
  int isV = 0;
  if (vmode == 1)      isV = (cw % 192) == 128;
  else if (vmode == 2) isV = cw >= 1024;

  if (isV) {
    // ---- V-transpose epilogue (wave-private; Asm0/Bsm0 dead after last barrier) ----
    int h = (vmode == 1) ? (cw / 192) : ((cw - 1024) >> 6);
    int rowb = bm + wm;               // 64 rows, within one batch (64-aligned)
    int b = rowb >> 10, k0 = rowb & 1023;
    __bf16* scr = (w < 2 ? Asm0 : Bsm0) + (w & 1) * 4096;  // 64x64 bf16 = 4096 elems
    #pragma unroll
    for (int mi = 0; mi < 4; ++mi) {
      #pragma unroll
      for (int ni = 0; ni < 4; ++ni) {
        int d = ni * 16 + l15;
        int sw = (d & 7) << 3;
        #pragma unroll
        for (int r = 0; r < 4; ++r) {
          int kl = mi * 16 + kg * 4 + r;
          scr[d * 64 + (kl ^ sw)] = (__bf16)acc[mi][ni][r];
        }
      }
    }
    // read back transposed: 8 iters x 64 lanes cover 64 d x 8 chunks of 8 k
    #pragma unroll
    for (int i = 0; i < 8; ++i) {
      int idx = i * 64 + lane;
      int d = idx >> 3, kc = (idx & 7) * 8;
      bf16x8 v = *(const bf16x8*)&scr[d * 64 + (kc ^ ((d & 7) << 3))];
      *(bf16x8*)(VTout + ((size_t)((b * 16 + h) * 64 + d) << 10) + k0 + kc) = v;
    }
    return;
  }

  #pragma unroll
  for (int mi = 0; mi < 4; ++mi) {
    #pragma unroll
    for (int ni = 0; ni < 4; ++ni) {
      int rbase = bm + wm + mi * 16 + kg * 4;
      int c = bn + wn + ni * 16 + l15;
      #pragma unroll
      for (int r = 0; r < 4; ++r) {
        float val = acc[mi][ni][r];
        if (bias) val += bias[c];
        size_t off = (size_t)(rbase + r) * ldc + c;
        if (res) val += res[off];
        if (outF) outF[off] = val;
        if (outB) outB[off] = (__bf16)val;
      }
    }
  }
}

// Single-GEMM kernel (2D grid, XCD-aware swizzle; nwg divisible by 8 at all call sites).
__global__ __launch_bounds__(256) void gemm_bf16(
    const __bf16* __restrict__ A, long long lda,
    const __bf16* __restrict__ B, long long ldb,
    float* __restrict__ outF, __bf16* __restrict__ outB, long long ldc,
    const float* __restrict__ bias, const float* __restrict__ res, int K,
    __bf16* __restrict__ VTout, int vmode) {
  __shared__ __bf16 sm[32768];
  int nwg = gridDim.x * gridDim.y;
  int orig = blockIdx.y * gridDim.x + blockIdx.x;
  int swz = (orig & 7) * (nwg >> 3) + (orig >> 3);
  gemm_body(sm, A, lda, B, ldb, outF, outB, ldc, bias, res, K,
            (swz / gridDim.x) * 128, (swz % gridDim.x) * 128, VTout, vmode);
}

// Dual-GEMM kernel: two independent GEMMs in one launch (1D grid, blocks < nb0 -> p0).
__global__ __launch_bounds__(256) void gemm_dual(
    const __bf16* __restrict__ A0, long long lda0, const __bf16* __restrict__ B0, long long ldb0,
    float* __restrict__ oF0, __bf16* __restrict__ oB0, long long ldc0,
    const float* __restrict__ bias0, const float* __restrict__ res0, int K0, int gx0, int nb0,
    const __bf16* __restrict__ A1, long long lda1, const __bf16* __restrict__ B1, long long ldb1,
    float* __restrict__ oF1, __bf16* __restrict__ oB1, long long ldc1,
    const float* __restrict__ bias1, const float* __restrict__ res1, int K1, int gx1,
    __bf16* __restrict__ VT1, int vm1) {
  __shared__ __bf16 sm[32768];
  int bid = blockIdx.x;
  if (bid < nb0) {
    int swz = (bid & 7) * (nb0 >> 3) + (bid >> 3);
    gemm_body(sm, A0, lda0, B0, ldb0, oF0, oB0, ldc0, bias0, res0, K0,
              (swz / gx0) * 128, (swz % gx0) * 128, nullptr, 0);
  } else {
    int b = bid - nb0;
    int nb1 = gridDim.x - nb0;
    int swz = (b & 7) * (nb1 >> 3) + (b >> 3);
    gemm_body(sm, A1, lda1, B1, ldb1, oF1, oB1, ldc1, bias1, res1, K1,
              (swz / gx1) * 128, (swz % gx1) * 128, VT1, vm1);
  }
}

// ---------------- qkv GEMM (blocks 0-767, vmode=1) + prep-rest (blocks 768-9983) --------
// prep-rest block map (same ids as the old prep_all): kT 768-1023 | vT 1024-1279 |
// saoT 1280-1535 | caoT 1536-1791 | lin1T 1792-2303 | lin2T 2304-2815 |
// ihB 2816-4351 | hhB 4352-5887 | qhid 5888-7935 | ctx 7936-9983.
// All prep-rest outputs are first consumed >= 2 launches later (sa_out+gh), so they
// legally ride behind the qkv GEMM blocks, overlapping prep traffic with GEMM compute.
// Both branches share one 64 KB LDS block (prep tile uses it as float[64][65]).
__global__ __launch_bounds__(256) void gemm_prep(
    const __bf16* __restrict__ Aq, const __bf16* __restrict__ Bq,
    __bf16* __restrict__ Cq, __bf16* __restrict__ VTq,
    const float* __restrict__ ca_k_w, const float* __restrict__ ca_v_w,
    const float* __restrict__ sa_out_w, const float* __restrict__ ca_out_w,
    const float* __restrict__ lin1_w, const float* __restrict__ lin2_w,
    const float* __restrict__ gru_w_ih, const float* __restrict__ gru_w_hh,
    const float* __restrict__ qhid, const float* __restrict__ contexts,
    __bf16* __restrict__ kT, __bf16* __restrict__ vT, __bf16* __restrict__ saoT,
    __bf16* __restrict__ caoT, __bf16* __restrict__ lin1T, __bf16* __restrict__ lin2T,
    __bf16* __restrict__ ihB, __bf16* __restrict__ hhB,
    __bf16* __restrict__ qhB, __bf16* __restrict__ ctxB) {
  __shared__ __bf16 sm[32768];
  int bid = blockIdx.x;
  int t = threadIdx.x;
  if (bid < 768) {
    int swz = (bid & 7) * 96 + (bid >> 3);
    gemm_body(sm, Aq, 1024, Bq, 1024, nullptr, Cq, 3072, nullptr, nullptr, 1024,
              (swz / 24) * 128, (swz % 24) * 128, VTq, 1);
    return;
  }
  if (bid >= 2816) {  // casts, 8 elems/thread
    const float* csrc; __bf16* cdst; int cbase;
    if (bid < 4352)      { csrc = gru_w_ih; cdst = ihB;  cbase = 2816; }
    else if (bid < 5888) { csrc = gru_w_hh; cdst = hhB;  cbase = 4352; }
    else if (bid < 7936) { csrc = qhid;     cdst = qhB;  cbase = 5888; }
    else                 { csrc = contexts; cdst = ctxB; cbase = 7936; }
    size_t idx = ((size_t)(bid - cbase) * 256 + t) * 8;
    float4 a = *(const float4*)(csrc + idx);
    float4 b = *(const float4*)(csrc + idx + 4);
    bf16x8 o = {(__bf16)a.x,(__bf16)a.y,(__bf16)a.z,(__bf16)a.w,
                (__bf16)b.x,(__bf16)b.y,(__bf16)b.z,(__bf16)b.w};
    *(bf16x8*)(cdst + idx) = o;
    return;
  }
  const float* src; __bf16* dst; int Kd, N, base;
  if (bid < 1024)      { src = ca_k_w;   dst = kT;    Kd = 1024; N = 1024; base = 768; }
  else if (bid < 1280) { src = ca_v_w;   dst = vT;    Kd = 1024; N = 1024; base = 1024; }
  else if (bid < 1536) { src = sa_out_w; dst = saoT;  Kd = 1024; N = 1024; base = 1280; }
  else if (bid < 1792) { src = ca_out_w; dst = caoT;  Kd = 1024; N = 1024; base = 1536; }
  else if (bid < 2304) { src = lin1_w;   dst = lin1T; Kd = 1024; N = 2048; base = 1792; }
  else                 { src = lin2_w;   dst = lin2T; Kd = 2048; N = 1024; base = 2304; }
  wtrans_tile(src, dst, Kd, N, bid - base, (float(*)[65])sm);
}

// ---------------- GRU cell elementwise, bf16 inputs, 8 elems/thread ----------------
__global__ __launch_bounds__(256) void gru_kernel(
    const __bf16* __restrict__ gi, const __bf16* __restrict__ gh,
    const float* __restrict__ hf, float* __restrict__ qh, __bf16* __restrict__ qhb) {
  size_t e0 = ((size_t)blockIdx.x * 256 + threadIdx.x) * 8;  // over 4M elems
  int row = (int)(e0 >> 10), col = (int)(e0 & 1023);
  size_t base = (size_t)row * 3072 + col;
  bf16x8 vir = *(const bf16x8*)(gi + base);
  bf16x8 viz = *(const bf16x8*)(gi + base + 1024);
  bf16x8 vin = *(const bf16x8*)(gi + base + 2048);
  bf16x8 vhr = *(const bf16x8*)(gh + base);
  bf16x8 vhz = *(const bf16x8*)(gh + base + 1024);
  bf16x8 vhn = *(const bf16x8*)(gh + base + 2048);
  float4 h0 = *(const float4*)(hf + e0);
  float4 h1 = *(const float4*)(hf + e0 + 4);
  float hv[8] = {h0.x, h0.y, h0.z, h0.w, h1.x, h1.y, h1.z, h1.w};
  float q[8];
  #pragma unroll
  for (int j = 0; j < 8; ++j) {
    float r = 1.f / (1.f + __expf(-((float)vir[j] + (float)vhr[j])));
    float z = 1.f / (1.f + __expf(-((float)viz[j] + (float)vhz[j])));
    float n = tanhf((float)vin[j] + r * (float)vhn[j]);
    q[j] = (1.f - z) * n + z * hv[j];
  }
  *(float4*)(qh + e0)     = make_float4(q[0], q[1], q[2], q[3]);
  *(float4*)(qh + e0 + 4) = make_float4(q[4], q[5], q[6], q[7]);
  bf16x8 qb;
  #pragma unroll
  for (int j = 0; j < 8; ++j) qb[j] = (__bf16)q[j];
  *(bf16x8*)(qhb + e0) = qb;
}

// ---------------- Fused flash attention, 3-deep pipelined K/V staging ----------------
// Per g=(b,h): O[q][d] = softmax_kv(S*scale) @ V, S = Q @ K^T (head dim 64).
// Swapped QK^T -> S^T acc (col=q=l15). P -> LDS packed bf16x4, XOR-swizzled.
// Psm/corr_l/l_l are wave-private rows => ONE raw s_barrier per tile suffices;
// staging for tile t+2 issued after the barrier (3 LDS buffers), waited with
// counted vmcnt (never 0 mid-loop). E: raw S stored nontemporally (268 MB stream).
template <int E>
__global__ __launch_bounds__(256) void flash_attn(
    const __bf16* __restrict__ Qb, long long q_sb, long long q_sh, int q_sm,
    const __bf16* __restrict__ Kb, long long k_sb, long long k_sh, int k_sm,
    const __bf16* __restrict__ VT, __bf16* __restrict__ Ob,
    float* __restrict__ energyOut, float scale) {
  __shared__ __bf16 Ksm[3][4096];
  __shared__ __bf16 Vsm[3][4096];
  __shared__ __bf16 Psm[128 * 64];
  __shared__ float corr_l[128];
  __shared__ float l_l[128];
  int g = blockIdx.y, b = g >> 4, h = g & 15;
  int qt = blockIdx.x * 128;
  const __bf16* Qg = Qb + (size_t)b * q_sb + (size_t)h * q_sh;
  const __bf16* Kg = Kb + (size_t)b * k_sb + (size_t)h * k_sh;
  const __bf16* Vg = VT + (size_t)g * 65536;
  int t = threadIdx.x, lane = t & 63, w = t >> 6;
  int l15 = lane & 15, kg = lane >> 4;
  int wq = w * 32;

  bf16x8 qf[2][2];
  #pragma unroll
  for (int nq = 0; nq < 2; ++nq)
    #pragma unroll
    for (int kk = 0; kk < 2; ++kk)
      qf[nq][kk] = *(const bf16x8*)(
          Qg + (size_t)(qt + wq + nq * 16 + l15) * q_sm + kk * 32 + kg * 8);

  f32x4 acc_o[2][4];
  #pragma unroll
  for (int i = 0; i < 2; ++i)
    #pragma unroll
    for (int j = 0; j < 4; ++j) acc_o[i][j] = (f32x4)(0.0f);
  float m_run[2] = {-1e30f, -1e30f};
  float l_run[2] = {0.f, 0.f};

  const __bf16* gK[2]; const __bf16* gV[2];
  int lo[2];
  #pragma unroll
  for (int i = 0; i < 2; ++i) {
    int slot = i * 256 + t;
    int row = slot >> 3, s = slot & 7, sx = s ^ (row & 7);
    gK[i] = Kg + (size_t)row * k_sm + (sx << 3);
    gV[i] = Vg + (size_t)row * 1024 + (sx << 3);
    lo[i] = (i * 256 + w * 64) << 3;
  }

  // prologue: stage tile 0 (4 oldest vmem ops) then tile 1
  #pragma unroll
  for (int i = 0; i < 2; ++i) g2l16(gK[i], &Ksm[0][lo[i]]);
  #pragma unroll
  for (int i = 0; i < 2; ++i) g2l16(gV[i], &Vsm[0][lo[i]]);
  #pragma unroll
  for (int i = 0; i < 2; ++i) g2l16(gK[i] + (size_t)64 * k_sm, &Ksm[1][lo[i]]);
  #pragma unroll
  for (int i = 0; i < 2; ++i) g2l16(gV[i] + 64, &Vsm[1][lo[i]]);

  int rb = 0;  // read buffer = kvt % 3
  for (int kvt = 0; kvt < 16; ++kvt) {
    // counted wait: exactly the newer-than-stage-kvt op count (4 loads/tile, 8 stores/tile if E)
    if (E) {
      if (kvt == 0)       asm volatile("s_waitcnt vmcnt(4)" ::: "memory");
      else if (kvt == 1)  asm volatile("s_waitcnt vmcnt(12)" ::: "memory");
      else if (kvt == 15) asm volatile("s_waitcnt vmcnt(16)" ::: "memory");
      else                asm volatile("s_waitcnt vmcnt(20)" ::: "memory");
    } else {
      if (kvt == 15)      asm volatile("s_waitcnt vmcnt(0)" ::: "memory");
      else                asm volatile("s_waitcnt vmcnt(4)" ::: "memory");
    }
    __builtin_amdgcn_s_barrier();
    __builtin_amdgcn_sched_barrier(0);  // pin: no memory op crosses the barrier

    if (kvt < 14) {  // stage tile kvt+2 (after barrier: all waves done reading that buffer)
      int sbuf = rb >= 1 ? rb - 1 : rb + 2;  // (kvt+2)%3
      size_t ko = (size_t)(kvt + 2) << 6;
      #pragma unroll
      for (int i = 0; i < 2; ++i) g2l16(gK[i] + ko * k_sm, &Ksm[sbuf][lo[i]]);
      #pragma unroll
      for (int i = 0; i < 2; ++i) g2l16(gV[i] + ko, &Vsm[sbuf][lo[i]]);
    }
    const __bf16* Ks = Ksm[rb];
    const __bf16* Vs = Vsm[rb];

    f32x4 accs[4][2];
    #pragma unroll
    for (int i = 0; i < 4; ++i)
      #pragma unroll
      for (int j = 0; j < 2; ++j) accs[i][j] = (f32x4)(0.0f);
    __builtin_amdgcn_s_setprio(1);
    #pragma unroll
    for (int tt = 0; tt < 4; ++tt) {
      bf16x8 kf[2];
      #pragma unroll
      for (int kk = 0; kk < 2; ++kk) {
        int row = tt * 16 + l15;
        int ks = kk * 4 + kg;
        kf[kk] = *(const bf16x8*)(Ks + row * 64 + ((ks ^ (row & 7)) << 3));
      }
      #pragma unroll
      for (int nq = 0; nq < 2; ++nq)
        #pragma unroll
        for (int kk = 0; kk < 2; ++kk)
          accs[tt][nq] = __builtin_amdgcn_mfma_f32_16x16x32_bf16(
              kf[kk], qf[nq][kk], accs[tt][nq], 0, 0, 0);
    }
    __builtin_amdgcn_s_setprio(0);

    if (E) {
      int kv0 = kvt << 6;
      float* eg = energyOut + ((size_t)g << 20);
      #pragma unroll
      for (int nq = 0; nq < 2; ++nq) {
        int q = qt + wq + nq * 16 + l15;
        #pragma unroll
        for (int tt = 0; tt < 4; ++tt)
          __builtin_nontemporal_store(
              accs[tt][nq], (f32x4*)(eg + (size_t)q * 1024 + kv0 + tt * 16 + kg * 4));
      }
    }

    #pragma unroll
    for (int nq = 0; nq < 2; ++nq) {
      float tmax = -1e30f;
      #pragma unroll
      for (int tt = 0; tt < 4; ++tt)
        #pragma unroll
        for (int r = 0; r < 4; ++r) tmax = fmaxf(tmax, accs[tt][nq][r]);
      tmax *= scale;
      tmax = fmaxf(tmax, __shfl_xor(tmax, 16));
      tmax = fmaxf(tmax, __shfl_xor(tmax, 32));
      float m_new = fmaxf(m_run[nq], tmax);
      float corr = __expf(m_run[nq] - m_new);
      m_run[nq] = m_new;
      int q = wq + nq * 16 + l15;
      float psum = 0.f;
      #pragma unroll
      for (int tt = 0; tt < 4; ++tt) {
        bf16x4 p4;
        #pragma unroll
        for (int r = 0; r < 4; ++r) {
          float p = __expf(accs[tt][nq][r] * scale - m_new);
          psum += p;
          p4[r] = (__bf16)p;
        }
        int kvs = (tt * 16 + kg * 4) ^ ((q & 7) << 3);
        *(bf16x4*)(Psm + q * 64 + kvs) = p4;
      }
      psum += __shfl_xor(psum, 16);
      psum += __shfl_xor(psum, 32);
      l_run[nq] = l_run[nq] * corr + psum;
      if (kg == 0) corr_l[q] = corr;
    }
    // no barrier: Psm / corr_l rows are wave-private

    #pragma unroll
    for (int mq = 0; mq < 2; ++mq) {
      f32x4 c4 = *(const f32x4*)&corr_l[wq + mq * 16 + kg * 4];
      #pragma unroll
      for (int nd = 0; nd < 4; ++nd)
        #pragma unroll
        for (int r = 0; r < 4; ++r) acc_o[mq][nd][r] *= c4[r];
    }
    __builtin_amdgcn_s_setprio(1);
    #pragma unroll
    for (int kk = 0; kk < 2; ++kk) {
      bf16x8 pf[2], vf[4];
      #pragma unroll
      for (int mq = 0; mq < 2; ++mq) {
        int row = wq + mq * 16 + l15;
        int kvs = (kk * 32 + kg * 8) ^ ((row & 7) << 3);
        pf[mq] = *(const bf16x8*)(Psm + row * 64 + kvs);
      }
      #pragma unroll
      for (int nd = 0; nd < 4; ++nd) {
        int vrow = nd * 16 + l15;
        vf[nd] = *(const bf16x8*)(Vs + vrow * 64 + (((kk * 4 + kg) ^ (vrow & 7)) << 3));
      }
      #pragma unroll
      for (int mq = 0; mq < 2; ++mq)
        #pragma unroll
        for (int nd = 0; nd < 4; ++nd)
          acc_o[mq][nd] = __builtin_amdgcn_mfma_f32_16x16x32_bf16(
              pf[mq], vf[nd], acc_o[mq][nd], 0, 0, 0);
    }
    __builtin_amdgcn_s_setprio(0);
    rb = rb == 2 ? 0 : rb + 1;
  }

  #pragma unroll
  for (int nq = 0; nq < 2; ++nq)
    if (kg == 0) l_l[wq + nq * 16 + l15] = l_run[nq];
  __syncthreads();

  #pragma unroll
  for (int mq = 0; mq < 2; ++mq) {
    f32x4 lv = *(const f32x4*)&l_l[wq + mq * 16 + kg * 4];
    #pragma unroll
    for (int nd = 0; nd < 4; ++nd) {
      int col = h * 64 + nd * 16 + l15;
      #pragma unroll
      for (int r = 0; r < 4; ++r) {
        int qrow = qt + wq + mq * 16 + kg * 4 + r;
        Ob[(size_t)(b * 1024 + qrow) * 1024 + col] = (__bf16)(acc_o[mq][nd][r] / lv[r]);
      }
    }
  }
}

extern "C" void kernel_launch(void* const* d_in, const int* in_sizes, int n_in,
                              void* d_out, int out_size, void* d_ws, size_t ws_size,
                              hipStream_t stream) {
  (void)in_sizes; (void)n_in; (void)out_size; (void)ws_size;
  const float* queries   = (const float*)d_in[0];
  const float* contexts  = (const float*)d_in[1];
  const float* qhid      = (const float*)d_in[2];
  const float* sa_norm_w = (const float*)d_in[3];
  const float* sa_norm_b = (const float*)d_in[4];
  const float* sa_qkv_w  = (const float*)d_in[5];
  const float* sa_out_w  = (const float*)d_in[6];
  const float* sa_out_b  = (const float*)d_in[7];
  const float* ca_norm_w = (const float*)d_in[8];
  const float* ca_norm_b = (const float*)d_in[9];
  const float* gru_w_ih  = (const float*)d_in[10];
  const float* gru_w_hh  = (const float*)d_in[11];
  const float* gru_b_ih  = (const float*)d_in[12];
  const float* gru_b_hh  = (const float*)d_in[13];
  const float* ca_k_w    = (const float*)d_in[14];
  const float* ca_v_w    = (const float*)d_in[15];
  const float* ca_out_w  = (const float*)d_in[16];
  const float* ca_out_b  = (const float*)d_in[17];
  const float* ln1_w     = (const float*)d_in[18];
  const float* ln1_b     = (const float*)d_in[19];
  const float* lin1_w    = (const float*)d_in[20];
  const float* ln2_w     = (const float*)d_in[21];
  const float* ln2_b     = (const float*)d_in[22];
  const float* lin2_w    = (const float*)d_in[23];

  float* out0   = (float*)d_out;               // [4096,1024]
  float* energy = out0 + (size_t)4194304;      // [64,1024,1024]
  float* qh_out = out0 + (size_t)71303168;     // [4096,1024]

  // ---- workspace map (units: MM = 1M floats = 4 MiB) ----
  const size_t MM = 1u << 20;
  float* ws = (float*)d_ws;
  float*  X     = ws;
  float*  X2    = ws + 4 * MM;
  __bf16* M1B    = (__bf16*)(ws + 9 * MM);
  __bf16* XN_b   = (__bf16*)(ws + 17 * MM);
  __bf16* QHID_b = (__bf16*)(ws + 19 * MM);
  __bf16* CTX_b  = (__bf16*)(ws + 21 * MM);
  __bf16* O_b    = (__bf16*)(ws + 23 * MM);
  __bf16* VT_b   = (__bf16*)(ws + 25 * MM);
  __bf16* QKV_b  = (__bf16*)(ws + 27 * MM);
  __bf16* KV_b   = (__bf16*)(ws + 27 * MM);  // [4096][2048] bf16, reuses QKV after SA
  __bf16* LN2_b  = (__bf16*)(ws);            // reuses dead X
  __bf16* qkvT   = (__bf16*)(ws + 33 * MM);
  __bf16* ihB    = (__bf16*)(ws + 34 * MM + MM / 2);
  __bf16* hhB    = (__bf16*)(ws + 36 * MM);
  __bf16* kT     = (__bf16*)(ws + 37 * MM + MM / 2);  // kT,vT contiguous => merged B [2048][1024]
  __bf16* vT     = (__bf16*)(ws + 38 * MM);
  __bf16* saoT   = (__bf16*)(ws + 38 * MM + MM / 2);
  __bf16* caoT   = (__bf16*)(ws + 39 * MM);
  __bf16* lin1T  = (__bf16*)(ws + 39 * MM + MM / 2);
  __bf16* lin2T  = (__bf16*)(ws + 40 * MM + MM / 2);
  __bf16* GI_b = (__bf16*)energy;            // [4096][3072] bf16 = 24 MB
  __bf16* GH_b = (__bf16*)(energy + 6 * MM); // next 24 MB

  const long long QKV_SB = 1024LL * 3072;
  const long long KV_SB  = 1024LL * 2048;

  // ---- prep-critical: qkvT transpose + ln_sa (only what the qkv GEMM needs) ----
  prep_crit<<<4864, 256, 0, stream>>>(
      sa_qkv_w, queries, sa_norm_w, sa_norm_b, qkvT, XN_b);

  // ---- SelfAttention: qkv GEMM (Q,K rows + V transposed, vmode=1) + prep-rest ----
  gemm_prep<<<9984, 256, 0, stream>>>(
      XN_b, qkvT, QKV_b, VT_b,
      ca_k_w, ca_v_w, sa_out_w, ca_out_w, lin1_w, lin2_w,
      gru_w_ih, gru_w_hh, qhid, contexts,
      kT, vT, saoT, caoT, lin1T, lin2T, ihB, hhB, QHID_b, CTX_b);
  flash_attn<0><<<dim3(8, 64), 256, 0, stream>>>(
      QKV_b, QKV_SB, 192, 3072, QKV_b + 64, QKV_SB, 192, 3072,
      VT_b, O_b, nullptr, SCALE);
  // sa_out (256 blocks, chain) merged with gh (768 blocks, independent after prep)
  gemm_dual<<<1024, 256, 0, stream>>>(
      O_b, 1024, saoT, 1024, X, nullptr, 1024, sa_out_b, queries, 1024, 8, 256,
      QHID_b, 1024, hhB, 1024, nullptr, GH_b, 3072, gru_b_hh, nullptr, 1024, 24,
      nullptr, 0);

  // ---- GRU dynamic query ----
  ln_bf16<1><<<4096, 256, 0, stream>>>(X, nullptr, ca_norm_w, ca_norm_b, XN_b, 0);
  // gi (768 blocks, chain) merged with CA kv projection (512 blocks, independent);
  // kv writes K rows to KV_b and V stripes transposed into VT_b (vmode=2)
  gemm_dual<<<1280, 256, 0, stream>>>(
      XN_b, 1024, ihB, 1024, nullptr, GI_b, 3072, gru_b_ih, nullptr, 1024, 24, 768,
      CTX_b, 1024, kT, 1024, nullptr, KV_b, 2048, nullptr, nullptr, 1024, 16,
      VT_b, 2);
  gru_kernel<<<2048, 256, 0, stream>>>(GI_b, GH_b, qhid, qh_out, QHID_b /*now QHB*/);

  // ---- Cross attention ----
  flash_attn<1><<<dim3(8, 64), 256, 0, stream>>>(
      QHID_b, 1024LL * 1024, 64, 1024, KV_b, KV_SB, 64, 2048,
      VT_b, O_b, energy, SCALE);
  gemm_bf16<<<dim3(8, 32), 256, 0, stream>>>(
      O_b, 1024, caoT, 1024, X2, nullptr, 1024, ca_out_b, X, 1024, nullptr, 0);

  // ---- MLP ----
  ln_bf16<1><<<4096, 256, 0, stream>>>(X2, nullptr, ln1_w, ln1_b, XN_b, 1);
  gemm_bf16<<<dim3(16, 32), 256, 0, stream>>>(
      XN_b, 1024, lin1T, 1024, nullptr, M1B, 2048, nullptr, nullptr, 1024, nullptr, 0);
  ln_bf16<2><<<4096, 256, 0, stream>>>(nullptr, M1B, ln2_w, ln2_b, LN2_b, 1);
  gemm_bf16<<<dim3(8, 32), 256, 0, stream>>>(
      LN2_b, 2048, lin2T, 2048, out0, nullptr, 1024, nullptr, X2, 2048, nullptr, 0);
}

// Round 9
// 568.876 us; speedup vs baseline: 1.1582x; 1.0388x over previous
//
#include <hip/hip_runtime.h>
#include <hip/hip_bf16.h>
#include <math.h>

static constexpr float SCALE = 0.03125f; // 1/sqrt(1024)

typedef __attribute__((ext_vector_type(4))) float f32x4;
typedef __attribute__((ext_vector_type(8))) __bf16 bf16x8;
typedef __attribute__((ext_vector_type(4))) __bf16 bf16x4;

__device__ __forceinline__ void g2l16(const void* g, void* l) {
  __builtin_amdgcn_global_load_lds(
      (const __attribute__((address_space(1))) unsigned int*)g,
      (__attribute__((address_space(3))) unsigned int*)l,
      16, 0, 0);
}

// ---------------- prep helpers ----------
// 64x64 fp32->bf16 transpose tile; tile buffer supplied by caller (16.6 KB as float[64][65]).
__device__ __forceinline__ void wtrans_tile(
    const float* __restrict__ src, __bf16* __restrict__ dst,
    int Kd, int N, int tid, float (*tile)[65]) {
  int t = threadIdx.x;
  int ntx = N >> 6;
  int n0 = (tid % ntx) * 64, k0 = (tid / ntx) * 64;
  #pragma unroll
  for (int i = 0; i < 16; ++i) {
    int idx = i * 256 + t; int r = idx >> 6, c = idx & 63;
    tile[r][c] = src[(size_t)(k0 + r) * N + n0 + c];
  }
  __syncthreads();
  #pragma unroll
  for (int i = 0; i < 16; ++i) {
    int idx = i * 256 + t; int r = idx >> 6, c = idx & 63;
    dst[(size_t)(n0 + r) * Kd + k0 + c] = (__bf16)tile[c][r];
  }
}

// ---------------- prep_crit: qkvT transpose (768 tiles) + ln_sa (4096 rows) -------------
__global__ __launch_bounds__(256) void prep_crit(
    const float* __restrict__ sa_qkv_w,
    const float* __restrict__ queries, const float* __restrict__ sa_norm_w,
    const float* __restrict__ sa_norm_b,
    __bf16* __restrict__ qkvT, __bf16* __restrict__ xnB) {
  int bid = blockIdx.x;
  int t = threadIdx.x;
  if (bid < 768) {
    __shared__ float tile[64][65];
    wtrans_tile(sa_qkv_w, qkvT, 1024, 3072, bid, tile);
    return;
  }
  // ---- LayerNorm(queries) -> xnB, D=1024 ----
  int row = bid - 768;
  int c = t * 4;
  float4 v = *(const float4*)(queries + (size_t)row * 1024 + c);
  float s = v.x + v.y + v.z + v.w;
  float s2 = v.x*v.x + v.y*v.y + v.z*v.z + v.w*v.w;
  #pragma unroll
  for (int off = 32; off > 0; off >>= 1) {
    s += __shfl_xor(s, off);
    s2 += __shfl_xor(s2, off);
  }
  __shared__ float red[4], red2[4];
  int wv = t >> 6;
  if ((t & 63) == 0) { red[wv] = s; red2[wv] = s2; }
  __syncthreads();
  float S  = red[0] + red[1] + red[2] + red[3];
  float S2 = red2[0] + red2[1] + red2[2] + red2[3];
  float mean = S / 1024.f;
  float var = S2 / 1024.f - mean * mean;
  float rs = rsqrtf(var + 1e-5f);
  float vv[4] = {v.x, v.y, v.z, v.w};
  bf16x4 o;
  #pragma unroll
  for (int j = 0; j < 4; ++j)
    o[j] = (__bf16)((vv[j] - mean) * rs * sa_norm_w[c+j] + sa_norm_b[c+j]);
  *(bf16x4*)(xnB + (size_t)row * 1024 + c) = o;
}

// ---------------- LayerNorm (+ optional SiLU) -> bf16, fp32 or bf16 input ----------------
template <int NV>  // NV = D/1024 (4*NV elems/thread)
__global__ __launch_bounds__(256) void ln_bf16(
    const float* __restrict__ xf, const __bf16* __restrict__ xb,
    const float* __restrict__ w, const float* __restrict__ b,
    __bf16* __restrict__ out, int silu) {
  const int D = NV * 1024;
  int row = blockIdx.x, t = threadIdx.x;
  float vals[NV * 4];
  float s = 0.f, s2 = 0.f;
  #pragma unroll
  for (int i = 0; i < NV; ++i) {
    int c = (i * 256 + t) * 4;
    float4 v;
    if (xf) {
      v = *(const float4*)(xf + (size_t)row * D + c);
    } else {
      bf16x4 vb = *(const bf16x4*)(xb + (size_t)row * D + c);
      v = make_float4((float)vb[0], (float)vb[1], (float)vb[2], (float)vb[3]);
    }
    vals[i*4+0] = v.x; vals[i*4+1] = v.y; vals[i*4+2] = v.z; vals[i*4+3] = v.w;
    s += v.x + v.y + v.z + v.w;
    s2 += v.x*v.x + v.y*v.y + v.z*v.z + v.w*v.w;
  }
  #pragma unroll
  for (int off = 32; off > 0; off >>= 1) {
    s += __shfl_xor(s, off);
    s2 += __shfl_xor(s2, off);
  }
  __shared__ float red[4], red2[4];
  int wv = t >> 6;
  if ((t & 63) == 0) { red[wv] = s; red2[wv] = s2; }
  __syncthreads();
  float S  = red[0] + red[1] + red[2] + red[3];
  float S2 = red2[0] + red2[1] + red2[2] + red2[3];
  float mean = S / D;
  float var = S2 / D - mean * mean;
  float rs = rsqrtf(var + 1e-5f);
  #pragma unroll
  for (int i = 0; i < NV; ++i) {
    int c = (i * 256 + t) * 4;
    bf16x4 o;
    #pragma unroll
    for (int j = 0; j < 4; ++j) {
      float v = (vals[i*4+j] - mean) * rs * w[c+j] + b[c+j];
      if (silu) v = v / (1.f + __expf(-v));
      o[j] = (__bf16)v;
    }
    *(bf16x4*)(out + (size_t)row * D + c) = o;
  }
}

// ---------------- bf16 MFMA GEMM core, 2-buffer stage-early/drain-late pipeline ----------
// C[M,N] = A[M,K] @ B^T; B stored [N][K]. Tile 128x128, BK=64, 4 waves.
// LDS (64 KB) supplied by the caller.
// vmode: 0 = plain epilogue. 1/2 = V-transpose epilogue (wave-private scratch).
__device__ __forceinline__ void gemm_body(
    __bf16* __restrict__ sm,
    const __bf16* __restrict__ A, long long lda,
    const __bf16* __restrict__ B, long long ldb,
    float* __restrict__ outF, __bf16* __restrict__ outB, long long ldc,
    const float* __restrict__ bias, const float* __restrict__ res,
    int K, int bm, int bn, __bf16* __restrict__ VTout, int vmode) {
  __bf16* Asm0 = sm;
  __bf16* Bsm0 = sm + 8192;
  __bf16* Asm1 = sm + 16384;
  __bf16* Bsm1 = sm + 24576;
  int t = threadIdx.x;
  int lane = t & 63, w = t >> 6;
  int l15 = lane & 15, kg = lane >> 4;
  int wm = (w >> 1) * 64, wn = (w & 1) * 64;

  f32x4 acc[4][4];
  #pragma unroll
  for (int i = 0; i < 4; ++i)
    #pragma unroll
    for (int j = 0; j < 4; ++j) acc[i][j] = (f32x4)(0.0f);

  const __bf16* ga[4]; const __bf16* gb[4];
  int lo[4];
  #pragma unroll
  for (int i = 0; i < 4; ++i) {
    int slot = i * 256 + t;
    int row = slot >> 3, s = slot & 7;
    int sx = s ^ (row & 7);
    ga[i] = A + (size_t)(bm + row) * lda + (sx << 3);
    gb[i] = B + (size_t)(bn + row) * ldb + (sx << 3);
    lo[i] = (i * 256 + w * 64) << 3;
  }

  auto STAGE = [&](__bf16* As, __bf16* Bs, int k0) {
    #pragma unroll
    for (int i = 0; i < 4; ++i) g2l16(ga[i] + k0, As + lo[i]);
    #pragma unroll
    for (int i = 0; i < 4; ++i) g2l16(gb[i] + k0, Bs + lo[i]);
  };
  auto COMPUTE = [&](const __bf16* As, const __bf16* Bs) {
    #pragma unroll
    for (int kk = 0; kk < 2; ++kk) {
      bf16x8 af[4], bfr[4];
      #pragma unroll
      for (int mi = 0; mi < 4; ++mi) {
        int row = wm + mi * 16 + l15;
        int ks = kk * 4 + kg;
        af[mi] = *(const bf16x8*)(As + row * 64 + ((ks ^ (row & 7)) << 3));
      }
      #pragma unroll
      for (int ni = 0; ni < 4; ++ni) {
        int row = wn + ni * 16 + l15;
        int ks = kk * 4 + kg;
        bfr[ni] = *(const bf16x8*)(Bs + row * 64 + ((ks ^ (row & 7)) << 3));
      }
      #pragma unroll
      for (int mi = 0; mi < 4; ++mi)
        #pragma unroll
        for (int ni = 0; ni < 4; ++ni)
          acc[mi][ni] = __builtin_amdgcn_mfma_f32_16x16x32_bf16(
              af[mi], bfr[ni], acc[mi][ni], 0, 0, 0);
    }
  };
  #define GEMM_SYNC() do { \
    asm volatile("s_waitcnt vmcnt(0)" ::: "memory"); \
    __builtin_amdgcn_s_barrier(); \
    __builtin_amdgcn_sched_barrier(0); \
  } while (0)

  STAGE(Asm0, Bsm0, 0);
  GEMM_SYNC();
  int nk = K >> 6;  // even
  for (int kt = 0; kt + 2 < nk; kt += 2) {
    STAGE(Asm1, Bsm1, (kt + 1) << 6);
    COMPUTE(Asm0, Bsm0);
    GEMM_SYNC();
    STAGE(Asm0, Bsm0, (kt + 2) << 6);
    COMPUTE(Asm1, Bsm1);
    GEMM_SYNC();
  }
  // tail: tiles nk-2 (in buf0), nk-1
  STAGE(Asm1, Bsm1, (nk - 1) << 6);
  COMPUTE(Asm0, Bsm0);
  GEMM_SYNC();
  COMPUTE(Asm1, Bsm1);
  #undef GEMM_SYNC

  int cw = bn + wn;
  int isV = 0;
  if (vmode == 1)      isV = (cw % 192) == 128;
  else if (vmode == 2) isV = cw >= 1024;

  if (isV) {
    // ---- V-transpose epilogue (wave-private; Asm0/Bsm0 dead after last barrier) ----
    int h = (vmode == 1) ? (cw / 192) : ((cw - 1024) >> 6);
    int rowb = bm + wm;               // 64 rows, within one batch (64-aligned)
    int b = rowb >> 10, k0 = rowb & 1023;
    __bf16* scr = (w < 2 ? Asm0 : Bsm0) + (w & 1) * 4096;  // 64x64 bf16
    #pragma unroll
    for (int mi = 0; mi < 4; ++mi) {
      #pragma unroll
      for (int ni = 0; ni < 4; ++ni) {
        int d = ni * 16 + l15;
        int sw = (d & 7) << 3;
        #pragma unroll
        for (int r = 0; r < 4; ++r) {
          int kl = mi * 16 + kg * 4 + r;
          scr[d * 64 + (kl ^ sw)] = (__bf16)acc[mi][ni][r];
        }
      }
    }
    #pragma unroll
    for (int i = 0; i < 8; ++i) {
      int idx = i * 64 + lane;
      int d = idx >> 3, kc = (idx & 7) * 8;
      bf16x8 v = *(const bf16x8*)&scr[d * 64 + (kc ^ ((d & 7) << 3))];
      *(bf16x8*)(VTout + ((size_t)((b * 16 + h) * 64 + d) << 10) + k0 + kc) = v;
    }
    return;
  }

  #pragma unroll
  for (int mi = 0; mi < 4; ++mi) {
    #pragma unroll
    for (int ni = 0; ni < 4; ++ni) {
      int rbase = bm + wm + mi * 16 + kg * 4;
      int c = bn + wn + ni * 16 + l15;
      #pragma unroll
      for (int r = 0; r < 4; ++r) {
        float val = acc[mi][ni][r];
        if (bias) val += bias[c];
        size_t off = (size_t)(rbase + r) * ldc + c;
        if (res) val += res[off];
        if (outF) outF[off] = val;
        if (outB) outB[off] = (__bf16)val;
      }
    }
  }
}

// Single-GEMM kernel (2D grid, XCD-aware swizzle; nwg divisible by 8 at all call sites).
__global__ __launch_bounds__(256) void gemm_bf16(
    const __bf16* __restrict__ A, long long lda,
    const __bf16* __restrict__ B, long long ldb,
    float* __restrict__ outF, __bf16* __restrict__ outB, long long ldc,
    const float* __restrict__ bias, const float* __restrict__ res, int K,
    __bf16* __restrict__ VTout, int vmode) {
  __shared__ __bf16 sm[32768];
  int nwg = gridDim.x * gridDim.y;
  int orig = blockIdx.y * gridDim.x + blockIdx.x;
  int swz = (orig & 7) * (nwg >> 3) + (orig >> 3);
  gemm_body(sm, A, lda, B, ldb, outF, outB, ldc, bias, res, K,
            (swz / gridDim.x) * 128, (swz % gridDim.x) * 128, VTout, vmode);
}

// Dual-GEMM kernel: two independent GEMMs in one launch (1D grid, blocks < nb0 -> p0).
__global__ __launch_bounds__(256) void gemm_dual(
    const __bf16* __restrict__ A0, long long lda0, const __bf16* __restrict__ B0, long long ldb0,
    float* __restrict__ oF0, __bf16* __restrict__ oB0, long long ldc0,
    const float* __restrict__ bias0, const float* __restrict__ res0, int K0, int gx0, int nb0,
    const __bf16* __restrict__ A1, long long lda1, const __bf16* __restrict__ B1, long long ldb1,
    float* __restrict__ oF1, __bf16* __restrict__ oB1, long long ldc1,
    const float* __restrict__ bias1, const float* __restrict__ res1, int K1, int gx1,
    __bf16* __restrict__ VT1, int vm1) {
  __shared__ __bf16 sm[32768];
  int bid = blockIdx.x;
  if (bid < nb0) {
    int swz = (bid & 7) * (nb0 >> 3) + (bid >> 3);
    gemm_body(sm, A0, lda0, B0, ldb0, oF0, oB0, ldc0, bias0, res0, K0,
              (swz / gx0) * 128, (swz % gx0) * 128, nullptr, 0);
  } else {
    int b = bid - nb0;
    int nb1 = gridDim.x - nb0;
    int swz = (b & 7) * (nb1 >> 3) + (b >> 3);
    gemm_body(sm, A1, lda1, B1, ldb1, oF1, oB1, ldc1, bias1, res1, K1,
              (swz / gx1) * 128, (swz % gx1) * 128, VT1, vm1);
  }
}

// ---------------- qkv GEMM (blocks 0-767, vmode=1) + prep-rest (blocks 768-9983) --------
__global__ __launch_bounds__(256) void gemm_prep(
    const __bf16* __restrict__ Aq, const __bf16* __restrict__ Bq,
    __bf16* __restrict__ Cq, __bf16* __restrict__ VTq,
    const float* __restrict__ ca_k_w, const float* __restrict__ ca_v_w,
    const float* __restrict__ sa_out_w, const float* __restrict__ ca_out_w,
    const float* __restrict__ lin1_w, const float* __restrict__ lin2_w,
    const float* __restrict__ gru_w_ih, const float* __restrict__ gru_w_hh,
    const float* __restrict__ qhid, const float* __restrict__ contexts,
    __bf16* __restrict__ kT, __bf16* __restrict__ vT, __bf16* __restrict__ saoT,
    __bf16* __restrict__ caoT, __bf16* __restrict__ lin1T, __bf16* __restrict__ lin2T,
    __bf16* __restrict__ ihB, __bf16* __restrict__ hhB,
    __bf16* __restrict__ qhB, __bf16* __restrict__ ctxB) {
  __shared__ __bf16 sm[32768];
  int bid = blockIdx.x;
  int t = threadIdx.x;
  if (bid < 768) {
    int swz = (bid & 7) * 96 + (bid >> 3);
    gemm_body(sm, Aq, 1024, Bq, 1024, nullptr, Cq, 3072, nullptr, nullptr, 1024,
              (swz / 24) * 128, (swz % 24) * 128, VTq, 1);
    return;
  }
  if (bid >= 2816) {  // casts, 8 elems/thread
    const float* csrc; __bf16* cdst; int cbase;
    if (bid < 4352)      { csrc = gru_w_ih; cdst = ihB;  cbase = 2816; }
    else if (bid < 5888) { csrc = gru_w_hh; cdst = hhB;  cbase = 4352; }
    else if (bid < 7936) { csrc = qhid;     cdst = qhB;  cbase = 5888; }
    else                 { csrc = contexts; cdst = ctxB; cbase = 7936; }
    size_t idx = ((size_t)(bid - cbase) * 256 + t) * 8;
    float4 a = *(const float4*)(csrc + idx);
    float4 b = *(const float4*)(csrc + idx + 4);
    bf16x8 o = {(__bf16)a.x,(__bf16)a.y,(__bf16)a.z,(__bf16)a.w,
                (__bf16)b.x,(__bf16)b.y,(__bf16)b.z,(__bf16)b.w};
    *(bf16x8*)(cdst + idx) = o;
    return;
  }
  const float* src; __bf16* dst; int Kd, N, base;
  if (bid < 1024)      { src = ca_k_w;   dst = kT;    Kd = 1024; N = 1024; base = 768; }
  else if (bid < 1280) { src = ca_v_w;   dst = vT;    Kd = 1024; N = 1024; base = 1024; }
  else if (bid < 1536) { src = sa_out_w; dst = saoT;  Kd = 1024; N = 1024; base = 1280; }
  else if (bid < 1792) { src = ca_out_w; dst = caoT;  Kd = 1024; N = 1024; base = 1536; }
  else if (bid < 2304) { src = lin1_w;   dst = lin1T; Kd = 1024; N = 2048; base = 1792; }
  else                 { src = lin2_w;   dst = lin2T; Kd = 2048; N = 1024; base = 2304; }
  wtrans_tile(src, dst, Kd, N, bid - base, (float(*)[65])sm);
}

// ---------------- GRU cell elementwise, bf16 inputs, 8 elems/thread ----------------
__global__ __launch_bounds__(256) void gru_kernel(
    const __bf16* __restrict__ gi, const __bf16* __restrict__ gh,
    const float* __restrict__ hf, float* __restrict__ qh, __bf16* __restrict__ qhb) {
  size_t e0 = ((size_t)blockIdx.x * 256 + threadIdx.x) * 8;  // over 4M elems
  int row = (int)(e0 >> 10), col = (int)(e0 & 1023);
  size_t base = (size_t)row * 3072 + col;
  bf16x8 vir = *(const bf16x8*)(gi + base);
  bf16x8 viz = *(const bf16x8*)(gi + base + 1024);
  bf16x8 vin = *(const bf16x8*)(gi + base + 2048);
  bf16x8 vhr = *(const bf16x8*)(gh + base);
  bf16x8 vhz = *(const bf16x8*)(gh + base + 1024);
  bf16x8 vhn = *(const bf16x8*)(gh + base + 2048);
  float4 h0 = *(const float4*)(hf + e0);
  float4 h1 = *(const float4*)(hf + e0 + 4);
  float hv[8] = {h0.x, h0.y, h0.z, h0.w, h1.x, h1.y, h1.z, h1.w};
  float q[8];
  #pragma unroll
  for (int j = 0; j < 8; ++j) {
    float r = 1.f / (1.f + __expf(-((float)vir[j] + (float)vhr[j])));
    float z = 1.f / (1.f + __expf(-((float)viz[j] + (float)vhz[j])));
    float n = tanhf((float)vin[j] + r * (float)vhn[j]);
    q[j] = (1.f - z) * n + z * hv[j];
  }
  *(float4*)(qh + e0)     = make_float4(q[0], q[1], q[2], q[3]);
  *(float4*)(qh + e0 + 4) = make_float4(q[4], q[5], q[6], q[7]);
  bf16x8 qb;
  #pragma unroll
  for (int j = 0; j < 8; ++j) qb[j] = (__bf16)q[j];
  *(bf16x8*)(qhb + e0) = qb;
}

// ---------------- Fused flash attention, 3-deep pipelined K/V staging ----------------
// Per g=(b,h): O[q][d] = softmax_kv(S*scale) @ V, S = Q @ K^T (head dim 64).
// Swapped QK^T -> S^T acc (col=q=l15). P -> LDS packed bf16x4, XOR-swizzled.
// Psm/corr_l/l_l are wave-private rows => ONE raw s_barrier per tile suffices;
// staging for tile t+2 issued after the barrier (3 LDS buffers), counted vmcnt.
template <int E>
__global__ __launch_bounds__(256) void flash_attn(
    const __bf16* __restrict__ Qb, long long q_sb, long long q_sh, int q_sm,
    const __bf16* __restrict__ Kb, long long k_sb, long long k_sh, int k_sm,
    const __bf16* __restrict__ VT, __bf16* __restrict__ Ob,
    float* __restrict__ energyOut, float scale) {
  __shared__ __bf16 Ksm[3][4096];
  __shared__ __bf16 Vsm[3][4096];
  __shared__ __bf16 Psm[128 * 64];
  __shared__ float corr_l[128];
  __shared__ float l_l[128];
  int g = blockIdx.y, b = g >> 4, h = g & 15;
  int qt = blockIdx.x * 128;
  const __bf16* Qg = Qb + (size_t)b * q_sb + (size_t)h * q_sh;
  const __bf16* Kg = Kb + (size_t)b * k_sb + (size_t)h * k_sh;
  const __bf16* Vg = VT + (size_t)g * 65536;
  int t = threadIdx.x, lane = t & 63, w = t >> 6;
  int l15 = lane & 15, kg = lane >> 4;
  int wq = w * 32;

  bf16x8 qf[2][2];
  #pragma unroll
  for (int nq = 0; nq < 2; ++nq)
    #pragma unroll
    for (int kk = 0; kk < 2; ++kk)
      qf[nq][kk] = *(const bf16x8*)(
          Qg + (size_t)(qt + wq + nq * 16 + l15) * q_sm + kk * 32 + kg * 8);

  f32x4 acc_o[2][4];
  #pragma unroll
  for (int i = 0; i < 2; ++i)
    #pragma unroll
    for (int j = 0; j < 4; ++j) acc_o[i][j] = (f32x4)(0.0f);
  float m_run[2] = {-1e30f, -1e30f};
  float l_run[2] = {0.f, 0.f};

  const __bf16* gK[2]; const __bf16* gV[2];
  int lo[2];
  #pragma unroll
  for (int i = 0; i < 2; ++i) {
    int slot = i * 256 + t;
    int row = slot >> 3, s = slot & 7, sx = s ^ (row & 7);
    gK[i] = Kg + (size_t)row * k_sm + (sx << 3);
    gV[i] = Vg + (size_t)row * 1024 + (sx << 3);
    lo[i] = (i * 256 + w * 64) << 3;
  }

  // prologue: stage tile 0 (4 oldest vmem ops) then tile 1
  #pragma unroll
  for (int i = 0; i < 2; ++i) g2l16(gK[i], &Ksm[0][lo[i]]);
  #pragma unroll
  for (int i = 0; i < 2; ++i) g2l16(gV[i], &Vsm[0][lo[i]]);
  #pragma unroll
  for (int i = 0; i < 2; ++i) g2l16(gK[i] + (size_t)64 * k_sm, &Ksm[1][lo[i]]);
  #pragma unroll
  for (int i = 0; i < 2; ++i) g2l16(gV[i] + 64, &Vsm[1][lo[i]]);

  int rb = 0;  // read buffer = kvt % 3
  for (int kvt = 0; kvt < 16; ++kvt) {
    if (E) {
      if (kvt == 0)       asm volatile("s_waitcnt vmcnt(4)" ::: "memory");
      else if (kvt == 1)  asm volatile("s_waitcnt vmcnt(12)" ::: "memory");
      else if (kvt == 15) asm volatile("s_waitcnt vmcnt(16)" ::: "memory");
      else                asm volatile("s_waitcnt vmcnt(20)" ::: "memory");
    } else {
      if (kvt == 15)      asm volatile("s_waitcnt vmcnt(0)" ::: "memory");
      else                asm volatile("s_waitcnt vmcnt(4)" ::: "memory");
    }
    __builtin_amdgcn_s_barrier();
    __builtin_amdgcn_sched_barrier(0);  // pin: no memory op crosses the barrier

    if (kvt < 14) {  // stage tile kvt+2
      int sbuf = rb >= 1 ? rb - 1 : rb + 2;  // (kvt+2)%3
      size_t ko = (size_t)(kvt + 2) << 6;
      #pragma unroll
      for (int i = 0; i < 2; ++i) g2l16(gK[i] + ko * k_sm, &Ksm[sbuf][lo[i]]);
      #pragma unroll
      for (int i = 0; i < 2; ++i) g2l16(gV[i] + ko, &Vsm[sbuf][lo[i]]);
    }
    const __bf16* Ks = Ksm[rb];
    const __bf16* Vs = Vsm[rb];

    f32x4 accs[4][2];
    #pragma unroll
    for (int i = 0; i < 4; ++i)
      #pragma unroll
      for (int j = 0; j < 2; ++j) accs[i][j] = (f32x4)(0.0f);
    __builtin_amdgcn_s_setprio(1);
    #pragma unroll
    for (int tt = 0; tt < 4; ++tt) {
      bf16x8 kf[2];
      #pragma unroll
      for (int kk = 0; kk < 2; ++kk) {
        int row = tt * 16 + l15;
        int ks = kk * 4 + kg;
        kf[kk] = *(const bf16x8*)(Ks + row * 64 + ((ks ^ (row & 7)) << 3));
      }
      #pragma unroll
      for (int nq = 0; nq < 2; ++nq)
        #pragma unroll
        for (int kk = 0; kk < 2; ++kk)
          accs[tt][nq] = __builtin_amdgcn_mfma_f32_16x16x32_bf16(
              kf[kk], qf[nq][kk], accs[tt][nq], 0, 0, 0);
    }
    __builtin_amdgcn_s_setprio(0);

    if (E) {
      int kv0 = kvt << 6;
      float* eg = energyOut + ((size_t)g << 20);
      #pragma unroll
      for (int nq = 0; nq < 2; ++nq) {
        int q = qt + wq + nq * 16 + l15;
        #pragma unroll
        for (int tt = 0; tt < 4; ++tt)
          __builtin_nontemporal_store(
              accs[tt][nq], (f32x4*)(eg + (size_t)q * 1024 + kv0 + tt * 16 + kg * 4));
      }
    }

    #pragma unroll
    for (int nq = 0; nq < 2; ++nq) {
      float tmax = -1e30f;
      #pragma unroll
      for (int tt = 0; tt < 4; ++tt)
        #pragma unroll
        for (int r = 0; r < 4; ++r) tmax = fmaxf(tmax, accs[tt][nq][r]);
      tmax *= scale;
      tmax = fmaxf(tmax, __shfl_xor(tmax, 16));
      tmax = fmaxf(tmax, __shfl_xor(tmax, 32));
      float m_new = fmaxf(m_run[nq], tmax);
      float corr = __expf(m_run[nq] - m_new);
      m_run[nq] = m_new;
      int q = wq + nq * 16 + l15;
      float psum = 0.f;
      #pragma unroll
      for (int tt = 0; tt < 4; ++tt) {
        bf16x4 p4;
        #pragma unroll
        for (int r = 0; r < 4; ++r) {
          float p = __expf(accs[tt][nq][r] * scale - m_new);
          psum += p;
          p4[r] = (__bf16)p;
        }
        int kvs = (tt * 16 + kg * 4) ^ ((q & 7) << 3);
        *(bf16x4*)(Psm + q * 64 + kvs) = p4;
      }
      psum += __shfl_xor(psum, 16);
      psum += __shfl_xor(psum, 32);
      l_run[nq] = l_run[nq] * corr + psum;
      if (kg == 0) corr_l[q] = corr;
    }
    // no barrier: Psm / corr_l rows are wave-private

    #pragma unroll
    for (int mq = 0; mq < 2; ++mq) {
      f32x4 c4 = *(const f32x4*)&corr_l[wq + mq * 16 + kg * 4];
      #pragma unroll
      for (int nd = 0; nd < 4; ++nd)
        #pragma unroll
        for (int r = 0; r < 4; ++r) acc_o[mq][nd][r] *= c4[r];
    }
    __builtin_amdgcn_s_setprio(1);
    #pragma unroll
    for (int kk = 0; kk < 2; ++kk) {
      bf16x8 pf[2], vf[4];
      #pragma unroll
      for (int mq = 0; mq < 2; ++mq) {
        int row = wq + mq * 16 + l15;
        int kvs = (kk * 32 + kg * 8) ^ ((row & 7) << 3);
        pf[mq] = *(const bf16x8*)(Psm + row * 64 + kvs);
      }
      #pragma unroll
      for (int nd = 0; nd < 4; ++nd) {
        int vrow = nd * 16 + l15;
        vf[nd] = *(const bf16x8*)(Vs + vrow * 64 + (((kk * 4 + kg) ^ (vrow & 7)) << 3));
      }
      #pragma unroll
      for (int mq = 0; mq < 2; ++mq)
        #pragma unroll
        for (int nd = 0; nd < 4; ++nd)
          acc_o[mq][nd] = __builtin_amdgcn_mfma_f32_16x16x32_bf16(
              pf[mq], vf[nd], acc_o[mq][nd], 0, 0, 0);
    }
    __builtin_amdgcn_s_setprio(0);
    rb = rb == 2 ? 0 : rb + 1;
  }

  #pragma unroll
  for (int nq = 0; nq < 2; ++nq)
    if (kg == 0) l_l[wq + nq * 16 + l15] = l_run[nq];
  __syncthreads();

  #pragma unroll
  for (int mq = 0; mq < 2; ++mq) {
    f32x4 lv = *(const f32x4*)&l_l[wq + mq * 16 + kg * 4];
    #pragma unroll
    for (int nd = 0; nd < 4; ++nd) {
      int col = h * 64 + nd * 16 + l15;
      #pragma unroll
      for (int r = 0; r < 4; ++r) {
        int qrow = qt + wq + mq * 16 + kg * 4 + r;
        Ob[(size_t)(b * 1024 + qrow) * 1024 + col] = (__bf16)(acc_o[mq][nd][r] / lv[r]);
      }
    }
  }
}

// ---------------- energy body: raw S = QH @ K^T for one (g, q-tile) ----------------
// Bit-identical to flash's QK^T: same fragment loads, same mfma order, same store map.
// K-only 3-deep staging (24 KB LDS). Counted vmcnt includes in-flight stores
// (2 loads/tile, 8 stores/tile): kvt0=2, kvt1=10, kvt15=16, else 18.
__device__ __forceinline__ void energy_body(
    __bf16* __restrict__ Ksmb,
    const __bf16* __restrict__ Qb, long long q_sb, long long q_sh, int q_sm,
    const __bf16* __restrict__ Kb, long long k_sb, long long k_sh, int k_sm,
    float* __restrict__ energyOut, int g, int qt) {
  int b = g >> 4, h = g & 15;
  const __bf16* Qg = Qb + (size_t)b * q_sb + (size_t)h * q_sh;
  const __bf16* Kg = Kb + (size_t)b * k_sb + (size_t)h * k_sh;
  int t = threadIdx.x, lane = t & 63, w = t >> 6;
  int l15 = lane & 15, kg = lane >> 4;
  int wq = w * 32;

  bf16x8 qf[2][2];
  #pragma unroll
  for (int nq = 0; nq < 2; ++nq)
    #pragma unroll
    for (int kk = 0; kk < 2; ++kk)
      qf[nq][kk] = *(const bf16x8*)(
          Qg + (size_t)(qt + wq + nq * 16 + l15) * q_sm + kk * 32 + kg * 8);

  const __bf16* gK[2];
  int lo[2];
  #pragma unroll
  for (int i = 0; i < 2; ++i) {
    int slot = i * 256 + t;
    int row = slot >> 3, s = slot & 7, sx = s ^ (row & 7);
    gK[i] = Kg + (size_t)row * k_sm + (sx << 3);
    lo[i] = (i * 256 + w * 64) << 3;
  }
  #pragma unroll
  for (int i = 0; i < 2; ++i) g2l16(gK[i], Ksmb + lo[i]);
  #pragma unroll
  for (int i = 0; i < 2; ++i) g2l16(gK[i] + (size_t)64 * k_sm, Ksmb + 4096 + lo[i]);

  float* eg = energyOut + ((size_t)g << 20);
  int rb = 0;
  for (int kvt = 0; kvt < 16; ++kvt) {
    if (kvt == 0)       asm volatile("s_waitcnt vmcnt(2)" ::: "memory");
    else if (kvt == 1)  asm volatile("s_waitcnt vmcnt(10)" ::: "memory");
    else if (kvt == 15) asm volatile("s_waitcnt vmcnt(16)" ::: "memory");
    else                asm volatile("s_waitcnt vmcnt(18)" ::: "memory");
    __builtin_amdgcn_s_barrier();
    __builtin_amdgcn_sched_barrier(0);

    if (kvt < 14) {
      int sbuf = rb >= 1 ? rb - 1 : rb + 2;  // (kvt+2)%3
      size_t ko = (size_t)(kvt + 2) << 6;
      #pragma unroll
      for (int i = 0; i < 2; ++i) g2l16(gK[i] + ko * k_sm, Ksmb + sbuf * 4096 + lo[i]);
    }
    const __bf16* Ks = Ksmb + rb * 4096;

    f32x4 accs[4][2];
    #pragma unroll
    for (int i = 0; i < 4; ++i)
      #pragma unroll
      for (int j = 0; j < 2; ++j) accs[i][j] = (f32x4)(0.0f);
    #pragma unroll
    for (int tt = 0; tt < 4; ++tt) {
      bf16x8 kf[2];
      #pragma unroll
      for (int kk = 0; kk < 2; ++kk) {
        int row = tt * 16 + l15;
        int ks = kk * 4 + kg;
        kf[kk] = *(const bf16x8*)(Ks + row * 64 + ((ks ^ (row & 7)) << 3));
      }
      #pragma unroll
      for (int nq = 0; nq < 2; ++nq)
        #pragma unroll
        for (int kk = 0; kk < 2; ++kk)
          accs[tt][nq] = __builtin_amdgcn_mfma_f32_16x16x32_bf16(
              kf[kk], qf[nq][kk], accs[tt][nq], 0, 0, 0);
    }
    int kv0 = kvt << 6;
    #pragma unroll
    for (int nq = 0; nq < 2; ++nq) {
      int q = qt + wq + nq * 16 + l15;
      #pragma unroll
      for (int tt = 0; tt < 4; ++tt)
        __builtin_nontemporal_store(
            accs[tt][nq], (f32x4*)(eg + (size_t)q * 1024 + kv0 + tt * 16 + kg * 4));
    }
    rb = rb == 2 ? 0 : rb + 1;
  }
}

// ---------------- final launch: lin2 GEMM (blocks 0-255) + energy (256-767) -------------
// lin2 fills 256 scheduler slots; energy fills the other half from t=0 (lin2 alone
// ran at 1 block/CU). Energy output is final -> nothing downstream waits on it.
__global__ __launch_bounds__(256) void gemm_lin2_energy(
    const __bf16* __restrict__ A, const __bf16* __restrict__ B,
    float* __restrict__ outF, const float* __restrict__ res,
    const __bf16* __restrict__ Qb, const __bf16* __restrict__ Kb,
    float* __restrict__ energyOut) {
  __shared__ __bf16 sm[32768];
  int bid = blockIdx.x;
  if (bid < 256) {
    int swz = (bid & 7) * 32 + (bid >> 3);
    gemm_body(sm, A, 2048, B, 2048, outF, nullptr, 1024, nullptr, res, 2048,
              (swz / 8) * 128, (swz % 8) * 128, nullptr, 0);
  } else {
    int eb = bid - 256;
    int g = eb & 63, qt = (eb >> 6) * 128;
    energy_body(sm, Qb, 1024LL * 1024, 64, 1024, Kb, 1024LL * 2048, 64, 2048,
                energyOut, g, qt);
  }
}

extern "C" void kernel_launch(void* const* d_in, const int* in_sizes, int n_in,
                              void* d_out, int out_size, void* d_ws, size_t ws_size,
                              hipStream_t stream) {
  (void)in_sizes; (void)n_in; (void)out_size; (void)ws_size;
  const float* queries   = (const float*)d_in[0];
  const float* contexts  = (const float*)d_in[1];
  const float* qhid      = (const float*)d_in[2];
  const float* sa_norm_w = (const float*)d_in[3];
  const float* sa_norm_b = (const float*)d_in[4];
  const float* sa_qkv_w  = (const float*)d_in[5];
  const float* sa_out_w  = (const float*)d_in[6];
  const float* sa_out_b  = (const float*)d_in[7];
  const float* ca_norm_w = (const float*)d_in[8];
  const float* ca_norm_b = (const float*)d_in[9];
  const float* gru_w_ih  = (const float*)d_in[10];
  const float* gru_w_hh  = (const float*)d_in[11];
  const float* gru_b_ih  = (const float*)d_in[12];
  const float* gru_b_hh  = (const float*)d_in[13];
  const float* ca_k_w    = (const float*)d_in[14];
  const float* ca_v_w    = (const float*)d_in[15];
  const float* ca_out_w  = (const float*)d_in[16];
  const float* ca_out_b  = (const float*)d_in[17];
  const float* ln1_w     = (const float*)d_in[18];
  const float* ln1_b     = (const float*)d_in[19];
  const float* lin1_w    = (const float*)d_in[20];
  const float* ln2_w     = (const float*)d_in[21];
  const float* ln2_b     = (const float*)d_in[22];
  const float* lin2_w    = (const float*)d_in[23];

  float* out0   = (float*)d_out;               // [4096,1024]
  float* energy = out0 + (size_t)4194304;      // [64,1024,1024]
  float* qh_out = out0 + (size_t)71303168;     // [4096,1024]

  // ---- workspace map (units: MM = 1M floats = 4 MiB) ----
  const size_t MM = 1u << 20;
  float* ws = (float*)d_ws;
  float*  X     = ws;
  float*  X2    = ws + 4 * MM;
  __bf16* M1B    = (__bf16*)(ws + 9 * MM);
  __bf16* XN_b   = (__bf16*)(ws + 17 * MM);
  __bf16* QHID_b = (__bf16*)(ws + 19 * MM);
  __bf16* CTX_b  = (__bf16*)(ws + 21 * MM);
  __bf16* O_b    = (__bf16*)(ws + 23 * MM);
  __bf16* VT_b   = (__bf16*)(ws + 25 * MM);
  __bf16* QKV_b  = (__bf16*)(ws + 27 * MM);
  __bf16* KV_b   = (__bf16*)(ws + 27 * MM);  // [4096][2048] bf16, reuses QKV after SA
  __bf16* LN2_b  = (__bf16*)(ws);            // reuses dead X
  __bf16* qkvT   = (__bf16*)(ws + 33 * MM);
  __bf16* ihB    = (__bf16*)(ws + 34 * MM + MM / 2);
  __bf16* hhB    = (__bf16*)(ws + 36 * MM);
  __bf16* kT     = (__bf16*)(ws + 37 * MM + MM / 2);
  __bf16* vT     = (__bf16*)(ws + 38 * MM);
  __bf16* saoT   = (__bf16*)(ws + 38 * MM + MM / 2);
  __bf16* caoT   = (__bf16*)(ws + 39 * MM);
  __bf16* lin1T  = (__bf16*)(ws + 39 * MM + MM / 2);
  __bf16* lin2T  = (__bf16*)(ws + 40 * MM + MM / 2);
  __bf16* GI_b = (__bf16*)energy;            // [4096][3072] bf16 = 24 MB (dead after gru)
  __bf16* GH_b = (__bf16*)(energy + 6 * MM); // next 24 MB (dead after gru)

  const long long QKV_SB = 1024LL * 3072;
  const long long KV_SB  = 1024LL * 2048;

  // ---- prep-critical: qkvT transpose + ln_sa ----
  prep_crit<<<4864, 256, 0, stream>>>(
      sa_qkv_w, queries, sa_norm_w, sa_norm_b, qkvT, XN_b);

  // ---- SelfAttention: qkv GEMM (Q,K rows + V transposed, vmode=1) + prep-rest ----
  gemm_prep<<<9984, 256, 0, stream>>>(
      XN_b, qkvT, QKV_b, VT_b,
      ca_k_w, ca_v_w, sa_out_w, ca_out_w, lin1_w, lin2_w,
      gru_w_ih, gru_w_hh, qhid, contexts,
      kT, vT, saoT, caoT, lin1T, lin2T, ihB, hhB, QHID_b, CTX_b);
  flash_attn<0><<<dim3(8, 64), 256, 0, stream>>>(
      QKV_b, QKV_SB, 192, 3072, QKV_b + 64, QKV_SB, 192, 3072,
      VT_b, O_b, nullptr, SCALE);
  // sa_out (256 blocks, chain) merged with gh (768 blocks, independent after prep)
  gemm_dual<<<1024, 256, 0, stream>>>(
      O_b, 1024, saoT, 1024, X, nullptr, 1024, sa_out_b, queries, 1024, 8, 256,
      QHID_b, 1024, hhB, 1024, nullptr, GH_b, 3072, gru_b_hh, nullptr, 1024, 24,
      nullptr, 0);

  // ---- GRU dynamic query ----
  ln_bf16<1><<<4096, 256, 0, stream>>>(X, nullptr, ca_norm_w, ca_norm_b, XN_b, 0);
  // gi (768 blocks, chain) merged with CA kv projection (512 blocks, independent);
  // kv writes K rows to KV_b and V stripes transposed into VT_b (vmode=2)
  gemm_dual<<<1280, 256, 0, stream>>>(
      XN_b, 1024, ihB, 1024, nullptr, GI_b, 3072, gru_b_ih, nullptr, 1024, 24, 768,
      CTX_b, 1024, kT, 1024, nullptr, KV_b, 2048, nullptr, nullptr, 1024, 16,
      VT_b, 2);
  gru_kernel<<<2048, 256, 0, stream>>>(GI_b, GH_b, qhid, qh_out, QHID_b /*now QHB*/);

  // ---- Cross attention (no energy stores: energy recomputed in the final launch) ----
  flash_attn<0><<<dim3(8, 64), 256, 0, stream>>>(
      QHID_b, 1024LL * 1024, 64, 1024, KV_b, KV_SB, 64, 2048,
      VT_b, O_b, nullptr, SCALE);
  gemm_bf16<<<dim3(8, 32), 256, 0, stream>>>(
      O_b, 1024, caoT, 1024, X2, nullptr, 1024, ca_out_b, X, 1024, nullptr, 0);

  // ---- MLP ----
  ln_bf16<1><<<4096, 256, 0, stream>>>(X2, nullptr, ln1_w, ln1_b, XN_b, 1);
  gemm_bf16<<<dim3(16, 32), 256, 0, stream>>>(
      XN_b, 1024, lin1T, 1024, nullptr, M1B, 2048, nullptr, nullptr, 1024, nullptr, 0);
  ln_bf16<2><<<4096, 256, 0, stream>>>(nullptr, M1B, ln2_w, ln2_b, LN2_b, 1);
  // final: lin2 (256 blocks) + energy recompute (512 blocks) — fills the idle half
  gemm_lin2_energy<<<768, 256, 0, stream>>>(
      LN2_b, lin2T, out0, X2, QHID_b, KV_b, energy);
}